// Round 5
// baseline (2791.717 us; speedup 1.0000x reference)
//
#include <hip/hip_runtime.h>
#include <math.h>

#define DEV static __device__ __forceinline__

DEV float4 ld4(const float* p){ return *(const float4*)p; }
DEV void   st4(float* p, float4 v){ *(float4*)p = v; }
DEV float4 f4add(float4 a, float4 b){ return make_float4(a.x+b.x,a.y+b.y,a.z+b.z,a.w+b.w); }
DEV float4 f4fma(float s, float4 a, float4 c){ return make_float4(fmaf(s,a.x,c.x),fmaf(s,a.y,c.y),fmaf(s,a.z,c.z),fmaf(s,a.w,c.w)); }
DEV float4 f4relu(float4 a){ return make_float4(fmaxf(a.x,0.f),fmaxf(a.y,0.f),fmaxf(a.z,0.f),fmaxf(a.w,0.f)); }

// ---------------- GNN: embedding tables  T[161][128] = emb_f @ W_slice ----------------
__global__ __launch_bounds__(128) void build_tables_k(
    const float* __restrict__ ea, const float* __restrict__ ed, const float* __restrict__ ec,
    const float* __restrict__ eh, const float* __restrict__ ear, const float* __restrict__ ech,
    const float* __restrict__ Wm, float* __restrict__ T)
{
    int r = blockIdx.x, c = threadIdx.x;
    const float* e; int dim, woff, rl;
    if      (r < 120) { e=ea;  dim=64; woff=0;   rl=r; }
    else if (r < 132) { e=ed;  dim=16; woff=64;  rl=r-120; }
    else if (r < 147) { e=ec;  dim=16; woff=80;  rl=r-132; }
    else if (r < 155) { e=eh;  dim=8;  woff=96;  rl=r-147; }
    else if (r < 157) { e=ear; dim=4;  woff=104; rl=r-155; }
    else              { e=ech; dim=4;  woff=108; rl=r-157; }
    float acc = 0.f;
    for (int k = 0; k < dim; ++k) acc += e[rl*dim + k] * Wm[(woff + k)*128 + c];
    T[r*128 + c] = acc;
}

// H[i][:] = sum of 6 table rows (+ charge * Wrow112)
__global__ __launch_bounds__(256) void embed_lookup_k(
    const int* __restrict__ xi, const float* __restrict__ charge,
    const float* __restrict__ T, const float* __restrict__ wq,
    float* __restrict__ H, int N)
{
    int t = threadIdx.x;
    int node = blockIdx.x*8 + (t >> 5);
    if (node >= N) return;
    int c = (t & 31)*4;
    const int* xp = xi + node*6;
    float4 acc = ld4(T + (       xp[0])*128 + c);
    acc = f4add(acc, ld4(T + (120+xp[1])*128 + c));
    acc = f4add(acc, ld4(T + (132+xp[2])*128 + c));
    acc = f4add(acc, ld4(T + (147+xp[3])*128 + c));
    acc = f4add(acc, ld4(T + (155+xp[4])*128 + c));
    acc = f4add(acc, ld4(T + (157+xp[5])*128 + c));
    if (charge) acc = f4fma(charge[node], ld4(wq + c), acc);
    st4(H + (size_t)node*128 + c, acc);
}

// ---------------- GCN degree / norm / CSR build ----------------
__global__ void init_deg_k(float* deg, int N){ int i = blockIdx.x*256+threadIdx.x; if (i<N) deg[i]=1.f; }

__global__ void deg_scatter_k(const int* __restrict__ col, const float* __restrict__ ew, float* deg, int E){
    int e = blockIdx.x*256+threadIdx.x; if (e>=E) return;
    unsafeAtomicAdd(deg + col[e], ew ? ew[e] : 1.f);
}

__global__ void dis_k(const float* __restrict__ deg, float* __restrict__ dis, int N){
    int i = blockIdx.x*256+threadIdx.x; if (i<N) dis[i] = 1.f/sqrtf(deg[i]);
}

// integer in-degree count (into cursor buffer, pre-zeroed)
__global__ void count_in_k(const int* __restrict__ col, int* __restrict__ cnt, int E){
    int e = blockIdx.x*256+threadIdx.x; if (e>=E) return;
    atomicAdd(&cnt[col[e]], 1);
}

// single-block exclusive scan: cnt (in cursor) -> rowptr; cursor reset to starts
__global__ __launch_bounds__(1024) void scan_k(int* __restrict__ cnt_cursor, int* __restrict__ rowptr, int N)
{
    __shared__ int part[1024];
    int t = threadIdx.x;
    int chunk = (N + 1023) >> 10;
    int base = t*chunk;
    int s = 0;
    for (int i = 0; i < chunk; ++i) { int idx = base+i; if (idx < N) s += cnt_cursor[idx]; }
    part[t] = s;
    __syncthreads();
    for (int off = 1; off < 1024; off <<= 1) {
        int v = (t >= off) ? part[t-off] : 0;
        __syncthreads();
        if (t >= off) part[t] += v;
        __syncthreads();
    }
    int run = (t == 0) ? 0 : part[t-1];
    for (int i = 0; i < chunk; ++i) {
        int idx = base+i; if (idx >= N) break;
        int c = cnt_cursor[idx];
        rowptr[idx] = run;
        cnt_cursor[idx] = run;   // cursor = start
        run += c;
    }
    if (t == 1023) rowptr[N] = part[1023];
}

// scatter edges into CSR slots; norm computed inline
__global__ void fill_csr_k(const int* __restrict__ row, const int* __restrict__ col,
                           const float* __restrict__ ew, const float* __restrict__ dis,
                           int* __restrict__ cursor, int* __restrict__ csr_src,
                           float* __restrict__ csr_nrm, int E)
{
    int e = blockIdx.x*256+threadIdx.x; if (e>=E) return;
    int r = row[e], c = col[e];
    int pos = atomicAdd(&cursor[c], 1);
    csr_src[pos] = r;
    csr_nrm[pos] = dis[r] * (ew ? ew[e] : 1.f) * dis[c];
}

// O[i] = bias + dis[i]^2 * H[i] + sum_j nrm_j * H[src_j]   (one wave per node, no atomics)
__global__ __launch_bounds__(256) void gcn_gather_k(
    const float* __restrict__ H, const int* __restrict__ rowptr,
    const int* __restrict__ csr_src, const float* __restrict__ csr_nrm,
    const float* __restrict__ dis, const float* __restrict__ bias,
    float* __restrict__ O, int N)
{
    int node = blockIdx.x*4 + (threadIdx.x >> 6);
    if (node >= N) return;
    int lane = threadIdx.x & 63;
    float s = dis[node]; s *= s;
    float2 h = *(const float2*)(H + (size_t)node*128 + lane*2);
    float2 b = *(const float2*)(bias + lane*2);
    float2 acc = make_float2(fmaf(s, h.x, b.x), fmaf(s, h.y, b.y));
    int beg = rowptr[node], end = rowptr[node+1];
    for (int j = beg; j < end; ++j) {
        int src = csr_src[j];
        float nm = csr_nrm[j];
        float2 hv = *(const float2*)(H + (size_t)src*128 + lane*2);
        acc.x = fmaf(nm, hv.x, acc.x);
        acc.y = fmaf(nm, hv.y, acc.y);
    }
    *(float2*)(O + (size_t)node*128 + lane*2) = acc;
}

// O = relu(A) @ W ; A:[N,128] W:[128,128]
__global__ __launch_bounds__(256) void gemm_relu128_k(
    const float* __restrict__ A, const float* __restrict__ W, float* __restrict__ O, int N)
{
    __shared__ float As[128*128];
    int t = threadIdx.x;
    int row0 = blockIdx.x * 128;
    int r = t >> 1, c0 = (t & 1)*64;
    for (int i = 0; i < 16; ++i) {
        float4 v = ld4(A + (size_t)(row0 + r)*128 + c0 + i*4);
        st4(As + r*128 + c0 + i*4, f4relu(v));
    }
    __syncthreads();
    int rg = (t >> 5)*16;
    int c  = (t & 31)*4;
    float4 acc[16];
    for (int i = 0; i < 16; ++i) acc[i] = make_float4(0.f,0.f,0.f,0.f);
    for (int k = 0; k < 128; ++k) {
        float4 w = ld4(W + k*128 + c);
        #pragma unroll
        for (int rr = 0; rr < 16; ++rr) {
            float a = As[(rg + rr)*128 + k];
            acc[rr] = f4fma(a, w, acc[rr]);
        }
    }
    for (int rr = 0; rr < 16; ++rr)
        st4(O + (size_t)(row0 + rg + rr)*128 + c, acc[rr]);
}

// ---------------- mean pool ----------------
__global__ __launch_bounds__(128) void mean_pool_sum_k(
    const float* __restrict__ X, const int* __restrict__ bv,
    float* __restrict__ featp /* stride 512 */, int chunk, int N)
{
    __shared__ float acc[16*128];
    int t = threadIdx.x;
    for (int b = 0; b < 16; ++b) acc[b*128 + t] = 0.f;
    int i0 = blockIdx.x * chunk;
    int iend = min(i0 + chunk, N);
    int bcur = bv[i0];
    float r = 0.f;
    for (int i = i0; i < iend; ++i) {
        int b = bv[i];
        if (b != bcur) { acc[bcur*128 + t] += r; r = 0.f; bcur = b; }
        r += fmaxf(X[(size_t)i*128 + t], 0.f);
    }
    acc[bcur*128 + t] += r;
    for (int b = 0; b < 16; ++b) {
        float v = acc[b*128 + t];
        if (v != 0.f) unsafeAtomicAdd(featp + b*512 + t, v);
    }
}

__global__ void count_batch_k(const int* __restrict__ bv, float* __restrict__ cnt, int N){
    __shared__ int h[16];
    int t = threadIdx.x;
    if (t < 16) h[t] = 0;
    __syncthreads();
    int i = blockIdx.x*256 + t;
    if (i < N) atomicAdd(&h[bv[i]], 1);
    __syncthreads();
    if (t < 16 && h[t]) unsafeAtomicAdd(&cnt[t], (float)h[t]);
}

// ---------------- voxel CNN: LDS-tiled fused conv(3x3x3 SAME)+bias+BN-stats+max/min-pool ----
// Block: 8x8x4 pooled tile (256 threads), 8 output channels. Per ci: stage 18x18x10 input
// halo tile into LDS (applying previous layer's BN+ReLU on the fly if BNIN), then each
// thread keeps its 4x4x4 patch in registers and FMAs against LDS-broadcast weights.
template<int CIN, int COUT, int D, bool BNIN>
__global__ __launch_bounds__(256) void conv_pool2_k(
    const float* __restrict__ inmax, const float* __restrict__ inmin,
    const float* __restrict__ scin, const float* __restrict__ shin,
    const float* __restrict__ wt, const float* __restrict__ bias,
    float* __restrict__ outmax, float* __restrict__ outmin, float* __restrict__ stats)
{
    constexpr int PD = D/2;
    constexpr int NTX = (PD >= 8) ? PD/8 : 1;
    constexpr int SY = 19, SZ = 19*18;             // padded tile strides
    __shared__ float tileL[10*SZ];                 // 3420 floats
    __shared__ float ldsW[CIN*9*32];
    __shared__ float swred[4*16];

    int tid = threadIdx.x;
    int co0 = blockIdx.y * 8;
    int n   = blockIdx.z;

    // stage packed weights [ci][r][cl][kw pad4]
    for (int i = tid; i < CIN*9*32; i += 256) {
        int kw = i & 3, cl = (i >> 2) & 7, r = (i >> 5) % 9, ci = i / 288;
        ldsW[i] = (kw < 3) ? wt[((co0 + cl)*CIN + ci)*27 + r*3 + kw] : 0.f;
    }

    int tb = blockIdx.x;
    int tx = tb % NTX, ty = (tb / NTX) % NTX, tz = tb / (NTX*NTX);
    int pw = tid & 7, ph = (tid >> 3) & 7, pd = tid >> 6;   // pooled coords in tile
    int ix0 = tx*16 - 1, iy0 = ty*16 - 1, iz0 = tz*8 - 1;

    float acc[8][8];
    #pragma unroll
    for (int cl = 0; cl < 8; ++cl)
        #pragma unroll
        for (int p = 0; p < 8; ++p) acc[cl][p] = 0.f;

    for (int ci = 0; ci < CIN; ++ci) {
        __syncthreads();   // also covers initial weight staging
        float s_in = 0.f, sh_in = 0.f;
        if (BNIN) { s_in = scin[ci]; sh_in = shin[ci]; }
        const float* imx = inmax + ((size_t)(n*CIN + ci))*((size_t)D*D*D);
        const float* imn = BNIN ? inmin + ((size_t)(n*CIN + ci))*((size_t)D*D*D) : nullptr;
        for (int i = tid; i < 10*18*18; i += 256) {
            int z = i / 324, r2 = i % 324, y = r2 / 18, x = r2 % 18;
            int gz = iz0 + z, gy = iy0 + y, gx = ix0 + x;
            float val = 0.f;
            if ((unsigned)gz < (unsigned)D && (unsigned)gy < (unsigned)D && (unsigned)gx < (unsigned)D) {
                size_t gi = ((size_t)gz*D + gy)*D + gx;
                if (BNIN) {
                    float v = (s_in >= 0.f) ? imx[gi] : imn[gi];
                    val = fmaxf(fmaf(v, s_in, sh_in), 0.f);
                } else val = imx[gi];
            }
            tileL[z*SZ + y*SY + x] = val;
        }
        __syncthreads();

        float v[4][4][4];
        int base = (2*pd)*SZ + (2*ph)*SY + 2*pw;
        #pragma unroll
        for (int a = 0; a < 4; ++a)
            #pragma unroll
            for (int b = 0; b < 4; ++b)
                #pragma unroll
                for (int c = 0; c < 4; ++c)
                    v[a][b][c] = tileL[base + a*SZ + b*SY + c];

        const float4* wrow = (const float4*)ldsW + ci*9*8;
        #pragma unroll
        for (int r = 0; r < 9; ++r) {
            const int kd = r/3, kh = r%3;
            #pragma unroll
            for (int cl = 0; cl < 8; ++cl) {
                float4 w = wrow[r*8 + cl];
                #pragma unroll
                for (int dz = 0; dz < 2; ++dz)
                #pragma unroll
                for (int dy = 0; dy < 2; ++dy)
                #pragma unroll
                for (int dx = 0; dx < 2; ++dx) {
                    float s = fmaf(w.x, v[dz+kd][dy+kh][dx],
                              fmaf(w.y, v[dz+kd][dy+kh][dx+1],
                                   w.z * v[dz+kd][dy+kh][dx+2]));
                    acc[cl][dz*4 + dy*2 + dx] += s;
                }
            }
        }
    }

    // bias, pooled max/min, per-channel stat partials
    int ow = tx*8 + pw, oh = ty*8 + ph, od = tz*4 + pd;
    float ssum[8], ssq[8];
    size_t obase = ((size_t)n*COUT + co0)*((size_t)PD*PD*PD) + ((size_t)od*PD + oh)*PD + ow;
    #pragma unroll
    for (int cl = 0; cl < 8; ++cl) {
        float cb = bias[co0 + cl];
        float mx = -1e30f, mn = 1e30f, s = 0.f, q = 0.f;
        #pragma unroll
        for (int p = 0; p < 8; ++p) {
            float val = acc[cl][p] + cb;
            mx = fmaxf(mx, val); mn = fminf(mn, val);
            s += val; q = fmaf(val, val, q);
        }
        ssum[cl] = s; ssq[cl] = q;
        outmax[obase + (size_t)cl*(PD*PD*PD)] = mx;
        outmin[obase + (size_t)cl*(PD*PD*PD)] = mn;
    }

    int lane = tid & 63, wid = tid >> 6;
    #pragma unroll
    for (int cl = 0; cl < 8; ++cl) {
        float a_ = ssum[cl], b_ = ssq[cl];
        #pragma unroll
        for (int off = 32; off; off >>= 1) {
            a_ += __shfl_down(a_, off, 64);
            b_ += __shfl_down(b_, off, 64);
        }
        if (lane == 0) { swred[wid*16 + cl*2] = a_; swred[wid*16 + cl*2 + 1] = b_; }
    }
    __syncthreads();
    if (tid < 16) {
        float t = swred[tid] + swred[16 + tid] + swred[32 + tid] + swred[48 + tid];
        unsafeAtomicAdd(&stats[co0*2 + tid], t);
    }
}

__global__ void bn_final_k(const float* __restrict__ stats, const float* __restrict__ g,
                           const float* __restrict__ b, float* __restrict__ sc, float* __restrict__ sh,
                           int C, float invN)
{
    int c = threadIdx.x; if (c >= C) return;
    float m = stats[c*2] * invN;
    float v = stats[c*2+1] * invN - m*m;
    float s = g[c] * rsqrtf(v + 1e-5f);
    sc[c] = s; sh[c] = b[c] - m*s;
}

__global__ __launch_bounds__(256) void bn_select_k(
    const float* __restrict__ mx, const float* __restrict__ mn,
    const float* __restrict__ sc, const float* __restrict__ sh,
    float* __restrict__ out, int Cmask, int lgPD3, int total)
{
    int idx = blockIdx.x*256 + threadIdx.x;
    if (idx >= total) return;
    int c = (idx >> lgPD3) & Cmask;
    float s = sc[c];
    float v = (s >= 0.f) ? mx[idx] : mn[idx];
    out[idx] = fmaxf(fmaf(v, s, sh[c]), 0.f);
}

// fc: X[16,32768] @ W[32768,128] -> accumulate into feat[:,384:512]
__global__ __launch_bounds__(128) void fc_acc_k(
    const float* __restrict__ X, const float* __restrict__ W, float* __restrict__ featv)
{
    int t = threadIdx.x;
    int k0 = blockIdx.x*256;
    float acc[16];
    #pragma unroll
    for (int b = 0; b < 16; ++b) acc[b] = 0.f;
    for (int k = k0; k < k0 + 256; ++k) {
        float w = W[(size_t)k*128 + t];
        #pragma unroll
        for (int b = 0; b < 16; ++b) acc[b] = fmaf(X[(size_t)b*32768 + k], w, acc[b]);
    }
    for (int b = 0; b < 16; ++b) unsafeAtomicAdd(featv + b*512 + t, acc[b]);
}

// ---------------- small dense layers ----------------
__global__ __launch_bounds__(256) void head_k(
    const float* __restrict__ X, const float* __restrict__ W, const float* __restrict__ b,
    float* __restrict__ O, int K, int Ncol, int relu)
{
    int t = blockIdx.x*256 + threadIdx.x;
    if (t >= 16*Ncol) return;
    int bi = t / Ncol, c = t % Ncol;
    float acc = b[c];
    for (int k = 0; k < K; ++k) acc = fmaf(X[bi*K + k], W[k*Ncol + c], acc);
    if (relu) acc = fmaxf(acc, 0.f);
    O[bi*Ncol + c] = acc;
}

__global__ void gebn_k(const float* __restrict__ g2, const float* __restrict__ g,
                       const float* __restrict__ b, float* __restrict__ featg /* stride 512 */)
{
    int c = threadIdx.x;  // 128
    float m = 0.f;
    for (int i = 0; i < 16; ++i) m += g2[i*128 + c];
    m *= (1.f/16.f);
    float v = 0.f;
    for (int i = 0; i < 16; ++i) { float d = g2[i*128 + c] - m; v += d*d; }
    v *= (1.f/16.f);
    float s = g[c] * rsqrtf(v + 1e-5f);
    for (int i = 0; i < 16; ++i)
        featg[i*512 + c] = fmaxf((g2[i*128 + c] - m)*s + b[c], 0.f);
}

__global__ void finalize_feat_k(float* __restrict__ feat, const float* __restrict__ cntm,
                                const float* __restrict__ cntz, const float* __restrict__ fcb)
{
    int t = blockIdx.x*256 + threadIdx.x;   // 16*512
    if (t >= 8192) return;
    int bi = t >> 9, c = t & 511;
    float v = feat[t];
    if      (c < 128) v /= fmaxf(cntm[bi], 1.f);
    else if (c < 256) v /= fmaxf(cntz[bi], 1.f);
    else if (c >= 384) v = fmaxf(v + fcb[c - 384], 0.f);
    feat[t] = v;
}

// =====================================================================================
extern "C" void kernel_launch(void* const* d_in, const int* in_sizes, int n_in,
                              void* d_out, int out_size, void* d_ws, size_t ws_size,
                              hipStream_t stream)
{
    const int*   mol_x  = (const int*)  d_in[0];
    const float* mol_q  = (const float*)d_in[1];
    const int*   mol_ei = (const int*)  d_in[2];
    const float* mol_ew = (const float*)d_in[3];
    const int*   mol_bv = (const int*)  d_in[4];
    const int*   zeo_x  = (const int*)  d_in[5];
    const int*   zeo_ei = (const int*)  d_in[6];
    const int*   zeo_bv = (const int*)  d_in[7];
    const float* voxel  = (const float*)d_in[8];
    const float* gattr  = (const float*)d_in[9];
    const float* ea  = (const float*)d_in[10];
    const float* ed  = (const float*)d_in[11];
    const float* ec  = (const float*)d_in[12];
    const float* eh  = (const float*)d_in[13];
    const float* ear = (const float*)d_in[14];
    const float* ech = (const float*)d_in[15];
    const float* mc1w=(const float*)d_in[16]; const float* mc1b=(const float*)d_in[17];
    const float* mc2w=(const float*)d_in[18]; const float* mc2b=(const float*)d_in[19];
    const float* zc1w=(const float*)d_in[20]; const float* zc1b=(const float*)d_in[21];
    const float* zc2w=(const float*)d_in[22]; const float* zc2b=(const float*)d_in[23];
    const float* cv1w=(const float*)d_in[24]; const float* cv1b=(const float*)d_in[25];
    const float* bn1g=(const float*)d_in[26]; const float* bn1b=(const float*)d_in[27];
    const float* cv2w=(const float*)d_in[28]; const float* cv2b=(const float*)d_in[29];
    const float* bn2g=(const float*)d_in[30]; const float* bn2b=(const float*)d_in[31];
    const float* cv3w=(const float*)d_in[32]; const float* cv3b=(const float*)d_in[33];
    const float* bn3g=(const float*)d_in[34]; const float* bn3b=(const float*)d_in[35];
    const float* fcw =(const float*)d_in[36]; const float* fcb =(const float*)d_in[37];
    const float* ge1w=(const float*)d_in[38]; const float* ge1b=(const float*)d_in[39];
    const float* ge2w=(const float*)d_in[40]; const float* ge2b=(const float*)d_in[41];
    const float* gbng=(const float*)d_in[42]; const float* gbnb=(const float*)d_in[43];
    const float* h1w =(const float*)d_in[44]; const float* h1b =(const float*)d_in[45];
    const float* h2w =(const float*)d_in[46]; const float* h2b =(const float*)d_in[47];
    const float* h3w =(const float*)d_in[48]; const float* h3b =(const float*)d_in[49];

    const int Nm = in_sizes[0]/6, Em = in_sizes[2]/2;
    const int Nz = in_sizes[5]/6, Ez = in_sizes[6]/2;

    float* WS = (float*)d_ws;
    float* A  = WS;                     // 16,777,216 floats (67 MB)
    float* Bb = WS + 16777216;          // 16,777,216 floats (67 MB)
    float* S  = WS + 33554432;          // small scratch
    float* deg  = S;
    float* dis  = S + 131072;
    float* csr_nrm = S + 262144;        // 524288
    float* T    = S + 786432;           // 161*128
    float* cntm = S + 807040;
    float* cntz = S + 807056;
    float* feat = S + 807072;           // [16][512]
    float* st1  = S + 815264; float* st2 = st1 + 32; float* st3 = st1 + 96;
    float* sc1  = S + 815488; float* sh1 = sc1 + 16;
    float* sc2  = sc1 + 32;   float* sh2 = sc1 + 64;
    float* sc3  = sc1 + 96;   float* sh3 = sc1 + 160;
    float* g1   = S + 815712;           // 16*64
    float* g2   = S + 816736;           // 16*128
    float* H1   = S + 818784;           // 16*512
    float* H2   = S + 826976;           // 16*256
    int* rowptr  = (int*)(S + 831072);  // 131073
    int* cursor  = (int*)(S + 962176);  // 131072
    int* csr_src = (int*)(S + 1093248); // 524288  (ends S+1617536)

    // zero small accumulators (feat/stats/cnt) each replay
    hipMemsetAsync(S, 0, (size_t)831072*sizeof(float), stream);

    // ---------------- molecule branch ----------------
    build_tables_k<<<161,128,0,stream>>>(ea,ed,ec,eh,ear,ech, mc1w, T);
    init_deg_k   <<<Nm/256,256,0,stream>>>(deg, Nm);
    deg_scatter_k<<<Em/256,256,0,stream>>>(mol_ei+Em, mol_ew, deg, Em);
    dis_k        <<<Nm/256,256,0,stream>>>(deg, dis, Nm);
    hipMemsetAsync(cursor, 0, (size_t)Nm*sizeof(int), stream);
    count_in_k   <<<Em/256,256,0,stream>>>(mol_ei+Em, cursor, Em);
    scan_k       <<<1,1024,0,stream>>>(cursor, rowptr, Nm);
    fill_csr_k   <<<Em/256,256,0,stream>>>(mol_ei, mol_ei+Em, mol_ew, dis, cursor, csr_src, csr_nrm, Em);
    embed_lookup_k<<<Nm/8,256,0,stream>>>(mol_x, mol_q, T, mc1w + 112*128, A, Nm);
    gcn_gather_k <<<Nm/4,256,0,stream>>>(A, rowptr, csr_src, csr_nrm, dis, mc1b, Bb, Nm);
    gemm_relu128_k<<<Nm/128,256,0,stream>>>(Bb, mc2w, A, Nm);
    gcn_gather_k <<<Nm/4,256,0,stream>>>(A, rowptr, csr_src, csr_nrm, dis, mc2b, Bb, Nm);
    count_batch_k<<<Nm/256,256,0,stream>>>(mol_bv, cntm, Nm);
    mean_pool_sum_k<<<256,128,0,stream>>>(Bb, mol_bv, feat + 0, (Nm+255)/256, Nm);

    // ---------------- zeolite branch ----------------
    build_tables_k<<<161,128,0,stream>>>(ea,ed,ec,eh,ear,ech, zc1w, T);
    init_deg_k   <<<Nz/256,256,0,stream>>>(deg, Nz);
    deg_scatter_k<<<Ez/256,256,0,stream>>>(zeo_ei+Ez, nullptr, deg, Ez);
    dis_k        <<<Nz/256,256,0,stream>>>(deg, dis, Nz);
    hipMemsetAsync(cursor, 0, (size_t)Nz*sizeof(int), stream);
    count_in_k   <<<Ez/256,256,0,stream>>>(zeo_ei+Ez, cursor, Ez);
    scan_k       <<<1,1024,0,stream>>>(cursor, rowptr, Nz);
    fill_csr_k   <<<Ez/256,256,0,stream>>>(zeo_ei, zeo_ei+Ez, nullptr, dis, cursor, csr_src, csr_nrm, Ez);
    embed_lookup_k<<<Nz/8,256,0,stream>>>(zeo_x, nullptr, T, nullptr, A, Nz);
    gcn_gather_k <<<Nz/4,256,0,stream>>>(A, rowptr, csr_src, csr_nrm, dis, zc1b, Bb, Nz);
    gemm_relu128_k<<<Nz/128,256,0,stream>>>(Bb, zc2w, A, Nz);
    gcn_gather_k <<<Nz/4,256,0,stream>>>(A, rowptr, csr_src, csr_nrm, dis, zc2b, Bb, Nz);
    count_batch_k<<<Nz/256,256,0,stream>>>(zeo_bv, cntz, Nz);
    mean_pool_sum_k<<<256,128,0,stream>>>(Bb, zeo_bv, feat + 128, (Nz+255)/256, Nz);

    // ---------------- voxel CNN (LDS-tiled fused conv; BN of prev layer fused into staging) ----
    // layer 1: voxel [16][2][64^3] -> max/min pooled [16][16][32^3] in A halves
    conv_pool2_k<2,16,64,false><<<dim3(128,2,16),256,0,stream>>>(
        voxel, nullptr, nullptr, nullptr, cv1w, cv1b, A, A+8388608, st1);
    bn_final_k<<<1,64,0,stream>>>(st1, bn1g, bn1b, sc1, sh1, 16, 1.f/(16.f*262144.f));

    // layer 2: (BN1 fused on stage) -> max/min pooled [16][32][16^3] in Bb halves
    conv_pool2_k<16,32,32,true><<<dim3(16,4,16),256,0,stream>>>(
        A, A+8388608, sc1, sh1, cv2w, cv2b, Bb, Bb+2097152, st2);
    bn_final_k<<<1,64,0,stream>>>(st2, bn2g, bn2b, sc2, sh2, 32, 1.f/(16.f*32768.f));

    // layer 3: (BN2 fused on stage) -> max/min pooled [16][64][8^3] in A halves
    conv_pool2_k<32,64,16,true><<<dim3(2,8,16),256,0,stream>>>(
        Bb, Bb+2097152, sc2, sh2, cv3w, cv3b, A, A+524288, st3);
    bn_final_k<<<1,64,0,stream>>>(st3, bn3g, bn3b, sc3, sh3, 64, 1.f/(16.f*4096.f));
    bn_select_k<<<2048,256,0,stream>>>(A, A+524288, sc3, sh3, Bb, 63, 9, 524288);

    fc_acc_k<<<128,128,0,stream>>>(Bb, fcw, feat + 384);

    // ---------------- global encoder ----------------
    head_k<<<4,256,0,stream>>>(gattr, ge1w, ge1b, g1, 17, 64, 1);
    head_k<<<8,256,0,stream>>>(g1, ge2w, ge2b, g2, 64, 128, 0);
    gebn_k<<<1,128,0,stream>>>(g2, gbng, gbnb, feat + 256);

    // ---------------- fusion head ----------------
    finalize_feat_k<<<32,256,0,stream>>>(feat, cntm, cntz, fcb);
    head_k<<<32,256,0,stream>>>(feat, h1w, h1b, H1, 512, 512, 1);
    head_k<<<16,256,0,stream>>>(H1, h2w, h2b, H2, 512, 256, 1);
    head_k<<<1,256,0,stream>>>(H2, h3w, h3b, (float*)d_out, 256, 3, 0);
}

// Round 6
// 2604.550 us; speedup vs baseline: 1.0719x; 1.0719x over previous
//
#include <hip/hip_runtime.h>
#include <math.h>

#define DEV static __device__ __forceinline__

DEV float4 ld4(const float* p){ return *(const float4*)p; }
DEV void   st4(float* p, float4 v){ *(float4*)p = v; }
DEV float4 f4add(float4 a, float4 b){ return make_float4(a.x+b.x,a.y+b.y,a.z+b.z,a.w+b.w); }
DEV float4 f4fma(float s, float4 a, float4 c){ return make_float4(fmaf(s,a.x,c.x),fmaf(s,a.y,c.y),fmaf(s,a.z,c.z),fmaf(s,a.w,c.w)); }
DEV float4 f4relu(float4 a){ return make_float4(fmaxf(a.x,0.f),fmaxf(a.y,0.f),fmaxf(a.z,0.f),fmaxf(a.w,0.f)); }

// ---------------- GNN: embedding tables  T[161][128] = emb_f @ W_slice ----------------
__global__ __launch_bounds__(128) void build_tables_k(
    const float* __restrict__ ea, const float* __restrict__ ed, const float* __restrict__ ec,
    const float* __restrict__ eh, const float* __restrict__ ear, const float* __restrict__ ech,
    const float* __restrict__ Wm, float* __restrict__ T)
{
    int r = blockIdx.x, c = threadIdx.x;
    const float* e; int dim, woff, rl;
    if      (r < 120) { e=ea;  dim=64; woff=0;   rl=r; }
    else if (r < 132) { e=ed;  dim=16; woff=64;  rl=r-120; }
    else if (r < 147) { e=ec;  dim=16; woff=80;  rl=r-132; }
    else if (r < 155) { e=eh;  dim=8;  woff=96;  rl=r-147; }
    else if (r < 157) { e=ear; dim=4;  woff=104; rl=r-155; }
    else              { e=ech; dim=4;  woff=108; rl=r-157; }
    float acc = 0.f;
    for (int k = 0; k < dim; ++k) acc += e[rl*dim + k] * Wm[(woff + k)*128 + c];
    T[r*128 + c] = acc;
}

// H[i][:] = sum of 6 table rows (+ charge * Wrow112)
__global__ __launch_bounds__(256) void embed_lookup_k(
    const int* __restrict__ xi, const float* __restrict__ charge,
    const float* __restrict__ T, const float* __restrict__ wq,
    float* __restrict__ H, int N)
{
    int t = threadIdx.x;
    int node = blockIdx.x*8 + (t >> 5);
    if (node >= N) return;
    int c = (t & 31)*4;
    const int* xp = xi + node*6;
    float4 acc = ld4(T + (       xp[0])*128 + c);
    acc = f4add(acc, ld4(T + (120+xp[1])*128 + c));
    acc = f4add(acc, ld4(T + (132+xp[2])*128 + c));
    acc = f4add(acc, ld4(T + (147+xp[3])*128 + c));
    acc = f4add(acc, ld4(T + (155+xp[4])*128 + c));
    acc = f4add(acc, ld4(T + (157+xp[5])*128 + c));
    if (charge) acc = f4fma(charge[node], ld4(wq + c), acc);
    st4(H + (size_t)node*128 + c, acc);
}

// ---------------- GCN degree / norm / CSR build ----------------
__global__ void init_deg_k(float* deg, int N){ int i = blockIdx.x*256+threadIdx.x; if (i<N) deg[i]=1.f; }

__global__ void deg_scatter_k(const int* __restrict__ col, const float* __restrict__ ew, float* deg, int E){
    int e = blockIdx.x*256+threadIdx.x; if (e>=E) return;
    unsafeAtomicAdd(deg + col[e], ew ? ew[e] : 1.f);
}

__global__ void dis_k(const float* __restrict__ deg, float* __restrict__ dis, int N){
    int i = blockIdx.x*256+threadIdx.x; if (i<N) dis[i] = 1.f/sqrtf(deg[i]);
}

// integer in-degree count (into cursor buffer, pre-zeroed)
__global__ void count_in_k(const int* __restrict__ col, int* __restrict__ cnt, int E){
    int e = blockIdx.x*256+threadIdx.x; if (e>=E) return;
    atomicAdd(&cnt[col[e]], 1);
}

// single-block exclusive scan: cnt (in cursor) -> rowptr; cursor reset to starts
__global__ __launch_bounds__(1024) void scan_k(int* __restrict__ cnt_cursor, int* __restrict__ rowptr, int N)
{
    __shared__ int part[1024];
    int t = threadIdx.x;
    int chunk = (N + 1023) >> 10;
    int base = t*chunk;
    int s = 0;
    for (int i = 0; i < chunk; ++i) { int idx = base+i; if (idx < N) s += cnt_cursor[idx]; }
    part[t] = s;
    __syncthreads();
    for (int off = 1; off < 1024; off <<= 1) {
        int v = (t >= off) ? part[t-off] : 0;
        __syncthreads();
        if (t >= off) part[t] += v;
        __syncthreads();
    }
    int run = (t == 0) ? 0 : part[t-1];
    for (int i = 0; i < chunk; ++i) {
        int idx = base+i; if (idx >= N) break;
        int c = cnt_cursor[idx];
        rowptr[idx] = run;
        cnt_cursor[idx] = run;   // cursor = start
        run += c;
    }
    if (t == 1023) rowptr[N] = part[1023];
}

// scatter edges into CSR slots; norm computed inline
__global__ void fill_csr_k(const int* __restrict__ row, const int* __restrict__ col,
                           const float* __restrict__ ew, const float* __restrict__ dis,
                           int* __restrict__ cursor, int* __restrict__ csr_src,
                           float* __restrict__ csr_nrm, int E)
{
    int e = blockIdx.x*256+threadIdx.x; if (e>=E) return;
    int r = row[e], c = col[e];
    int pos = atomicAdd(&cursor[c], 1);
    csr_src[pos] = r;
    csr_nrm[pos] = dis[r] * (ew ? ew[e] : 1.f) * dis[c];
}

// O[i] = bias + dis[i]^2 * H[i] + sum_j nrm_j * H[src_j]
// 32 lanes/node (float4), 8 nodes/block, manual unroll-2 for memory-level parallelism
__global__ __launch_bounds__(256) void gcn_gather_k(
    const float* __restrict__ H, const int* __restrict__ rowptr,
    const int* __restrict__ csr_src, const float* __restrict__ csr_nrm,
    const float* __restrict__ dis, const float* __restrict__ bias,
    float* __restrict__ O, int N)
{
    int node = blockIdx.x*8 + (threadIdx.x >> 5);
    if (node >= N) return;
    int lane = (threadIdx.x & 31)*4;
    float s = dis[node]; s *= s;
    float4 h = ld4(H + (size_t)node*128 + lane);
    float4 b = ld4(bias + lane);
    float4 acc = f4fma(s, h, b);
    int j = rowptr[node], end = rowptr[node+1];
    for (; j + 2 <= end; j += 2) {
        int   s0 = csr_src[j],   s1 = csr_src[j+1];
        float n0 = csr_nrm[j],   n1 = csr_nrm[j+1];
        float4 h0 = ld4(H + (size_t)s0*128 + lane);
        float4 h1 = ld4(H + (size_t)s1*128 + lane);
        acc = f4fma(n0, h0, acc);
        acc = f4fma(n1, h1, acc);
    }
    if (j < end) {
        float4 h0 = ld4(H + (size_t)csr_src[j]*128 + lane);
        acc = f4fma(csr_nrm[j], h0, acc);
    }
    st4(O + (size_t)node*128 + lane, acc);
}

// O = relu(A) @ W ; A:[N,128] W:[128,128]
__global__ __launch_bounds__(256) void gemm_relu128_k(
    const float* __restrict__ A, const float* __restrict__ W, float* __restrict__ O, int N)
{
    __shared__ float As[128*128];
    int t = threadIdx.x;
    int row0 = blockIdx.x * 128;
    int r = t >> 1, c0 = (t & 1)*64;
    for (int i = 0; i < 16; ++i) {
        float4 v = ld4(A + (size_t)(row0 + r)*128 + c0 + i*4);
        st4(As + r*128 + c0 + i*4, f4relu(v));
    }
    __syncthreads();
    int rg = (t >> 5)*16;
    int c  = (t & 31)*4;
    float4 acc[16];
    for (int i = 0; i < 16; ++i) acc[i] = make_float4(0.f,0.f,0.f,0.f);
    for (int k = 0; k < 128; ++k) {
        float4 w = ld4(W + k*128 + c);
        #pragma unroll
        for (int rr = 0; rr < 16; ++rr) {
            float a = As[(rg + rr)*128 + k];
            acc[rr] = f4fma(a, w, acc[rr]);
        }
    }
    for (int rr = 0; rr < 16; ++rr)
        st4(O + (size_t)(row0 + rg + rr)*128 + c, acc[rr]);
}

// ---------------- mean pool ----------------
__global__ __launch_bounds__(128) void mean_pool_sum_k(
    const float* __restrict__ X, const int* __restrict__ bv,
    float* __restrict__ featp /* stride 512 */, int chunk, int N)
{
    __shared__ float acc[16*128];
    int t = threadIdx.x;
    for (int b = 0; b < 16; ++b) acc[b*128 + t] = 0.f;
    int i0 = blockIdx.x * chunk;
    int iend = min(i0 + chunk, N);
    int bcur = bv[i0];
    float r = 0.f;
    for (int i = i0; i < iend; ++i) {
        int b = bv[i];
        if (b != bcur) { acc[bcur*128 + t] += r; r = 0.f; bcur = b; }
        r += fmaxf(X[(size_t)i*128 + t], 0.f);
    }
    acc[bcur*128 + t] += r;
    for (int b = 0; b < 16; ++b) {
        float v = acc[b*128 + t];
        if (v != 0.f) unsafeAtomicAdd(featp + b*512 + t, v);
    }
}

__global__ void count_batch_k(const int* __restrict__ bv, float* __restrict__ cnt, int N){
    __shared__ int h[16];
    int t = threadIdx.x;
    if (t < 16) h[t] = 0;
    __syncthreads();
    int i = blockIdx.x*256 + t;
    if (i < N) atomicAdd(&h[bv[i]], 1);
    __syncthreads();
    if (t < 16 && h[t]) unsafeAtomicAdd(&cnt[t], (float)h[t]);
}

// ---------------- voxel CNN: LDS-tiled conv(3x3x3 SAME)+bias+BN-stats+max/min-pool -------
// Block: 256 threads = 8x8x4 pooled positions; CL output channels per thread.
// Weights: block-uniform indices -> scalar (SGPR) loads, no LDS.
// Input tile: 18x18x10 halo in LDS (stride-padded); prev-layer BN+ReLU fused into staging.
// Inner loop: pure chained FMAs.
template<int CIN, int COUT, int D, int CL, bool BNIN>
__global__ __launch_bounds__(256) void conv_pool3_k(
    const float* __restrict__ inmax, const float* __restrict__ inmin,
    const float* __restrict__ scin, const float* __restrict__ shin,
    const float* __restrict__ wt, const float* __restrict__ bias,
    float* __restrict__ outmax, float* __restrict__ outmin, float* __restrict__ stats)
{
    constexpr int PD = D/2;
    constexpr int NTX = (PD >= 8) ? PD/8 : 1;
    constexpr int SY = 20, SZ = 20*18;
    __shared__ float tileL[10*SZ];                 // 3600 floats
    __shared__ float swred[4*2*CL];

    int tid = threadIdx.x;
    int co0 = blockIdx.y * CL;
    int n   = blockIdx.z;

    int tb = blockIdx.x;
    int tx = tb % NTX, ty = (tb / NTX) % NTX, tz = tb / (NTX*NTX);
    int pw = tid & 7, ph = (tid >> 3) & 7, pd = tid >> 6;   // pooled coords in tile
    int ix0 = tx*16 - 1, iy0 = ty*16 - 1, iz0 = tz*8 - 1;

    // staging coordinates (computed once; 18x18 slice = 324 slots, 2 passes of 256)
    int sy0 = tid / 18, sx0 = tid - sy0*18;
    int sp1 = tid + 256;
    int sy1 = sp1 / 18, sx1 = sp1 - sy1*18;
    bool has1 = (sp1 < 324);

    float acc[CL][8];
    #pragma unroll
    for (int cl = 0; cl < CL; ++cl)
        #pragma unroll
        for (int p = 0; p < 8; ++p) acc[cl][p] = 0.f;

    for (int ci = 0; ci < CIN; ++ci) {
        __syncthreads();   // tile consumed (prev iter)
        float s_in = 0.f, sh_in = 0.f;
        if (BNIN) { s_in = scin[ci]; sh_in = shin[ci]; }
        const float* ib;
        if (BNIN) ib = (s_in >= 0.f) ? inmax + ((size_t)(n*CIN + ci))*((size_t)D*D*D)
                                     : inmin + ((size_t)(n*CIN + ci))*((size_t)D*D*D);
        else      ib = inmax + ((size_t)(n*CIN + ci))*((size_t)D*D*D);

        #pragma unroll 2
        for (int z = 0; z < 10; ++z) {
            int gz = iz0 + z; bool zok = (unsigned)gz < (unsigned)D;
            {
                int gy = iy0 + sy0, gx = ix0 + sx0;
                float val = 0.f;
                if (zok && (unsigned)gy < (unsigned)D && (unsigned)gx < (unsigned)D) {
                    float v = ib[((size_t)gz*D + gy)*D + gx];
                    val = BNIN ? fmaxf(fmaf(v, s_in, sh_in), 0.f) : v;
                }
                tileL[z*SZ + sy0*SY + sx0] = val;
            }
            if (has1) {
                int gy = iy0 + sy1, gx = ix0 + sx1;
                float val = 0.f;
                if (zok && (unsigned)gy < (unsigned)D && (unsigned)gx < (unsigned)D) {
                    float v = ib[((size_t)gz*D + gy)*D + gx];
                    val = BNIN ? fmaxf(fmaf(v, s_in, sh_in), 0.f) : v;
                }
                tileL[z*SZ + sy1*SY + sx1] = val;
            }
        }
        __syncthreads();   // tile ready

        // 4x4x4 register patch (consecutive x at even offsets -> fusable LDS reads)
        float v[4][4][4];
        int base = (2*pd)*SZ + (2*ph)*SY + 2*pw;
        #pragma unroll
        for (int a = 0; a < 4; ++a)
            #pragma unroll
            for (int b = 0; b < 4; ++b)
                #pragma unroll
                for (int c = 0; c < 4; ++c)
                    v[a][b][c] = tileL[base + a*SZ + b*SY + c];

        const float* wb = wt + ((size_t)co0*CIN + ci)*27;   // uniform -> s_load
        #pragma unroll
        for (int cl = 0; cl < CL; ++cl) {
            const float* wc = wb + (size_t)cl*CIN*27;
            #pragma unroll
            for (int r = 0; r < 9; ++r) {
                const int kd = r/3, kh = r%3;
                float w0 = wc[r*3+0], w1 = wc[r*3+1], w2 = wc[r*3+2];
                #pragma unroll
                for (int dz = 0; dz < 2; ++dz)
                #pragma unroll
                for (int dy = 0; dy < 2; ++dy)
                #pragma unroll
                for (int dx = 0; dx < 2; ++dx) {
                    int p = dz*4 + dy*2 + dx;
                    acc[cl][p] = fmaf(w0, v[dz+kd][dy+kh][dx+0], acc[cl][p]);
                    acc[cl][p] = fmaf(w1, v[dz+kd][dy+kh][dx+1], acc[cl][p]);
                    acc[cl][p] = fmaf(w2, v[dz+kd][dy+kh][dx+2], acc[cl][p]);
                }
            }
        }
    }

    // bias, pooled max/min, per-channel stat partials
    int ow = tx*8 + pw, oh = ty*8 + ph, od = tz*4 + pd;
    float ssum[CL], ssq[CL];
    size_t obase = ((size_t)n*COUT + co0)*((size_t)PD*PD*PD) + ((size_t)od*PD + oh)*PD + ow;
    #pragma unroll
    for (int cl = 0; cl < CL; ++cl) {
        float cb = bias[co0 + cl];
        float mx = -1e30f, mn = 1e30f, s = 0.f, q = 0.f;
        #pragma unroll
        for (int p = 0; p < 8; ++p) {
            float val = acc[cl][p] + cb;
            mx = fmaxf(mx, val); mn = fminf(mn, val);
            s += val; q = fmaf(val, val, q);
        }
        ssum[cl] = s; ssq[cl] = q;
        outmax[obase + (size_t)cl*(PD*PD*PD)] = mx;
        outmin[obase + (size_t)cl*(PD*PD*PD)] = mn;
    }

    int lane = tid & 63, wid = tid >> 6;
    #pragma unroll
    for (int cl = 0; cl < CL; ++cl) {
        float a_ = ssum[cl], b_ = ssq[cl];
        #pragma unroll
        for (int off = 32; off; off >>= 1) {
            a_ += __shfl_down(a_, off, 64);
            b_ += __shfl_down(b_, off, 64);
        }
        if (lane == 0) { swred[wid*2*CL + cl*2] = a_; swred[wid*2*CL + cl*2 + 1] = b_; }
    }
    __syncthreads();
    if (tid < 2*CL) {
        float t = swred[tid] + swred[2*CL + tid] + swred[4*CL + tid] + swred[6*CL + tid];
        unsafeAtomicAdd(&stats[co0*2 + tid], t);
    }
}

__global__ void bn_final_k(const float* __restrict__ stats, const float* __restrict__ g,
                           const float* __restrict__ b, float* __restrict__ sc, float* __restrict__ sh,
                           int C, float invN)
{
    int c = threadIdx.x; if (c >= C) return;
    float m = stats[c*2] * invN;
    float v = stats[c*2+1] * invN - m*m;
    float s = g[c] * rsqrtf(v + 1e-5f);
    sc[c] = s; sh[c] = b[c] - m*s;
}

__global__ __launch_bounds__(256) void bn_select_k(
    const float* __restrict__ mx, const float* __restrict__ mn,
    const float* __restrict__ sc, const float* __restrict__ sh,
    float* __restrict__ out, int Cmask, int lgPD3, int total)
{
    int idx = blockIdx.x*256 + threadIdx.x;
    if (idx >= total) return;
    int c = (idx >> lgPD3) & Cmask;
    float s = sc[c];
    float v = (s >= 0.f) ? mx[idx] : mn[idx];
    out[idx] = fmaxf(fmaf(v, s, sh[c]), 0.f);
}

// fc: X[16,32768] @ W[32768,128] -> accumulate into feat[:,384:512]
__global__ __launch_bounds__(128) void fc_acc_k(
    const float* __restrict__ X, const float* __restrict__ W, float* __restrict__ featv)
{
    int t = threadIdx.x;
    int k0 = blockIdx.x*256;
    float acc[16];
    #pragma unroll
    for (int b = 0; b < 16; ++b) acc[b] = 0.f;
    for (int k = k0; k < k0 + 256; ++k) {
        float w = W[(size_t)k*128 + t];
        #pragma unroll
        for (int b = 0; b < 16; ++b) acc[b] = fmaf(X[(size_t)b*32768 + k], w, acc[b]);
    }
    for (int b = 0; b < 16; ++b) unsafeAtomicAdd(featv + b*512 + t, acc[b]);
}

// ---------------- small dense layers ----------------
__global__ __launch_bounds__(256) void head_k(
    const float* __restrict__ X, const float* __restrict__ W, const float* __restrict__ b,
    float* __restrict__ O, int K, int Ncol, int relu)
{
    int t = blockIdx.x*256 + threadIdx.x;
    if (t >= 16*Ncol) return;
    int bi = t / Ncol, c = t % Ncol;
    float acc = b[c];
    for (int k = 0; k < K; ++k) acc = fmaf(X[bi*K + k], W[k*Ncol + c], acc);
    if (relu) acc = fmaxf(acc, 0.f);
    O[bi*Ncol + c] = acc;
}

__global__ void gebn_k(const float* __restrict__ g2, const float* __restrict__ g,
                       const float* __restrict__ b, float* __restrict__ featg /* stride 512 */)
{
    int c = threadIdx.x;  // 128
    float m = 0.f;
    for (int i = 0; i < 16; ++i) m += g2[i*128 + c];
    m *= (1.f/16.f);
    float v = 0.f;
    for (int i = 0; i < 16; ++i) { float d = g2[i*128 + c] - m; v += d*d; }
    v *= (1.f/16.f);
    float s = g[c] * rsqrtf(v + 1e-5f);
    for (int i = 0; i < 16; ++i)
        featg[i*512 + c] = fmaxf((g2[i*128 + c] - m)*s + b[c], 0.f);
}

__global__ void finalize_feat_k(float* __restrict__ feat, const float* __restrict__ cntm,
                                const float* __restrict__ cntz, const float* __restrict__ fcb)
{
    int t = blockIdx.x*256 + threadIdx.x;   // 16*512
    if (t >= 8192) return;
    int bi = t >> 9, c = t & 511;
    float v = feat[t];
    if      (c < 128) v /= fmaxf(cntm[bi], 1.f);
    else if (c < 256) v /= fmaxf(cntz[bi], 1.f);
    else if (c >= 384) v = fmaxf(v + fcb[c - 384], 0.f);
    feat[t] = v;
}

// =====================================================================================
extern "C" void kernel_launch(void* const* d_in, const int* in_sizes, int n_in,
                              void* d_out, int out_size, void* d_ws, size_t ws_size,
                              hipStream_t stream)
{
    const int*   mol_x  = (const int*)  d_in[0];
    const float* mol_q  = (const float*)d_in[1];
    const int*   mol_ei = (const int*)  d_in[2];
    const float* mol_ew = (const float*)d_in[3];
    const int*   mol_bv = (const int*)  d_in[4];
    const int*   zeo_x  = (const int*)  d_in[5];
    const int*   zeo_ei = (const int*)  d_in[6];
    const int*   zeo_bv = (const int*)  d_in[7];
    const float* voxel  = (const float*)d_in[8];
    const float* gattr  = (const float*)d_in[9];
    const float* ea  = (const float*)d_in[10];
    const float* ed  = (const float*)d_in[11];
    const float* ec  = (const float*)d_in[12];
    const float* eh  = (const float*)d_in[13];
    const float* ear = (const float*)d_in[14];
    const float* ech = (const float*)d_in[15];
    const float* mc1w=(const float*)d_in[16]; const float* mc1b=(const float*)d_in[17];
    const float* mc2w=(const float*)d_in[18]; const float* mc2b=(const float*)d_in[19];
    const float* zc1w=(const float*)d_in[20]; const float* zc1b=(const float*)d_in[21];
    const float* zc2w=(const float*)d_in[22]; const float* zc2b=(const float*)d_in[23];
    const float* cv1w=(const float*)d_in[24]; const float* cv1b=(const float*)d_in[25];
    const float* bn1g=(const float*)d_in[26]; const float* bn1b=(const float*)d_in[27];
    const float* cv2w=(const float*)d_in[28]; const float* cv2b=(const float*)d_in[29];
    const float* bn2g=(const float*)d_in[30]; const float* bn2b=(const float*)d_in[31];
    const float* cv3w=(const float*)d_in[32]; const float* cv3b=(const float*)d_in[33];
    const float* bn3g=(const float*)d_in[34]; const float* bn3b=(const float*)d_in[35];
    const float* fcw =(const float*)d_in[36]; const float* fcb =(const float*)d_in[37];
    const float* ge1w=(const float*)d_in[38]; const float* ge1b=(const float*)d_in[39];
    const float* ge2w=(const float*)d_in[40]; const float* ge2b=(const float*)d_in[41];
    const float* gbng=(const float*)d_in[42]; const float* gbnb=(const float*)d_in[43];
    const float* h1w =(const float*)d_in[44]; const float* h1b =(const float*)d_in[45];
    const float* h2w =(const float*)d_in[46]; const float* h2b =(const float*)d_in[47];
    const float* h3w =(const float*)d_in[48]; const float* h3b =(const float*)d_in[49];

    const int Nm = in_sizes[0]/6, Em = in_sizes[2]/2;
    const int Nz = in_sizes[5]/6, Ez = in_sizes[6]/2;

    float* WS = (float*)d_ws;
    float* A  = WS;                     // 16,777,216 floats (67 MB)
    float* Bb = WS + 16777216;          // 16,777,216 floats (67 MB)
    float* S  = WS + 33554432;          // small scratch
    float* deg  = S;
    float* dis  = S + 131072;
    float* csr_nrm = S + 262144;        // 524288
    float* T    = S + 786432;           // 161*128
    float* cntm = S + 807040;
    float* cntz = S + 807056;
    float* feat = S + 807072;           // [16][512]
    float* st1  = S + 815264; float* st2 = st1 + 32; float* st3 = st1 + 96;
    float* sc1  = S + 815488; float* sh1 = sc1 + 16;
    float* sc2  = sc1 + 32;   float* sh2 = sc1 + 64;
    float* sc3  = sc1 + 96;   float* sh3 = sc1 + 160;
    float* g1   = S + 815712;           // 16*64
    float* g2   = S + 816736;           // 16*128
    float* H1   = S + 818784;           // 16*512
    float* H2   = S + 826976;           // 16*256
    int* rowptr  = (int*)(S + 831072);  // 131073
    int* cursor  = (int*)(S + 962176);  // 131072
    int* csr_src = (int*)(S + 1093248); // 524288  (ends S+1617536)

    // zero small accumulators (feat/stats/cnt) each replay
    hipMemsetAsync(S, 0, (size_t)831072*sizeof(float), stream);

    // ---------------- molecule branch ----------------
    build_tables_k<<<161,128,0,stream>>>(ea,ed,ec,eh,ear,ech, mc1w, T);
    init_deg_k   <<<Nm/256,256,0,stream>>>(deg, Nm);
    deg_scatter_k<<<Em/256,256,0,stream>>>(mol_ei+Em, mol_ew, deg, Em);
    dis_k        <<<Nm/256,256,0,stream>>>(deg, dis, Nm);
    hipMemsetAsync(cursor, 0, (size_t)Nm*sizeof(int), stream);
    count_in_k   <<<Em/256,256,0,stream>>>(mol_ei+Em, cursor, Em);
    scan_k       <<<1,1024,0,stream>>>(cursor, rowptr, Nm);
    fill_csr_k   <<<Em/256,256,0,stream>>>(mol_ei, mol_ei+Em, mol_ew, dis, cursor, csr_src, csr_nrm, Em);
    embed_lookup_k<<<Nm/8,256,0,stream>>>(mol_x, mol_q, T, mc1w + 112*128, A, Nm);
    gcn_gather_k <<<Nm/8,256,0,stream>>>(A, rowptr, csr_src, csr_nrm, dis, mc1b, Bb, Nm);
    gemm_relu128_k<<<Nm/128,256,0,stream>>>(Bb, mc2w, A, Nm);
    gcn_gather_k <<<Nm/8,256,0,stream>>>(A, rowptr, csr_src, csr_nrm, dis, mc2b, Bb, Nm);
    count_batch_k<<<Nm/256,256,0,stream>>>(mol_bv, cntm, Nm);
    mean_pool_sum_k<<<256,128,0,stream>>>(Bb, mol_bv, feat + 0, (Nm+255)/256, Nm);

    // ---------------- zeolite branch ----------------
    build_tables_k<<<161,128,0,stream>>>(ea,ed,ec,eh,ear,ech, zc1w, T);
    init_deg_k   <<<Nz/256,256,0,stream>>>(deg, Nz);
    deg_scatter_k<<<Ez/256,256,0,stream>>>(zeo_ei+Ez, nullptr, deg, Ez);
    dis_k        <<<Nz/256,256,0,stream>>>(deg, dis, Nz);
    hipMemsetAsync(cursor, 0, (size_t)Nz*sizeof(int), stream);
    count_in_k   <<<Ez/256,256,0,stream>>>(zeo_ei+Ez, cursor, Ez);
    scan_k       <<<1,1024,0,stream>>>(cursor, rowptr, Nz);
    fill_csr_k   <<<Ez/256,256,0,stream>>>(zeo_ei, zeo_ei+Ez, nullptr, dis, cursor, csr_src, csr_nrm, Ez);
    embed_lookup_k<<<Nz/8,256,0,stream>>>(zeo_x, nullptr, T, nullptr, A, Nz);
    gcn_gather_k <<<Nz/8,256,0,stream>>>(A, rowptr, csr_src, csr_nrm, dis, zc1b, Bb, Nz);
    gemm_relu128_k<<<Nz/128,256,0,stream>>>(Bb, zc2w, A, Nz);
    gcn_gather_k <<<Nz/8,256,0,stream>>>(A, rowptr, csr_src, csr_nrm, dis, zc2b, Bb, Nz);
    count_batch_k<<<Nz/256,256,0,stream>>>(zeo_bv, cntz, Nz);
    mean_pool_sum_k<<<256,128,0,stream>>>(Bb, zeo_bv, feat + 128, (Nz+255)/256, Nz);

    // ---------------- voxel CNN (LDS-tiled fused conv; prev-layer BN fused into staging) ----
    // layer 1: voxel [16][2][64^3] -> max/min pooled [16][16][32^3] in A halves
    conv_pool3_k<2,16,64,8,false><<<dim3(128,2,16),256,0,stream>>>(
        voxel, nullptr, nullptr, nullptr, cv1w, cv1b, A, A+8388608, st1);
    bn_final_k<<<1,64,0,stream>>>(st1, bn1g, bn1b, sc1, sh1, 16, 1.f/(16.f*262144.f));

    // layer 2: (BN1 fused on stage) -> max/min pooled [16][32][16^3] in Bb halves
    conv_pool3_k<16,32,32,8,true><<<dim3(16,4,16),256,0,stream>>>(
        A, A+8388608, sc1, sh1, cv2w, cv2b, Bb, Bb+2097152, st2);
    bn_final_k<<<1,64,0,stream>>>(st2, bn2g, bn2b, sc2, sh2, 32, 1.f/(16.f*32768.f));

    // layer 3: (BN2 fused on stage) -> max/min pooled [16][64][8^3] in A halves
    conv_pool3_k<32,64,16,4,true><<<dim3(2,16,16),256,0,stream>>>(
        Bb, Bb+2097152, sc2, sh2, cv3w, cv3b, A, A+524288, st3);
    bn_final_k<<<1,64,0,stream>>>(st3, bn3g, bn3b, sc3, sh3, 64, 1.f/(16.f*4096.f));
    bn_select_k<<<2048,256,0,stream>>>(A, A+524288, sc3, sh3, Bb, 63, 9, 524288);

    fc_acc_k<<<128,128,0,stream>>>(Bb, fcw, feat + 384);

    // ---------------- global encoder ----------------
    head_k<<<4,256,0,stream>>>(gattr, ge1w, ge1b, g1, 17, 64, 1);
    head_k<<<8,256,0,stream>>>(g1, ge2w, ge2b, g2, 64, 128, 0);
    gebn_k<<<1,128,0,stream>>>(g2, gbng, gbnb, feat + 256);

    // ---------------- fusion head ----------------
    finalize_feat_k<<<32,256,0,stream>>>(feat, cntm, cntz, fcb);
    head_k<<<32,256,0,stream>>>(feat, h1w, h1b, H1, 512, 512, 1);
    head_k<<<16,256,0,stream>>>(H1, h2w, h2b, H2, 512, 256, 1);
    head_k<<<1,256,0,stream>>>(H2, h3w, h3b, (float*)d_out, 256, 3, 0);
}

// Round 7
// 2585.606 us; speedup vs baseline: 1.0797x; 1.0073x over previous
//
#include <hip/hip_runtime.h>
#include <math.h>

#define DEV static __device__ __forceinline__

DEV float4 ld4(const float* p){ return *(const float4*)p; }
DEV float2 ld2(const float* p){ return *(const float2*)p; }
DEV void   st4(float* p, float4 v){ *(float4*)p = v; }
DEV float4 f4add(float4 a, float4 b){ return make_float4(a.x+b.x,a.y+b.y,a.z+b.z,a.w+b.w); }
DEV float4 f4fma(float s, float4 a, float4 c){ return make_float4(fmaf(s,a.x,c.x),fmaf(s,a.y,c.y),fmaf(s,a.z,c.z),fmaf(s,a.w,c.w)); }
DEV float4 f4relu(float4 a){ return make_float4(fmaxf(a.x,0.f),fmaxf(a.y,0.f),fmaxf(a.z,0.f),fmaxf(a.w,0.f)); }

// ---------------- GNN: embedding tables  T[161][128] = emb_f @ W_slice ----------------
__global__ __launch_bounds__(128) void build_tables_k(
    const float* __restrict__ ea, const float* __restrict__ ed, const float* __restrict__ ec,
    const float* __restrict__ eh, const float* __restrict__ ear, const float* __restrict__ ech,
    const float* __restrict__ Wm, float* __restrict__ T)
{
    int r = blockIdx.x, c = threadIdx.x;
    const float* e; int dim, woff, rl;
    if      (r < 120) { e=ea;  dim=64; woff=0;   rl=r; }
    else if (r < 132) { e=ed;  dim=16; woff=64;  rl=r-120; }
    else if (r < 147) { e=ec;  dim=16; woff=80;  rl=r-132; }
    else if (r < 155) { e=eh;  dim=8;  woff=96;  rl=r-147; }
    else if (r < 157) { e=ear; dim=4;  woff=104; rl=r-155; }
    else              { e=ech; dim=4;  woff=108; rl=r-157; }
    float acc = 0.f;
    for (int k = 0; k < dim; ++k) acc += e[rl*dim + k] * Wm[(woff + k)*128 + c];
    T[r*128 + c] = acc;
}

// H[i][:] = sum of 6 table rows (+ charge * Wrow112)
__global__ __launch_bounds__(256) void embed_lookup_k(
    const int* __restrict__ xi, const float* __restrict__ charge,
    const float* __restrict__ T, const float* __restrict__ wq,
    float* __restrict__ H, int N)
{
    int t = threadIdx.x;
    int node = blockIdx.x*8 + (t >> 5);
    if (node >= N) return;
    int c = (t & 31)*4;
    const int* xp = xi + node*6;
    float4 acc = ld4(T + (       xp[0])*128 + c);
    acc = f4add(acc, ld4(T + (120+xp[1])*128 + c));
    acc = f4add(acc, ld4(T + (132+xp[2])*128 + c));
    acc = f4add(acc, ld4(T + (147+xp[3])*128 + c));
    acc = f4add(acc, ld4(T + (155+xp[4])*128 + c));
    acc = f4add(acc, ld4(T + (157+xp[5])*128 + c));
    if (charge) acc = f4fma(charge[node], ld4(wq + c), acc);
    st4(H + (size_t)node*128 + c, acc);
}

// ---------------- GCN degree / norm / CSR build ----------------
__global__ void init_deg_k(float* deg, int N){ int i = blockIdx.x*256+threadIdx.x; if (i<N) deg[i]=1.f; }

__global__ void deg_scatter_k(const int* __restrict__ col, const float* __restrict__ ew, float* deg, int E){
    int e = blockIdx.x*256+threadIdx.x; if (e>=E) return;
    unsafeAtomicAdd(deg + col[e], ew ? ew[e] : 1.f);
}

__global__ void dis_k(const float* __restrict__ deg, float* __restrict__ dis, int N){
    int i = blockIdx.x*256+threadIdx.x; if (i<N) dis[i] = 1.f/sqrtf(deg[i]);
}

// integer in-degree count (into cursor buffer, pre-zeroed)
__global__ void count_in_k(const int* __restrict__ col, int* __restrict__ cnt, int E){
    int e = blockIdx.x*256+threadIdx.x; if (e>=E) return;
    atomicAdd(&cnt[col[e]], 1);
}

// single-block exclusive scan: cnt (in cursor) -> rowptr; cursor reset to starts
__global__ __launch_bounds__(1024) void scan_k(int* __restrict__ cnt_cursor, int* __restrict__ rowptr, int N)
{
    __shared__ int part[1024];
    int t = threadIdx.x;
    int chunk = (N + 1023) >> 10;
    int base = t*chunk;
    int s = 0;
    for (int i = 0; i < chunk; ++i) { int idx = base+i; if (idx < N) s += cnt_cursor[idx]; }
    part[t] = s;
    __syncthreads();
    for (int off = 1; off < 1024; off <<= 1) {
        int v = (t >= off) ? part[t-off] : 0;
        __syncthreads();
        if (t >= off) part[t] += v;
        __syncthreads();
    }
    int run = (t == 0) ? 0 : part[t-1];
    for (int i = 0; i < chunk; ++i) {
        int idx = base+i; if (idx >= N) break;
        int c = cnt_cursor[idx];
        rowptr[idx] = run;
        cnt_cursor[idx] = run;   // cursor = start
        run += c;
    }
    if (t == 1023) rowptr[N] = part[1023];
}

// scatter edges into CSR slots; norm computed inline
__global__ void fill_csr_k(const int* __restrict__ row, const int* __restrict__ col,
                           const float* __restrict__ ew, const float* __restrict__ dis,
                           int* __restrict__ cursor, int* __restrict__ csr_src,
                           float* __restrict__ csr_nrm, int E)
{
    int e = blockIdx.x*256+threadIdx.x; if (e>=E) return;
    int r = row[e], c = col[e];
    int pos = atomicAdd(&cursor[c], 1);
    csr_src[pos] = r;
    csr_nrm[pos] = dis[r] * (ew ? ew[e] : 1.f) * dis[c];
}

// O[i] = bias + dis[i]^2 * H[i] + sum_j nrm_j * H[src_j]
// 32 lanes/node (float4), 8 nodes/block, unroll-4 for memory-level parallelism
__global__ __launch_bounds__(256) void gcn_gather_k(
    const float* __restrict__ H, const int* __restrict__ rowptr,
    const int* __restrict__ csr_src, const float* __restrict__ csr_nrm,
    const float* __restrict__ dis, const float* __restrict__ bias,
    float* __restrict__ O, int N)
{
    int node = blockIdx.x*8 + (threadIdx.x >> 5);
    if (node >= N) return;
    int lane = (threadIdx.x & 31)*4;
    float s = dis[node]; s *= s;
    float4 h = ld4(H + (size_t)node*128 + lane);
    float4 b = ld4(bias + lane);
    float4 acc = f4fma(s, h, b);
    int j = rowptr[node], end = rowptr[node+1];
    for (; j + 4 <= end; j += 4) {
        int   s0 = csr_src[j],   s1 = csr_src[j+1], s2 = csr_src[j+2], s3 = csr_src[j+3];
        float n0 = csr_nrm[j],   n1 = csr_nrm[j+1], n2 = csr_nrm[j+2], n3 = csr_nrm[j+3];
        float4 h0 = ld4(H + (size_t)s0*128 + lane);
        float4 h1 = ld4(H + (size_t)s1*128 + lane);
        float4 h2 = ld4(H + (size_t)s2*128 + lane);
        float4 h3 = ld4(H + (size_t)s3*128 + lane);
        acc = f4fma(n0, h0, acc);
        acc = f4fma(n1, h1, acc);
        acc = f4fma(n2, h2, acc);
        acc = f4fma(n3, h3, acc);
    }
    for (; j < end; ++j) {
        float4 h0 = ld4(H + (size_t)csr_src[j]*128 + lane);
        acc = f4fma(csr_nrm[j], h0, acc);
    }
    st4(O + (size_t)node*128 + lane, acc);
}

// O = relu(A) @ W ; A:[N,128] W:[128,128]
__global__ __launch_bounds__(256) void gemm_relu128_k(
    const float* __restrict__ A, const float* __restrict__ W, float* __restrict__ O, int N)
{
    __shared__ float As[128*128];
    int t = threadIdx.x;
    int row0 = blockIdx.x * 128;
    int r = t >> 1, c0 = (t & 1)*64;
    for (int i = 0; i < 16; ++i) {
        float4 v = ld4(A + (size_t)(row0 + r)*128 + c0 + i*4);
        st4(As + r*128 + c0 + i*4, f4relu(v));
    }
    __syncthreads();
    int rg = (t >> 5)*16;
    int c  = (t & 31)*4;
    float4 acc[16];
    for (int i = 0; i < 16; ++i) acc[i] = make_float4(0.f,0.f,0.f,0.f);
    for (int k = 0; k < 128; ++k) {
        float4 w = ld4(W + k*128 + c);
        #pragma unroll
        for (int rr = 0; rr < 16; ++rr) {
            float a = As[(rg + rr)*128 + k];
            acc[rr] = f4fma(a, w, acc[rr]);
        }
    }
    for (int rr = 0; rr < 16; ++rr)
        st4(O + (size_t)(row0 + rg + rr)*128 + c, acc[rr]);
}

// ---------------- mean pool ----------------
__global__ __launch_bounds__(128) void mean_pool_sum_k(
    const float* __restrict__ X, const int* __restrict__ bv,
    float* __restrict__ featp /* stride 512 */, int chunk, int N)
{
    __shared__ float acc[16*128];
    int t = threadIdx.x;
    for (int b = 0; b < 16; ++b) acc[b*128 + t] = 0.f;
    int i0 = blockIdx.x * chunk;
    int iend = min(i0 + chunk, N);
    int bcur = bv[i0];
    float r = 0.f;
    for (int i = i0; i < iend; ++i) {
        int b = bv[i];
        if (b != bcur) { acc[bcur*128 + t] += r; r = 0.f; bcur = b; }
        r += fmaxf(X[(size_t)i*128 + t], 0.f);
    }
    acc[bcur*128 + t] += r;
    for (int b = 0; b < 16; ++b) {
        float v = acc[b*128 + t];
        if (v != 0.f) unsafeAtomicAdd(featp + b*512 + t, v);
    }
}

__global__ void count_batch_k(const int* __restrict__ bv, float* __restrict__ cnt, int N){
    __shared__ int h[16];
    int t = threadIdx.x;
    if (t < 16) h[t] = 0;
    __syncthreads();
    int i = blockIdx.x*256 + t;
    if (i < N) atomicAdd(&h[bv[i]], 1);
    __syncthreads();
    if (t < 16 && h[t]) unsafeAtomicAdd(&cnt[t], (float)h[t]);
}

// ---------------- voxel CNN: LDS-tiled conv(3x3x3 SAME)+bias+BN-stats+max/min-pool -------
// Block: 256 threads = 8x8x4 pooled positions; CL output channels per thread.
// Weights: block-uniform -> SGPR s_load. Input tile: 18x18x10 halo in LDS.
// Compute: kernel-row r OUTER loop; per r only a 2x2x4 LDS slice (16 regs) is live,
// so acc[CL][8] + slice fits in registers with no spill/re-read at CL=8.
template<int CIN, int COUT, int D, int CL, bool BNIN>
__global__ __launch_bounds__(256) void conv_pool4_k(
    const float* __restrict__ inmax, const float* __restrict__ inmin,
    const float* __restrict__ scin, const float* __restrict__ shin,
    const float* __restrict__ wt, const float* __restrict__ bias,
    float* __restrict__ outmax, float* __restrict__ outmin, float* __restrict__ stats)
{
    constexpr int PD = D/2;
    constexpr int NTX = (PD >= 8) ? PD/8 : 1;
    constexpr int SY = 20, SZ = 20*18;
    __shared__ float tileL[10*SZ];                 // 3600 floats
    __shared__ float swred[4*2*CL];

    int tid = threadIdx.x;
    int co0 = blockIdx.y * CL;
    int n   = blockIdx.z;

    int tb = blockIdx.x;
    int tx = tb % NTX, ty = (tb / NTX) % NTX, tz = tb / (NTX*NTX);
    int pw = tid & 7, ph = (tid >> 3) & 7, pd = tid >> 6;   // pooled coords in tile
    int ix0 = tx*16 - 1, iy0 = ty*16 - 1, iz0 = tz*8 - 1;

    // staging coordinates (324 slots per z-slice; 2 passes of 256)
    int sy0 = tid / 18, sx0 = tid - sy0*18;
    int sp1 = tid + 256;
    int sy1 = sp1 / 18, sx1 = sp1 - sy1*18;
    bool has1 = (sp1 < 324);

    float acc[CL][8];
    #pragma unroll
    for (int cl = 0; cl < CL; ++cl)
        #pragma unroll
        for (int p = 0; p < 8; ++p) acc[cl][p] = 0.f;

    int base = (2*pd)*SZ + (2*ph)*SY + 2*pw;

    for (int ci = 0; ci < CIN; ++ci) {
        __syncthreads();   // tile consumed (prev iter)
        float s_in = 0.f, sh_in = 0.f;
        if (BNIN) { s_in = scin[ci]; sh_in = shin[ci]; }
        const float* ib;
        if (BNIN) ib = (s_in >= 0.f) ? inmax + ((size_t)(n*CIN + ci))*((size_t)D*D*D)
                                     : inmin + ((size_t)(n*CIN + ci))*((size_t)D*D*D);
        else      ib = inmax + ((size_t)(n*CIN + ci))*((size_t)D*D*D);

        #pragma unroll 2
        for (int z = 0; z < 10; ++z) {
            int gz = iz0 + z; bool zok = (unsigned)gz < (unsigned)D;
            {
                int gy = iy0 + sy0, gx = ix0 + sx0;
                float val = 0.f;
                if (zok && (unsigned)gy < (unsigned)D && (unsigned)gx < (unsigned)D) {
                    float v = ib[((size_t)gz*D + gy)*D + gx];
                    val = BNIN ? fmaxf(fmaf(v, s_in, sh_in), 0.f) : v;
                }
                tileL[z*SZ + sy0*SY + sx0] = val;
            }
            if (has1) {
                int gy = iy0 + sy1, gx = ix0 + sx1;
                float val = 0.f;
                if (zok && (unsigned)gy < (unsigned)D && (unsigned)gx < (unsigned)D) {
                    float v = ib[((size_t)gz*D + gy)*D + gx];
                    val = BNIN ? fmaxf(fmaf(v, s_in, sh_in), 0.f) : v;
                }
                tileL[z*SZ + sy1*SY + sx1] = val;
            }
        }
        __syncthreads();   // tile ready

        const float* wb = wt + ((size_t)co0*CIN + ci)*27;   // uniform -> s_load
        #pragma unroll
        for (int r = 0; r < 9; ++r) {
            const int kd = r/3, kh = r%3;
            float vv[2][2][4];
            #pragma unroll
            for (int dz = 0; dz < 2; ++dz)
            #pragma unroll
            for (int dy = 0; dy < 2; ++dy) {
                const float* rp = &tileL[base + (dz+kd)*SZ + (dy+kh)*SY];
                float2 p0 = ld2(rp), p1 = ld2(rp+2);
                vv[dz][dy][0]=p0.x; vv[dz][dy][1]=p0.y; vv[dz][dy][2]=p1.x; vv[dz][dy][3]=p1.y;
            }
            #pragma unroll
            for (int cl = 0; cl < CL; ++cl) {
                const float* wc = wb + (size_t)cl*CIN*27 + r*3;
                float w0 = wc[0], w1 = wc[1], w2 = wc[2];
                #pragma unroll
                for (int dz = 0; dz < 2; ++dz)
                #pragma unroll
                for (int dy = 0; dy < 2; ++dy)
                #pragma unroll
                for (int dx = 0; dx < 2; ++dx) {
                    int p = dz*4 + dy*2 + dx;
                    acc[cl][p] = fmaf(w0, vv[dz][dy][dx+0], acc[cl][p]);
                    acc[cl][p] = fmaf(w1, vv[dz][dy][dx+1], acc[cl][p]);
                    acc[cl][p] = fmaf(w2, vv[dz][dy][dx+2], acc[cl][p]);
                }
            }
        }
    }

    // bias, pooled max/min, per-channel stat partials
    int ow = tx*8 + pw, oh = ty*8 + ph, od = tz*4 + pd;
    float ssum[CL], ssq[CL];
    size_t obase = ((size_t)n*COUT + co0)*((size_t)PD*PD*PD) + ((size_t)od*PD + oh)*PD + ow;
    #pragma unroll
    for (int cl = 0; cl < CL; ++cl) {
        float cb = bias[co0 + cl];
        float mx = -1e30f, mn = 1e30f, s = 0.f, q = 0.f;
        #pragma unroll
        for (int p = 0; p < 8; ++p) {
            float val = acc[cl][p] + cb;
            mx = fmaxf(mx, val); mn = fminf(mn, val);
            s += val; q = fmaf(val, val, q);
        }
        ssum[cl] = s; ssq[cl] = q;
        outmax[obase + (size_t)cl*(PD*PD*PD)] = mx;
        outmin[obase + (size_t)cl*(PD*PD*PD)] = mn;
    }

    int lane = tid & 63, wid = tid >> 6;
    #pragma unroll
    for (int cl = 0; cl < CL; ++cl) {
        float a_ = ssum[cl], b_ = ssq[cl];
        #pragma unroll
        for (int off = 32; off; off >>= 1) {
            a_ += __shfl_down(a_, off, 64);
            b_ += __shfl_down(b_, off, 64);
        }
        if (lane == 0) { swred[wid*2*CL + cl*2] = a_; swred[wid*2*CL + cl*2 + 1] = b_; }
    }
    __syncthreads();
    if (tid < 2*CL) {
        float t = swred[tid] + swred[2*CL + tid] + swred[4*CL + tid] + swred[6*CL + tid];
        unsafeAtomicAdd(&stats[co0*2 + tid], t);
    }
}

__global__ void bn_final_k(const float* __restrict__ stats, const float* __restrict__ g,
                           const float* __restrict__ b, float* __restrict__ sc, float* __restrict__ sh,
                           int C, float invN)
{
    int c = threadIdx.x; if (c >= C) return;
    float m = stats[c*2] * invN;
    float v = stats[c*2+1] * invN - m*m;
    float s = g[c] * rsqrtf(v + 1e-5f);
    sc[c] = s; sh[c] = b[c] - m*s;
}

__global__ __launch_bounds__(256) void bn_select_k(
    const float* __restrict__ mx, const float* __restrict__ mn,
    const float* __restrict__ sc, const float* __restrict__ sh,
    float* __restrict__ out, int Cmask, int lgPD3, int total)
{
    int idx = blockIdx.x*256 + threadIdx.x;
    if (idx >= total) return;
    int c = (idx >> lgPD3) & Cmask;
    float s = sc[c];
    float v = (s >= 0.f) ? mx[idx] : mn[idx];
    out[idx] = fmaxf(fmaf(v, s, sh[c]), 0.f);
}

// fc: X[16,32768] @ W[32768,128] -> accumulate into feat[:,384:512]
__global__ __launch_bounds__(128) void fc_acc_k(
    const float* __restrict__ X, const float* __restrict__ W, float* __restrict__ featv)
{
    int t = threadIdx.x;
    int k0 = blockIdx.x*256;
    float acc[16];
    #pragma unroll
    for (int b = 0; b < 16; ++b) acc[b] = 0.f;
    for (int k = k0; k < k0 + 256; ++k) {
        float w = W[(size_t)k*128 + t];
        #pragma unroll
        for (int b = 0; b < 16; ++b) acc[b] = fmaf(X[(size_t)b*32768 + k], w, acc[b]);
    }
    for (int b = 0; b < 16; ++b) unsafeAtomicAdd(featv + b*512 + t, acc[b]);
}

// ---------------- small dense layers ----------------
__global__ __launch_bounds__(256) void head_k(
    const float* __restrict__ X, const float* __restrict__ W, const float* __restrict__ b,
    float* __restrict__ O, int K, int Ncol, int relu)
{
    int t = blockIdx.x*256 + threadIdx.x;
    if (t >= 16*Ncol) return;
    int bi = t / Ncol, c = t % Ncol;
    float acc = b[c];
    for (int k = 0; k < K; ++k) acc = fmaf(X[bi*K + k], W[k*Ncol + c], acc);
    if (relu) acc = fmaxf(acc, 0.f);
    O[bi*Ncol + c] = acc;
}

__global__ void gebn_k(const float* __restrict__ g2, const float* __restrict__ g,
                       const float* __restrict__ b, float* __restrict__ featg /* stride 512 */)
{
    int c = threadIdx.x;  // 128
    float m = 0.f;
    for (int i = 0; i < 16; ++i) m += g2[i*128 + c];
    m *= (1.f/16.f);
    float v = 0.f;
    for (int i = 0; i < 16; ++i) { float d = g2[i*128 + c] - m; v += d*d; }
    v *= (1.f/16.f);
    float s = g[c] * rsqrtf(v + 1e-5f);
    for (int i = 0; i < 16; ++i)
        featg[i*512 + c] = fmaxf((g2[i*128 + c] - m)*s + b[c], 0.f);
}

__global__ void finalize_feat_k(float* __restrict__ feat, const float* __restrict__ cntm,
                                const float* __restrict__ cntz, const float* __restrict__ fcb)
{
    int t = blockIdx.x*256 + threadIdx.x;   // 16*512
    if (t >= 8192) return;
    int bi = t >> 9, c = t & 511;
    float v = feat[t];
    if      (c < 128) v /= fmaxf(cntm[bi], 1.f);
    else if (c < 256) v /= fmaxf(cntz[bi], 1.f);
    else if (c >= 384) v = fmaxf(v + fcb[c - 384], 0.f);
    feat[t] = v;
}

// =====================================================================================
extern "C" void kernel_launch(void* const* d_in, const int* in_sizes, int n_in,
                              void* d_out, int out_size, void* d_ws, size_t ws_size,
                              hipStream_t stream)
{
    const int*   mol_x  = (const int*)  d_in[0];
    const float* mol_q  = (const float*)d_in[1];
    const int*   mol_ei = (const int*)  d_in[2];
    const float* mol_ew = (const float*)d_in[3];
    const int*   mol_bv = (const int*)  d_in[4];
    const int*   zeo_x  = (const int*)  d_in[5];
    const int*   zeo_ei = (const int*)  d_in[6];
    const int*   zeo_bv = (const int*)  d_in[7];
    const float* voxel  = (const float*)d_in[8];
    const float* gattr  = (const float*)d_in[9];
    const float* ea  = (const float*)d_in[10];
    const float* ed  = (const float*)d_in[11];
    const float* ec  = (const float*)d_in[12];
    const float* eh  = (const float*)d_in[13];
    const float* ear = (const float*)d_in[14];
    const float* ech = (const float*)d_in[15];
    const float* mc1w=(const float*)d_in[16]; const float* mc1b=(const float*)d_in[17];
    const float* mc2w=(const float*)d_in[18]; const float* mc2b=(const float*)d_in[19];
    const float* zc1w=(const float*)d_in[20]; const float* zc1b=(const float*)d_in[21];
    const float* zc2w=(const float*)d_in[22]; const float* zc2b=(const float*)d_in[23];
    const float* cv1w=(const float*)d_in[24]; const float* cv1b=(const float*)d_in[25];
    const float* bn1g=(const float*)d_in[26]; const float* bn1b=(const float*)d_in[27];
    const float* cv2w=(const float*)d_in[28]; const float* cv2b=(const float*)d_in[29];
    const float* bn2g=(const float*)d_in[30]; const float* bn2b=(const float*)d_in[31];
    const float* cv3w=(const float*)d_in[32]; const float* cv3b=(const float*)d_in[33];
    const float* bn3g=(const float*)d_in[34]; const float* bn3b=(const float*)d_in[35];
    const float* fcw =(const float*)d_in[36]; const float* fcb =(const float*)d_in[37];
    const float* ge1w=(const float*)d_in[38]; const float* ge1b=(const float*)d_in[39];
    const float* ge2w=(const float*)d_in[40]; const float* ge2b=(const float*)d_in[41];
    const float* gbng=(const float*)d_in[42]; const float* gbnb=(const float*)d_in[43];
    const float* h1w =(const float*)d_in[44]; const float* h1b =(const float*)d_in[45];
    const float* h2w =(const float*)d_in[46]; const float* h2b =(const float*)d_in[47];
    const float* h3w =(const float*)d_in[48]; const float* h3b =(const float*)d_in[49];

    const int Nm = in_sizes[0]/6, Em = in_sizes[2]/2;
    const int Nz = in_sizes[5]/6, Ez = in_sizes[6]/2;

    float* WS = (float*)d_ws;
    float* A  = WS;                     // 16,777,216 floats (67 MB)
    float* Bb = WS + 16777216;          // 16,777,216 floats (67 MB)
    float* S  = WS + 33554432;          // small scratch
    float* deg  = S;
    float* dis  = S + 131072;
    float* csr_nrm = S + 262144;        // 524288
    float* T    = S + 786432;           // 161*128
    float* cntm = S + 807040;
    float* cntz = S + 807056;
    float* feat = S + 807072;           // [16][512]
    float* st1  = S + 815264; float* st2 = st1 + 32; float* st3 = st1 + 96;
    float* sc1  = S + 815488; float* sh1 = sc1 + 16;
    float* sc2  = sc1 + 32;   float* sh2 = sc1 + 64;
    float* sc3  = sc1 + 96;   float* sh3 = sc1 + 160;
    float* g1   = S + 815712;           // 16*64
    float* g2   = S + 816736;           // 16*128
    float* H1   = S + 818784;           // 16*512
    float* H2   = S + 826976;           // 16*256
    int* rowptr  = (int*)(S + 831072);  // 131073
    int* cursor  = (int*)(S + 962176);  // 131072
    int* csr_src = (int*)(S + 1093248); // 524288  (ends S+1617536)

    // zero small accumulators (feat/stats/cnt) each replay
    hipMemsetAsync(S, 0, (size_t)831072*sizeof(float), stream);

    // ---------------- molecule branch ----------------
    build_tables_k<<<161,128,0,stream>>>(ea,ed,ec,eh,ear,ech, mc1w, T);
    init_deg_k   <<<Nm/256,256,0,stream>>>(deg, Nm);
    deg_scatter_k<<<Em/256,256,0,stream>>>(mol_ei+Em, mol_ew, deg, Em);
    dis_k        <<<Nm/256,256,0,stream>>>(deg, dis, Nm);
    hipMemsetAsync(cursor, 0, (size_t)Nm*sizeof(int), stream);
    count_in_k   <<<Em/256,256,0,stream>>>(mol_ei+Em, cursor, Em);
    scan_k       <<<1,1024,0,stream>>>(cursor, rowptr, Nm);
    fill_csr_k   <<<Em/256,256,0,stream>>>(mol_ei, mol_ei+Em, mol_ew, dis, cursor, csr_src, csr_nrm, Em);
    embed_lookup_k<<<Nm/8,256,0,stream>>>(mol_x, mol_q, T, mc1w + 112*128, A, Nm);
    gcn_gather_k <<<Nm/8,256,0,stream>>>(A, rowptr, csr_src, csr_nrm, dis, mc1b, Bb, Nm);
    gemm_relu128_k<<<Nm/128,256,0,stream>>>(Bb, mc2w, A, Nm);
    gcn_gather_k <<<Nm/8,256,0,stream>>>(A, rowptr, csr_src, csr_nrm, dis, mc2b, Bb, Nm);
    count_batch_k<<<Nm/256,256,0,stream>>>(mol_bv, cntm, Nm);
    mean_pool_sum_k<<<256,128,0,stream>>>(Bb, mol_bv, feat + 0, (Nm+255)/256, Nm);

    // ---------------- zeolite branch ----------------
    build_tables_k<<<161,128,0,stream>>>(ea,ed,ec,eh,ear,ech, zc1w, T);
    init_deg_k   <<<Nz/256,256,0,stream>>>(deg, Nz);
    deg_scatter_k<<<Ez/256,256,0,stream>>>(zeo_ei+Ez, nullptr, deg, Ez);
    dis_k        <<<Nz/256,256,0,stream>>>(deg, dis, Nz);
    hipMemsetAsync(cursor, 0, (size_t)Nz*sizeof(int), stream);
    count_in_k   <<<Ez/256,256,0,stream>>>(zeo_ei+Ez, cursor, Ez);
    scan_k       <<<1,1024,0,stream>>>(cursor, rowptr, Nz);
    fill_csr_k   <<<Ez/256,256,0,stream>>>(zeo_ei, zeo_ei+Ez, nullptr, dis, cursor, csr_src, csr_nrm, Ez);
    embed_lookup_k<<<Nz/8,256,0,stream>>>(zeo_x, nullptr, T, nullptr, A, Nz);
    gcn_gather_k <<<Nz/8,256,0,stream>>>(A, rowptr, csr_src, csr_nrm, dis, zc1b, Bb, Nz);
    gemm_relu128_k<<<Nz/128,256,0,stream>>>(Bb, zc2w, A, Nz);
    gcn_gather_k <<<Nz/8,256,0,stream>>>(A, rowptr, csr_src, csr_nrm, dis, zc2b, Bb, Nz);
    count_batch_k<<<Nz/256,256,0,stream>>>(zeo_bv, cntz, Nz);
    mean_pool_sum_k<<<256,128,0,stream>>>(Bb, zeo_bv, feat + 128, (Nz+255)/256, Nz);

    // ---------------- voxel CNN (LDS-tiled fused conv; prev-layer BN fused into staging) ----
    // layer 1: voxel [16][2][64^3] -> max/min pooled [16][16][32^3] in A halves
    conv_pool4_k<2,16,64,8,false><<<dim3(128,2,16),256,0,stream>>>(
        voxel, nullptr, nullptr, nullptr, cv1w, cv1b, A, A+8388608, st1);
    bn_final_k<<<1,64,0,stream>>>(st1, bn1g, bn1b, sc1, sh1, 16, 1.f/(16.f*262144.f));

    // layer 2: (BN1 fused on stage) -> max/min pooled [16][32][16^3] in Bb halves
    conv_pool4_k<16,32,32,8,true><<<dim3(16,4,16),256,0,stream>>>(
        A, A+8388608, sc1, sh1, cv2w, cv2b, Bb, Bb+2097152, st2);
    bn_final_k<<<1,64,0,stream>>>(st2, bn2g, bn2b, sc2, sh2, 32, 1.f/(16.f*32768.f));

    // layer 3: (BN2 fused on stage) -> max/min pooled [16][64][8^3] in A halves
    conv_pool4_k<32,64,16,4,true><<<dim3(2,16,16),256,0,stream>>>(
        Bb, Bb+2097152, sc2, sh2, cv3w, cv3b, A, A+524288, st3);
    bn_final_k<<<1,64,0,stream>>>(st3, bn3g, bn3b, sc3, sh3, 64, 1.f/(16.f*4096.f));
    bn_select_k<<<2048,256,0,stream>>>(A, A+524288, sc3, sh3, Bb, 63, 9, 524288);

    fc_acc_k<<<128,128,0,stream>>>(Bb, fcw, feat + 384);

    // ---------------- global encoder ----------------
    head_k<<<4,256,0,stream>>>(gattr, ge1w, ge1b, g1, 17, 64, 1);
    head_k<<<8,256,0,stream>>>(g1, ge2w, ge2b, g2, 64, 128, 0);
    gebn_k<<<1,128,0,stream>>>(g2, gbng, gbnb, feat + 256);

    // ---------------- fusion head ----------------
    finalize_feat_k<<<32,256,0,stream>>>(feat, cntm, cntz, fcb);
    head_k<<<32,256,0,stream>>>(feat, h1w, h1b, H1, 512, 512, 1);
    head_k<<<16,256,0,stream>>>(H1, h2w, h2b, H2, 512, 256, 1);
    head_k<<<1,256,0,stream>>>(H2, h3w, h3b, (float*)d_out, 256, 3, 0);
}

// Round 8
// 2463.185 us; speedup vs baseline: 1.1334x; 1.0497x over previous
//
#include <hip/hip_runtime.h>
#include <math.h>

#define DEV static __device__ __forceinline__

DEV float4 ld4(const float* p){ return *(const float4*)p; }
DEV float2 ld2(const float* p){ return *(const float2*)p; }
DEV void   st4(float* p, float4 v){ *(float4*)p = v; }
DEV float4 f4add(float4 a, float4 b){ return make_float4(a.x+b.x,a.y+b.y,a.z+b.z,a.w+b.w); }
DEV float4 f4fma(float s, float4 a, float4 c){ return make_float4(fmaf(s,a.x,c.x),fmaf(s,a.y,c.y),fmaf(s,a.z,c.z),fmaf(s,a.w,c.w)); }
DEV float4 f4relu(float4 a){ return make_float4(fmaxf(a.x,0.f),fmaxf(a.y,0.f),fmaxf(a.z,0.f),fmaxf(a.w,0.f)); }

// bf16 helpers (RNE pack, exact unpack)
DEV float  b2f(ushort u){ return __uint_as_float(((unsigned)u) << 16); }
DEV ushort f2b(float f){
    unsigned u = __float_as_uint(f);
    return (ushort)((u + 0x7FFFu + ((u >> 16) & 1u)) >> 16);
}
DEV float4 b2f4(ushort4 v){ return make_float4(b2f(v.x), b2f(v.y), b2f(v.z), b2f(v.w)); }
DEV ushort4 f2b4(float4 v){ ushort4 o; o.x=f2b(v.x); o.y=f2b(v.y); o.z=f2b(v.z); o.w=f2b(v.w); return o; }

typedef __attribute__((ext_vector_type(8))) short short8v;   // 8 bf16 = 4 VGPR
typedef __attribute__((ext_vector_type(4))) float f32x4;

// ---------------- GNN: embedding tables  T[161][128] = emb_f @ W_slice ----------------
__global__ __launch_bounds__(128) void build_tables_k(
    const float* __restrict__ ea, const float* __restrict__ ed, const float* __restrict__ ec,
    const float* __restrict__ eh, const float* __restrict__ ear, const float* __restrict__ ech,
    const float* __restrict__ Wm, float* __restrict__ T)
{
    int r = blockIdx.x, c = threadIdx.x;
    const float* e; int dim, woff, rl;
    if      (r < 120) { e=ea;  dim=64; woff=0;   rl=r; }
    else if (r < 132) { e=ed;  dim=16; woff=64;  rl=r-120; }
    else if (r < 147) { e=ec;  dim=16; woff=80;  rl=r-132; }
    else if (r < 155) { e=eh;  dim=8;  woff=96;  rl=r-147; }
    else if (r < 157) { e=ear; dim=4;  woff=104; rl=r-155; }
    else              { e=ech; dim=4;  woff=108; rl=r-157; }
    float acc = 0.f;
    for (int k = 0; k < dim; ++k) acc += e[rl*dim + k] * Wm[(woff + k)*128 + c];
    T[r*128 + c] = acc;
}

// X0[i][:] = sum of 6 table rows (+ charge * Wrow112), written bf16
__global__ __launch_bounds__(256) void embed_lookup_k(
    const int* __restrict__ xi, const float* __restrict__ charge,
    const float* __restrict__ T, const float* __restrict__ wq,
    ushort* __restrict__ H, int N)
{
    int t = threadIdx.x;
    int node = blockIdx.x*8 + (t >> 5);
    if (node >= N) return;
    int c = (t & 31)*4;
    const int* xp = xi + node*6;
    float4 acc = ld4(T + (       xp[0])*128 + c);
    acc = f4add(acc, ld4(T + (120+xp[1])*128 + c));
    acc = f4add(acc, ld4(T + (132+xp[2])*128 + c));
    acc = f4add(acc, ld4(T + (147+xp[3])*128 + c));
    acc = f4add(acc, ld4(T + (155+xp[4])*128 + c));
    acc = f4add(acc, ld4(T + (157+xp[5])*128 + c));
    if (charge) acc = f4fma(charge[node], ld4(wq + c), acc);
    *(ushort4*)(H + (size_t)node*128 + c) = f2b4(acc);
}

// ---------------- GCN degree / norm / CSR build ----------------
__global__ void init_deg_k(float* deg, int N){ int i = blockIdx.x*256+threadIdx.x; if (i<N) deg[i]=1.f; }

__global__ void deg_scatter_k(const int* __restrict__ col, const float* __restrict__ ew, float* deg, int E){
    int e = blockIdx.x*256+threadIdx.x; if (e>=E) return;
    unsafeAtomicAdd(deg + col[e], ew ? ew[e] : 1.f);
}

__global__ void dis_k(const float* __restrict__ deg, float* __restrict__ dis, int N){
    int i = blockIdx.x*256+threadIdx.x; if (i<N) dis[i] = 1.f/sqrtf(deg[i]);
}

__global__ void count_in_k(const int* __restrict__ col, int* __restrict__ cnt, int E){
    int e = blockIdx.x*256+threadIdx.x; if (e>=E) return;
    atomicAdd(&cnt[col[e]], 1);
}

// single-block exclusive scan: cnt (in cursor) -> rowptr; cursor reset to starts
__global__ __launch_bounds__(1024) void scan_k(int* __restrict__ cnt_cursor, int* __restrict__ rowptr, int N)
{
    __shared__ int part[1024];
    int t = threadIdx.x;
    int chunk = (N + 1023) >> 10;
    int base = t*chunk;
    int s = 0;
    for (int i = 0; i < chunk; ++i) { int idx = base+i; if (idx < N) s += cnt_cursor[idx]; }
    part[t] = s;
    __syncthreads();
    for (int off = 1; off < 1024; off <<= 1) {
        int v = (t >= off) ? part[t-off] : 0;
        __syncthreads();
        if (t >= off) part[t] += v;
        __syncthreads();
    }
    int run = (t == 0) ? 0 : part[t-1];
    for (int i = 0; i < chunk; ++i) {
        int idx = base+i; if (idx >= N) break;
        int c = cnt_cursor[idx];
        rowptr[idx] = run;
        cnt_cursor[idx] = run;   // cursor = start
        run += c;
    }
    if (t == 1023) rowptr[N] = part[1023];
}

__global__ void fill_csr_k(const int* __restrict__ row, const int* __restrict__ col,
                           const float* __restrict__ ew, const float* __restrict__ dis,
                           int* __restrict__ cursor, int* __restrict__ csr_src,
                           float* __restrict__ csr_nrm, int E)
{
    int e = blockIdx.x*256+threadIdx.x; if (e>=E) return;
    int r = row[e], c = col[e];
    int pos = atomicAdd(&cursor[c], 1);
    csr_src[pos] = r;
    csr_nrm[pos] = dis[r] * (ew ? ew[e] : 1.f) * dis[c];
}

// O[i] = bias + dis[i]^2 * H[i] + sum_j nrm_j * H[src_j]   -- bf16 in/out, fp32 math
__global__ __launch_bounds__(256) void gcn_gather_k(
    const ushort* __restrict__ H, const int* __restrict__ rowptr,
    const int* __restrict__ csr_src, const float* __restrict__ csr_nrm,
    const float* __restrict__ dis, const float* __restrict__ bias,
    ushort* __restrict__ O, int N)
{
    int node = blockIdx.x*8 + (threadIdx.x >> 5);
    if (node >= N) return;
    int lane = (threadIdx.x & 31)*4;
    float s = dis[node]; s *= s;
    float4 h = b2f4(*(const ushort4*)(H + (size_t)node*128 + lane));
    float4 b = ld4(bias + lane);
    float4 acc = f4fma(s, h, b);
    int j = rowptr[node], end = rowptr[node+1];
    for (; j + 4 <= end; j += 4) {
        int   s0 = csr_src[j],   s1 = csr_src[j+1], s2 = csr_src[j+2], s3 = csr_src[j+3];
        float n0 = csr_nrm[j],   n1 = csr_nrm[j+1], n2 = csr_nrm[j+2], n3 = csr_nrm[j+3];
        float4 h0 = b2f4(*(const ushort4*)(H + (size_t)s0*128 + lane));
        float4 h1 = b2f4(*(const ushort4*)(H + (size_t)s1*128 + lane));
        float4 h2 = b2f4(*(const ushort4*)(H + (size_t)s2*128 + lane));
        float4 h3 = b2f4(*(const ushort4*)(H + (size_t)s3*128 + lane));
        acc = f4fma(n0, h0, acc);
        acc = f4fma(n1, h1, acc);
        acc = f4fma(n2, h2, acc);
        acc = f4fma(n3, h3, acc);
    }
    for (; j < end; ++j) {
        float4 h0 = b2f4(*(const ushort4*)(H + (size_t)csr_src[j]*128 + lane));
        acc = f4fma(csr_nrm[j], h0, acc);
    }
    *(ushort4*)(O + (size_t)node*128 + lane) = f2b4(acc);
}

// O = relu(A) @ W via bf16 MFMA; A:[N,128] bf16, W:[128,128] f32, O bf16
// block: 256 thr = 4 waves, 64-row tile. W staged frag-ordered in LDS.
__global__ __launch_bounds__(256) void gemm_mfma_k(
    const ushort* __restrict__ A, const float* __restrict__ W,
    ushort* __restrict__ O, int N)
{
    __shared__ ushort WsF[16384];     // [ct][ks][kg][col][j] frag-ordered bf16
    __shared__ ushort As[64*136];     // padded rows (+16B) to spread banks
    int t = threadIdx.x;
    for (int i = t; i < 16384; i += 256) {
        int j = i & 7, col = (i >> 3) & 15, kg = (i >> 7) & 3, ks = (i >> 9) & 3, ct = i >> 11;
        WsF[i] = f2b(W[(ks*32 + kg*8 + j)*128 + ct*16 + col]);
    }
    int row0 = blockIdx.x*64;
    for (int i = t; i < 64*32; i += 256) {            // ushort4 chunks
        int r = i >> 5, c4 = (i & 31)*4;
        ushort4 v = *(const ushort4*)(A + (size_t)(row0 + r)*128 + c4);
        v.x = (v.x & 0x8000) ? 0 : v.x;               // bf16 relu
        v.y = (v.y & 0x8000) ? 0 : v.y;
        v.z = (v.z & 0x8000) ? 0 : v.z;
        v.w = (v.w & 0x8000) ? 0 : v.w;
        *(ushort4*)(As + r*136 + c4) = v;
    }
    __syncthreads();
    int w = t >> 6, l = t & 63;
    int m16 = l & 15, kg = l >> 4;
    short8v af[4];
    #pragma unroll
    for (int ks = 0; ks < 4; ++ks)
        af[ks] = *(const short8v*)(As + (w*16 + m16)*136 + ks*32 + kg*8);
    #pragma unroll
    for (int ct = 0; ct < 8; ++ct) {
        f32x4 acc = {0.f, 0.f, 0.f, 0.f};
        #pragma unroll
        for (int ks = 0; ks < 4; ++ks) {
            short8v bf = *(const short8v*)(WsF + ((ct*4 + ks)*4 + kg)*128 + m16*8);
            acc = __builtin_amdgcn_mfma_f32_16x16x32_bf16(af[ks], bf, acc, 0, 0, 0);
        }
        int col = ct*16 + m16;
        int rbase = row0 + w*16 + kg*4;                // D: col=lane&15, row=(lane>>4)*4+reg
        #pragma unroll
        for (int j = 0; j < 4; ++j)
            O[(size_t)(rbase + j)*128 + col] = f2b(acc[j]);
    }
}

// ---------------- mean pool (bf16 input) ----------------
__global__ __launch_bounds__(128) void mean_pool_sum_k(
    const ushort* __restrict__ X, const int* __restrict__ bv,
    float* __restrict__ featp /* stride 512 */, int chunk, int N)
{
    __shared__ float acc[16*128];
    int t = threadIdx.x;
    for (int b = 0; b < 16; ++b) acc[b*128 + t] = 0.f;
    int i0 = blockIdx.x * chunk;
    int iend = min(i0 + chunk, N);
    int bcur = bv[i0];
    float r = 0.f;
    for (int i = i0; i < iend; ++i) {
        int b = bv[i];
        if (b != bcur) { acc[bcur*128 + t] += r; r = 0.f; bcur = b; }
        r += fmaxf(b2f(X[(size_t)i*128 + t]), 0.f);
    }
    acc[bcur*128 + t] += r;
    for (int b = 0; b < 16; ++b) {
        float v = acc[b*128 + t];
        if (v != 0.f) unsafeAtomicAdd(featp + b*512 + t, v);
    }
}

__global__ void count_batch_k(const int* __restrict__ bv, float* __restrict__ cnt, int N){
    __shared__ int h[16];
    int t = threadIdx.x;
    if (t < 16) h[t] = 0;
    __syncthreads();
    int i = blockIdx.x*256 + t;
    if (i < N) atomicAdd(&h[bv[i]], 1);
    __syncthreads();
    if (t < 16 && h[t]) unsafeAtomicAdd(&cnt[t], (float)h[t]);
}

// ---------------- voxel CNN: LDS-tiled conv(3x3x3 SAME)+bias+BN-stats+max/min-pool -------
template<int CIN, int COUT, int D, int CL, bool BNIN>
__global__ __launch_bounds__(256) void conv_pool4_k(
    const float* __restrict__ inmax, const float* __restrict__ inmin,
    const float* __restrict__ scin, const float* __restrict__ shin,
    const float* __restrict__ wt, const float* __restrict__ bias,
    float* __restrict__ outmax, float* __restrict__ outmin, float* __restrict__ stats)
{
    constexpr int PD = D/2;
    constexpr int NTX = (PD >= 8) ? PD/8 : 1;
    constexpr int SY = 20, SZ = 20*18;
    __shared__ float tileL[10*SZ];
    __shared__ float swred[4*2*CL];

    int tid = threadIdx.x;
    int co0 = blockIdx.y * CL;
    int n   = blockIdx.z;

    int tb = blockIdx.x;
    int tx = tb % NTX, ty = (tb / NTX) % NTX, tz = tb / (NTX*NTX);
    int pw = tid & 7, ph = (tid >> 3) & 7, pd = tid >> 6;
    int ix0 = tx*16 - 1, iy0 = ty*16 - 1, iz0 = tz*8 - 1;

    int sy0 = tid / 18, sx0 = tid - sy0*18;
    int sp1 = tid + 256;
    int sy1 = sp1 / 18, sx1 = sp1 - sy1*18;
    bool has1 = (sp1 < 324);

    float acc[CL][8];
    #pragma unroll
    for (int cl = 0; cl < CL; ++cl)
        #pragma unroll
        for (int p = 0; p < 8; ++p) acc[cl][p] = 0.f;

    int base = (2*pd)*SZ + (2*ph)*SY + 2*pw;

    for (int ci = 0; ci < CIN; ++ci) {
        __syncthreads();
        float s_in = 0.f, sh_in = 0.f;
        if (BNIN) { s_in = scin[ci]; sh_in = shin[ci]; }
        const float* ib;
        if (BNIN) ib = (s_in >= 0.f) ? inmax + ((size_t)(n*CIN + ci))*((size_t)D*D*D)
                                     : inmin + ((size_t)(n*CIN + ci))*((size_t)D*D*D);
        else      ib = inmax + ((size_t)(n*CIN + ci))*((size_t)D*D*D);

        #pragma unroll 2
        for (int z = 0; z < 10; ++z) {
            int gz = iz0 + z; bool zok = (unsigned)gz < (unsigned)D;
            {
                int gy = iy0 + sy0, gx = ix0 + sx0;
                float val = 0.f;
                if (zok && (unsigned)gy < (unsigned)D && (unsigned)gx < (unsigned)D) {
                    float v = ib[((size_t)gz*D + gy)*D + gx];
                    val = BNIN ? fmaxf(fmaf(v, s_in, sh_in), 0.f) : v;
                }
                tileL[z*SZ + sy0*SY + sx0] = val;
            }
            if (has1) {
                int gy = iy0 + sy1, gx = ix0 + sx1;
                float val = 0.f;
                if (zok && (unsigned)gy < (unsigned)D && (unsigned)gx < (unsigned)D) {
                    float v = ib[((size_t)gz*D + gy)*D + gx];
                    val = BNIN ? fmaxf(fmaf(v, s_in, sh_in), 0.f) : v;
                }
                tileL[z*SZ + sy1*SY + sx1] = val;
            }
        }
        __syncthreads();

        const float* wb = wt + ((size_t)co0*CIN + ci)*27;
        #pragma unroll
        for (int r = 0; r < 9; ++r) {
            const int kd = r/3, kh = r%3;
            float vv[2][2][4];
            #pragma unroll
            for (int dz = 0; dz < 2; ++dz)
            #pragma unroll
            for (int dy = 0; dy < 2; ++dy) {
                const float* rp = &tileL[base + (dz+kd)*SZ + (dy+kh)*SY];
                float2 p0 = ld2(rp), p1 = ld2(rp+2);
                vv[dz][dy][0]=p0.x; vv[dz][dy][1]=p0.y; vv[dz][dy][2]=p1.x; vv[dz][dy][3]=p1.y;
            }
            #pragma unroll
            for (int cl = 0; cl < CL; ++cl) {
                const float* wc = wb + (size_t)cl*CIN*27 + r*3;
                float w0 = wc[0], w1 = wc[1], w2 = wc[2];
                #pragma unroll
                for (int dz = 0; dz < 2; ++dz)
                #pragma unroll
                for (int dy = 0; dy < 2; ++dy)
                #pragma unroll
                for (int dx = 0; dx < 2; ++dx) {
                    int p = dz*4 + dy*2 + dx;
                    acc[cl][p] = fmaf(w0, vv[dz][dy][dx+0], acc[cl][p]);
                    acc[cl][p] = fmaf(w1, vv[dz][dy][dx+1], acc[cl][p]);
                    acc[cl][p] = fmaf(w2, vv[dz][dy][dx+2], acc[cl][p]);
                }
            }
        }
    }

    int ow = tx*8 + pw, oh = ty*8 + ph, od = tz*4 + pd;
    float ssum[CL], ssq[CL];
    size_t obase = ((size_t)n*COUT + co0)*((size_t)PD*PD*PD) + ((size_t)od*PD + oh)*PD + ow;
    #pragma unroll
    for (int cl = 0; cl < CL; ++cl) {
        float cb = bias[co0 + cl];
        float mx = -1e30f, mn = 1e30f, s = 0.f, q = 0.f;
        #pragma unroll
        for (int p = 0; p < 8; ++p) {
            float val = acc[cl][p] + cb;
            mx = fmaxf(mx, val); mn = fminf(mn, val);
            s += val; q = fmaf(val, val, q);
        }
        ssum[cl] = s; ssq[cl] = q;
        outmax[obase + (size_t)cl*(PD*PD*PD)] = mx;
        outmin[obase + (size_t)cl*(PD*PD*PD)] = mn;
    }

    int lane = tid & 63, wid = tid >> 6;
    #pragma unroll
    for (int cl = 0; cl < CL; ++cl) {
        float a_ = ssum[cl], b_ = ssq[cl];
        #pragma unroll
        for (int off = 32; off; off >>= 1) {
            a_ += __shfl_down(a_, off, 64);
            b_ += __shfl_down(b_, off, 64);
        }
        if (lane == 0) { swred[wid*2*CL + cl*2] = a_; swred[wid*2*CL + cl*2 + 1] = b_; }
    }
    __syncthreads();
    if (tid < 2*CL) {
        float t = swred[tid] + swred[2*CL + tid] + swred[4*CL + tid] + swred[6*CL + tid];
        unsafeAtomicAdd(&stats[co0*2 + tid], t);
    }
}

__global__ void bn_final_k(const float* __restrict__ stats, const float* __restrict__ g,
                           const float* __restrict__ b, float* __restrict__ sc, float* __restrict__ sh,
                           int C, float invN)
{
    int c = threadIdx.x; if (c >= C) return;
    float m = stats[c*2] * invN;
    float v = stats[c*2+1] * invN - m*m;
    float s = g[c] * rsqrtf(v + 1e-5f);
    sc[c] = s; sh[c] = b[c] - m*s;
}

__global__ __launch_bounds__(256) void bn_select_k(
    const float* __restrict__ mx, const float* __restrict__ mn,
    const float* __restrict__ sc, const float* __restrict__ sh,
    float* __restrict__ out, int Cmask, int lgPD3, int total)
{
    int idx = blockIdx.x*256 + threadIdx.x;
    if (idx >= total) return;
    int c = (idx >> lgPD3) & Cmask;
    float s = sc[c];
    float v = (s >= 0.f) ? mx[idx] : mn[idx];
    out[idx] = fmaxf(fmaf(v, s, sh[c]), 0.f);
}

// fc: X[16,32768] @ W[32768,128] -> accumulate into feat[:,384:512]
__global__ __launch_bounds__(128) void fc_acc_k(
    const float* __restrict__ X, const float* __restrict__ W, float* __restrict__ featv)
{
    int t = threadIdx.x;
    int k0 = blockIdx.x*256;
    float acc[16];
    #pragma unroll
    for (int b = 0; b < 16; ++b) acc[b] = 0.f;
    for (int k = k0; k < k0 + 256; ++k) {
        float w = W[(size_t)k*128 + t];
        #pragma unroll
        for (int b = 0; b < 16; ++b) acc[b] = fmaf(X[(size_t)b*32768 + k], w, acc[b]);
    }
    for (int b = 0; b < 16; ++b) unsafeAtomicAdd(featv + b*512 + t, acc[b]);
}

// ---------------- small dense layers ----------------
__global__ __launch_bounds__(256) void head_k(
    const float* __restrict__ X, const float* __restrict__ W, const float* __restrict__ b,
    float* __restrict__ O, int K, int Ncol, int relu)
{
    int t = blockIdx.x*256 + threadIdx.x;
    if (t >= 16*Ncol) return;
    int bi = t / Ncol, c = t % Ncol;
    float acc = b[c];
    for (int k = 0; k < K; ++k) acc = fmaf(X[bi*K + k], W[k*Ncol + c], acc);
    if (relu) acc = fmaxf(acc, 0.f);
    O[bi*Ncol + c] = acc;
}

__global__ void gebn_k(const float* __restrict__ g2, const float* __restrict__ g,
                       const float* __restrict__ b, float* __restrict__ featg /* stride 512 */)
{
    int c = threadIdx.x;  // 128
    float m = 0.f;
    for (int i = 0; i < 16; ++i) m += g2[i*128 + c];
    m *= (1.f/16.f);
    float v = 0.f;
    for (int i = 0; i < 16; ++i) { float d = g2[i*128 + c] - m; v += d*d; }
    v *= (1.f/16.f);
    float s = g[c] * rsqrtf(v + 1e-5f);
    for (int i = 0; i < 16; ++i)
        featg[i*512 + c] = fmaxf((g2[i*128 + c] - m)*s + b[c], 0.f);
}

__global__ void finalize_feat_k(float* __restrict__ feat, const float* __restrict__ cntm,
                                const float* __restrict__ cntz, const float* __restrict__ fcb)
{
    int t = blockIdx.x*256 + threadIdx.x;   // 16*512
    if (t >= 8192) return;
    int bi = t >> 9, c = t & 511;
    float v = feat[t];
    if      (c < 128) v /= fmaxf(cntm[bi], 1.f);
    else if (c < 256) v /= fmaxf(cntz[bi], 1.f);
    else if (c >= 384) v = fmaxf(v + fcb[c - 384], 0.f);
    feat[t] = v;
}

// =====================================================================================
extern "C" void kernel_launch(void* const* d_in, const int* in_sizes, int n_in,
                              void* d_out, int out_size, void* d_ws, size_t ws_size,
                              hipStream_t stream)
{
    const int*   mol_x  = (const int*)  d_in[0];
    const float* mol_q  = (const float*)d_in[1];
    const int*   mol_ei = (const int*)  d_in[2];
    const float* mol_ew = (const float*)d_in[3];
    const int*   mol_bv = (const int*)  d_in[4];
    const int*   zeo_x  = (const int*)  d_in[5];
    const int*   zeo_ei = (const int*)  d_in[6];
    const int*   zeo_bv = (const int*)  d_in[7];
    const float* voxel  = (const float*)d_in[8];
    const float* gattr  = (const float*)d_in[9];
    const float* ea  = (const float*)d_in[10];
    const float* ed  = (const float*)d_in[11];
    const float* ec  = (const float*)d_in[12];
    const float* eh  = (const float*)d_in[13];
    const float* ear = (const float*)d_in[14];
    const float* ech = (const float*)d_in[15];
    const float* mc1w=(const float*)d_in[16]; const float* mc1b=(const float*)d_in[17];
    const float* mc2w=(const float*)d_in[18]; const float* mc2b=(const float*)d_in[19];
    const float* zc1w=(const float*)d_in[20]; const float* zc1b=(const float*)d_in[21];
    const float* zc2w=(const float*)d_in[22]; const float* zc2b=(const float*)d_in[23];
    const float* cv1w=(const float*)d_in[24]; const float* cv1b=(const float*)d_in[25];
    const float* bn1g=(const float*)d_in[26]; const float* bn1b=(const float*)d_in[27];
    const float* cv2w=(const float*)d_in[28]; const float* cv2b=(const float*)d_in[29];
    const float* bn2g=(const float*)d_in[30]; const float* bn2b=(const float*)d_in[31];
    const float* cv3w=(const float*)d_in[32]; const float* cv3b=(const float*)d_in[33];
    const float* bn3g=(const float*)d_in[34]; const float* bn3b=(const float*)d_in[35];
    const float* fcw =(const float*)d_in[36]; const float* fcb =(const float*)d_in[37];
    const float* ge1w=(const float*)d_in[38]; const float* ge1b=(const float*)d_in[39];
    const float* ge2w=(const float*)d_in[40]; const float* ge2b=(const float*)d_in[41];
    const float* gbng=(const float*)d_in[42]; const float* gbnb=(const float*)d_in[43];
    const float* h1w =(const float*)d_in[44]; const float* h1b =(const float*)d_in[45];
    const float* h2w =(const float*)d_in[46]; const float* h2b =(const float*)d_in[47];
    const float* h3w =(const float*)d_in[48]; const float* h3b =(const float*)d_in[49];

    const int Nm = in_sizes[0]/6, Em = in_sizes[2]/2;
    const int Nz = in_sizes[5]/6, Ez = in_sizes[6]/2;

    float* WS = (float*)d_ws;
    float* A  = WS;                     // 16,777,216 floats (67 MB)
    float* Bb = WS + 16777216;          // 16,777,216 floats (67 MB)
    float* S  = WS + 33554432;          // small scratch
    // bf16 GNN activations (live only before the conv phase)
    ushort* X0 = (ushort*)A;                 // [N][128] bf16
    ushort* X1 = (ushort*)A + 16777216;
    ushort* X2 = (ushort*)Bb;
    ushort* X3 = (ushort*)Bb + 16777216;
    float* deg  = S;
    float* dis  = S + 131072;
    float* csr_nrm = S + 262144;        // 524288
    float* T    = S + 786432;           // 161*128
    float* cntm = S + 807040;
    float* cntz = S + 807056;
    float* feat = S + 807072;           // [16][512]
    float* st1  = S + 815264; float* st2 = st1 + 32; float* st3 = st1 + 96;
    float* sc1  = S + 815488; float* sh1 = sc1 + 16;
    float* sc2  = sc1 + 32;   float* sh2 = sc1 + 64;
    float* sc3  = sc1 + 96;   float* sh3 = sc1 + 160;
    float* g1   = S + 815712;           // 16*64
    float* g2   = S + 816736;           // 16*128
    float* H1   = S + 818784;           // 16*512
    float* H2   = S + 826976;           // 16*256
    int* rowptr  = (int*)(S + 831072);  // 131073
    int* cursor  = (int*)(S + 962176);  // 131072
    int* csr_src = (int*)(S + 1093248); // 524288

    // zero small accumulators (feat/stats/cnt) each replay
    hipMemsetAsync(S, 0, (size_t)831072*sizeof(float), stream);

    // ---------------- molecule branch ----------------
    build_tables_k<<<161,128,0,stream>>>(ea,ed,ec,eh,ear,ech, mc1w, T);
    init_deg_k   <<<Nm/256,256,0,stream>>>(deg, Nm);
    deg_scatter_k<<<Em/256,256,0,stream>>>(mol_ei+Em, mol_ew, deg, Em);
    dis_k        <<<Nm/256,256,0,stream>>>(deg, dis, Nm);
    hipMemsetAsync(cursor, 0, (size_t)Nm*sizeof(int), stream);
    count_in_k   <<<Em/256,256,0,stream>>>(mol_ei+Em, cursor, Em);
    scan_k       <<<1,1024,0,stream>>>(cursor, rowptr, Nm);
    fill_csr_k   <<<Em/256,256,0,stream>>>(mol_ei, mol_ei+Em, mol_ew, dis, cursor, csr_src, csr_nrm, Em);
    embed_lookup_k<<<Nm/8,256,0,stream>>>(mol_x, mol_q, T, mc1w + 112*128, X0, Nm);
    gcn_gather_k <<<Nm/8,256,0,stream>>>(X0, rowptr, csr_src, csr_nrm, dis, mc1b, X1, Nm);
    gemm_mfma_k  <<<Nm/64,256,0,stream>>>(X1, mc2w, X2, Nm);
    gcn_gather_k <<<Nm/8,256,0,stream>>>(X2, rowptr, csr_src, csr_nrm, dis, mc2b, X3, Nm);
    count_batch_k<<<Nm/256,256,0,stream>>>(mol_bv, cntm, Nm);
    mean_pool_sum_k<<<256,128,0,stream>>>(X3, mol_bv, feat + 0, (Nm+255)/256, Nm);

    // ---------------- zeolite branch ----------------
    build_tables_k<<<161,128,0,stream>>>(ea,ed,ec,eh,ear,ech, zc1w, T);
    init_deg_k   <<<Nz/256,256,0,stream>>>(deg, Nz);
    deg_scatter_k<<<Ez/256,256,0,stream>>>(zeo_ei+Ez, nullptr, deg, Ez);
    dis_k        <<<Nz/256,256,0,stream>>>(deg, dis, Nz);
    hipMemsetAsync(cursor, 0, (size_t)Nz*sizeof(int), stream);
    count_in_k   <<<Ez/256,256,0,stream>>>(zeo_ei+Ez, cursor, Ez);
    scan_k       <<<1,1024,0,stream>>>(cursor, rowptr, Nz);
    fill_csr_k   <<<Ez/256,256,0,stream>>>(zeo_ei, zeo_ei+Ez, nullptr, dis, cursor, csr_src, csr_nrm, Ez);
    embed_lookup_k<<<Nz/8,256,0,stream>>>(zeo_x, nullptr, T, nullptr, X0, Nz);
    gcn_gather_k <<<Nz/8,256,0,stream>>>(X0, rowptr, csr_src, csr_nrm, dis, zc1b, X1, Nz);
    gemm_mfma_k  <<<Nz/64,256,0,stream>>>(X1, zc2w, X2, Nz);
    gcn_gather_k <<<Nz/8,256,0,stream>>>(X2, rowptr, csr_src, csr_nrm, dis, zc2b, X3, Nz);
    count_batch_k<<<Nz/256,256,0,stream>>>(zeo_bv, cntz, Nz);
    mean_pool_sum_k<<<256,128,0,stream>>>(X3, zeo_bv, feat + 128, (Nz+255)/256, Nz);

    // ---------------- voxel CNN (fp32, unchanged) ----------------
    conv_pool4_k<2,16,64,8,false><<<dim3(128,2,16),256,0,stream>>>(
        voxel, nullptr, nullptr, nullptr, cv1w, cv1b, A, A+8388608, st1);
    bn_final_k<<<1,64,0,stream>>>(st1, bn1g, bn1b, sc1, sh1, 16, 1.f/(16.f*262144.f));

    conv_pool4_k<16,32,32,8,true><<<dim3(16,4,16),256,0,stream>>>(
        A, A+8388608, sc1, sh1, cv2w, cv2b, Bb, Bb+2097152, st2);
    bn_final_k<<<1,64,0,stream>>>(st2, bn2g, bn2b, sc2, sh2, 32, 1.f/(16.f*32768.f));

    conv_pool4_k<32,64,16,4,true><<<dim3(2,16,16),256,0,stream>>>(
        Bb, Bb+2097152, sc2, sh2, cv3w, cv3b, A, A+524288, st3);
    bn_final_k<<<1,64,0,stream>>>(st3, bn3g, bn3b, sc3, sh3, 64, 1.f/(16.f*4096.f));
    bn_select_k<<<2048,256,0,stream>>>(A, A+524288, sc3, sh3, Bb, 63, 9, 524288);

    fc_acc_k<<<128,128,0,stream>>>(Bb, fcw, feat + 384);

    // ---------------- global encoder ----------------
    head_k<<<4,256,0,stream>>>(gattr, ge1w, ge1b, g1, 17, 64, 1);
    head_k<<<8,256,0,stream>>>(g1, ge2w, ge2b, g2, 64, 128, 0);
    gebn_k<<<1,128,0,stream>>>(g2, gbng, gbnb, feat + 256);

    // ---------------- fusion head ----------------
    finalize_feat_k<<<32,256,0,stream>>>(feat, cntm, cntz, fcb);
    head_k<<<32,256,0,stream>>>(feat, h1w, h1b, H1, 512, 512, 1);
    head_k<<<16,256,0,stream>>>(H1, h2w, h2b, H2, 512, 256, 1);
    head_k<<<1,256,0,stream>>>(H2, h3w, h3b, (float*)d_out, 256, 3, 0);
}

// Round 9
// 2038.924 us; speedup vs baseline: 1.3692x; 1.2081x over previous
//
#include <hip/hip_runtime.h>
#include <math.h>

#define DEV static __device__ __forceinline__

DEV float4 ld4(const float* p){ return *(const float4*)p; }
DEV float2 ld2(const float* p){ return *(const float2*)p; }
DEV void   st4(float* p, float4 v){ *(float4*)p = v; }
DEV float4 f4add(float4 a, float4 b){ return make_float4(a.x+b.x,a.y+b.y,a.z+b.z,a.w+b.w); }
DEV float4 f4fma(float s, float4 a, float4 c){ return make_float4(fmaf(s,a.x,c.x),fmaf(s,a.y,c.y),fmaf(s,a.z,c.z),fmaf(s,a.w,c.w)); }
DEV float4 f4relu(float4 a){ return make_float4(fmaxf(a.x,0.f),fmaxf(a.y,0.f),fmaxf(a.z,0.f),fmaxf(a.w,0.f)); }

// bf16 helpers (RNE pack, exact unpack)
DEV float  b2f(ushort u){ return __uint_as_float(((unsigned)u) << 16); }
DEV ushort f2b(float f){
    unsigned u = __float_as_uint(f);
    return (ushort)((u + 0x7FFFu + ((u >> 16) & 1u)) >> 16);
}
DEV float4 b2f4(ushort4 v){ return make_float4(b2f(v.x), b2f(v.y), b2f(v.z), b2f(v.w)); }
DEV ushort4 f2b4(float4 v){ ushort4 o; o.x=f2b(v.x); o.y=f2b(v.y); o.z=f2b(v.z); o.w=f2b(v.w); return o; }

typedef __attribute__((ext_vector_type(8))) short short8v;            // 8 bf16 = 4 VGPR
typedef __attribute__((ext_vector_type(8))) unsigned short ushort8v;
typedef __attribute__((ext_vector_type(4))) float f32x4;

// ---------------- GNN: embedding tables  T[161][128] = emb_f @ W_slice ----------------
__global__ __launch_bounds__(128) void build_tables_k(
    const float* __restrict__ ea, const float* __restrict__ ed, const float* __restrict__ ec,
    const float* __restrict__ eh, const float* __restrict__ ear, const float* __restrict__ ech,
    const float* __restrict__ Wm, float* __restrict__ T)
{
    int r = blockIdx.x, c = threadIdx.x;
    const float* e; int dim, woff, rl;
    if      (r < 120) { e=ea;  dim=64; woff=0;   rl=r; }
    else if (r < 132) { e=ed;  dim=16; woff=64;  rl=r-120; }
    else if (r < 147) { e=ec;  dim=16; woff=80;  rl=r-132; }
    else if (r < 155) { e=eh;  dim=8;  woff=96;  rl=r-147; }
    else if (r < 157) { e=ear; dim=4;  woff=104; rl=r-155; }
    else              { e=ech; dim=4;  woff=108; rl=r-157; }
    float acc = 0.f;
    for (int k = 0; k < dim; ++k) acc += e[rl*dim + k] * Wm[(woff + k)*128 + c];
    T[r*128 + c] = acc;
}

__global__ __launch_bounds__(256) void embed_lookup_k(
    const int* __restrict__ xi, const float* __restrict__ charge,
    const float* __restrict__ T, const float* __restrict__ wq,
    ushort* __restrict__ H, int N)
{
    int t = threadIdx.x;
    int node = blockIdx.x*8 + (t >> 5);
    if (node >= N) return;
    int c = (t & 31)*4;
    const int* xp = xi + node*6;
    float4 acc = ld4(T + (       xp[0])*128 + c);
    acc = f4add(acc, ld4(T + (120+xp[1])*128 + c));
    acc = f4add(acc, ld4(T + (132+xp[2])*128 + c));
    acc = f4add(acc, ld4(T + (147+xp[3])*128 + c));
    acc = f4add(acc, ld4(T + (155+xp[4])*128 + c));
    acc = f4add(acc, ld4(T + (157+xp[5])*128 + c));
    if (charge) acc = f4fma(charge[node], ld4(wq + c), acc);
    *(ushort4*)(H + (size_t)node*128 + c) = f2b4(acc);
}

// ---------------- GCN degree / norm / CSR build ----------------
__global__ void init_deg_k(float* deg, int N){ int i = blockIdx.x*256+threadIdx.x; if (i<N) deg[i]=1.f; }

__global__ void deg_scatter_k(const int* __restrict__ col, const float* __restrict__ ew, float* deg, int E){
    int e = blockIdx.x*256+threadIdx.x; if (e>=E) return;
    unsafeAtomicAdd(deg + col[e], ew ? ew[e] : 1.f);
}

__global__ void dis_k(const float* __restrict__ deg, float* __restrict__ dis, int N){
    int i = blockIdx.x*256+threadIdx.x; if (i<N) dis[i] = 1.f/sqrtf(deg[i]);
}

__global__ void count_in_k(const int* __restrict__ col, int* __restrict__ cnt, int E){
    int e = blockIdx.x*256+threadIdx.x; if (e>=E) return;
    atomicAdd(&cnt[col[e]], 1);
}

__global__ __launch_bounds__(1024) void scan_k(int* __restrict__ cnt_cursor, int* __restrict__ rowptr, int N)
{
    __shared__ int part[1024];
    int t = threadIdx.x;
    int chunk = (N + 1023) >> 10;
    int base = t*chunk;
    int s = 0;
    for (int i = 0; i < chunk; ++i) { int idx = base+i; if (idx < N) s += cnt_cursor[idx]; }
    part[t] = s;
    __syncthreads();
    for (int off = 1; off < 1024; off <<= 1) {
        int v = (t >= off) ? part[t-off] : 0;
        __syncthreads();
        if (t >= off) part[t] += v;
        __syncthreads();
    }
    int run = (t == 0) ? 0 : part[t-1];
    for (int i = 0; i < chunk; ++i) {
        int idx = base+i; if (idx >= N) break;
        int c = cnt_cursor[idx];
        rowptr[idx] = run;
        cnt_cursor[idx] = run;
        run += c;
    }
    if (t == 1023) rowptr[N] = part[1023];
}

__global__ void fill_csr_k(const int* __restrict__ row, const int* __restrict__ col,
                           const float* __restrict__ ew, const float* __restrict__ dis,
                           int* __restrict__ cursor, int* __restrict__ csr_src,
                           float* __restrict__ csr_nrm, int E)
{
    int e = blockIdx.x*256+threadIdx.x; if (e>=E) return;
    int r = row[e], c = col[e];
    int pos = atomicAdd(&cursor[c], 1);
    csr_src[pos] = r;
    csr_nrm[pos] = dis[r] * (ew ? ew[e] : 1.f) * dis[c];
}

// O[i] = bias + dis[i]^2 * H[i] + sum_j nrm_j * H[src_j]   -- bf16 in/out, fp32 math
__global__ __launch_bounds__(256) void gcn_gather_k(
    const ushort* __restrict__ H, const int* __restrict__ rowptr,
    const int* __restrict__ csr_src, const float* __restrict__ csr_nrm,
    const float* __restrict__ dis, const float* __restrict__ bias,
    ushort* __restrict__ O, int N)
{
    int node = blockIdx.x*8 + (threadIdx.x >> 5);
    if (node >= N) return;
    int lane = (threadIdx.x & 31)*4;
    float s = dis[node]; s *= s;
    float4 h = b2f4(*(const ushort4*)(H + (size_t)node*128 + lane));
    float4 b = ld4(bias + lane);
    float4 acc = f4fma(s, h, b);
    int j = rowptr[node], end = rowptr[node+1];
    for (; j + 4 <= end; j += 4) {
        int   s0 = csr_src[j],   s1 = csr_src[j+1], s2 = csr_src[j+2], s3 = csr_src[j+3];
        float n0 = csr_nrm[j],   n1 = csr_nrm[j+1], n2 = csr_nrm[j+2], n3 = csr_nrm[j+3];
        float4 h0 = b2f4(*(const ushort4*)(H + (size_t)s0*128 + lane));
        float4 h1 = b2f4(*(const ushort4*)(H + (size_t)s1*128 + lane));
        float4 h2 = b2f4(*(const ushort4*)(H + (size_t)s2*128 + lane));
        float4 h3 = b2f4(*(const ushort4*)(H + (size_t)s3*128 + lane));
        acc = f4fma(n0, h0, acc);
        acc = f4fma(n1, h1, acc);
        acc = f4fma(n2, h2, acc);
        acc = f4fma(n3, h3, acc);
    }
    for (; j < end; ++j) {
        float4 h0 = b2f4(*(const ushort4*)(H + (size_t)csr_src[j]*128 + lane));
        acc = f4fma(csr_nrm[j], h0, acc);
    }
    *(ushort4*)(O + (size_t)node*128 + lane) = f2b4(acc);
}

// O = relu(A) @ W via bf16 MFMA; A:[N,128] bf16, W:[128,128] f32, O bf16
__global__ __launch_bounds__(256) void gemm_mfma_k(
    const ushort* __restrict__ A, const float* __restrict__ W,
    ushort* __restrict__ O, int N)
{
    __shared__ ushort WsF[16384];
    __shared__ ushort As[64*136];
    int t = threadIdx.x;
    for (int i = t; i < 16384; i += 256) {
        int j = i & 7, col = (i >> 3) & 15, kg = (i >> 7) & 3, ks = (i >> 9) & 3, ct = i >> 11;
        WsF[i] = f2b(W[(ks*32 + kg*8 + j)*128 + ct*16 + col]);
    }
    int row0 = blockIdx.x*64;
    for (int i = t; i < 64*32; i += 256) {
        int r = i >> 5, c4 = (i & 31)*4;
        ushort4 v = *(const ushort4*)(A + (size_t)(row0 + r)*128 + c4);
        v.x = (v.x & 0x8000) ? 0 : v.x;
        v.y = (v.y & 0x8000) ? 0 : v.y;
        v.z = (v.z & 0x8000) ? 0 : v.z;
        v.w = (v.w & 0x8000) ? 0 : v.w;
        *(ushort4*)(As + r*136 + c4) = v;
    }
    __syncthreads();
    int w = t >> 6, l = t & 63;
    int m16 = l & 15, kg = l >> 4;
    short8v af[4];
    #pragma unroll
    for (int ks = 0; ks < 4; ++ks)
        af[ks] = *(const short8v*)(As + (w*16 + m16)*136 + ks*32 + kg*8);
    #pragma unroll
    for (int ct = 0; ct < 8; ++ct) {
        f32x4 acc = {0.f, 0.f, 0.f, 0.f};
        #pragma unroll
        for (int ks = 0; ks < 4; ++ks) {
            short8v bf = *(const short8v*)(WsF + ((ct*4 + ks)*4 + kg)*128 + m16*8);
            acc = __builtin_amdgcn_mfma_f32_16x16x32_bf16(af[ks], bf, acc, 0, 0, 0);
        }
        int col = ct*16 + m16;
        int rbase = row0 + w*16 + kg*4;
        #pragma unroll
        for (int j = 0; j < 4; ++j)
            O[(size_t)(rbase + j)*128 + col] = f2b(acc[j]);
    }
}

// ---------------- mean pool (bf16 input) ----------------
__global__ __launch_bounds__(128) void mean_pool_sum_k(
    const ushort* __restrict__ X, const int* __restrict__ bv,
    float* __restrict__ featp, int chunk, int N)
{
    __shared__ float acc[16*128];
    int t = threadIdx.x;
    for (int b = 0; b < 16; ++b) acc[b*128 + t] = 0.f;
    int i0 = blockIdx.x * chunk;
    int iend = min(i0 + chunk, N);
    int bcur = bv[i0];
    float r = 0.f;
    for (int i = i0; i < iend; ++i) {
        int b = bv[i];
        if (b != bcur) { acc[bcur*128 + t] += r; r = 0.f; bcur = b; }
        r += fmaxf(b2f(X[(size_t)i*128 + t]), 0.f);
    }
    acc[bcur*128 + t] += r;
    for (int b = 0; b < 16; ++b) {
        float v = acc[b*128 + t];
        if (v != 0.f) unsafeAtomicAdd(featp + b*512 + t, v);
    }
}

__global__ void count_batch_k(const int* __restrict__ bv, float* __restrict__ cnt, int N){
    __shared__ int h[16];
    int t = threadIdx.x;
    if (t < 16) h[t] = 0;
    __syncthreads();
    int i = blockIdx.x*256 + t;
    if (i < N) atomicAdd(&h[bv[i]], 1);
    __syncthreads();
    if (t < 16 && h[t]) unsafeAtomicAdd(&cnt[t], (float)h[t]);
}

// ---------------- conv layer 1: direct LDS-tiled (Cin=2), fp32 NCDHW out -------------
template<int CIN, int COUT, int D, int CL, bool BNIN>
__global__ __launch_bounds__(256) void conv_pool4_k(
    const float* __restrict__ inmax, const float* __restrict__ inmin,
    const float* __restrict__ scin, const float* __restrict__ shin,
    const float* __restrict__ wt, const float* __restrict__ bias,
    float* __restrict__ outmax, float* __restrict__ outmin, float* __restrict__ stats)
{
    constexpr int PD = D/2;
    constexpr int NTX = (PD >= 8) ? PD/8 : 1;
    constexpr int SY = 20, SZ = 20*18;
    __shared__ float tileL[10*SZ];
    __shared__ float swred[4*2*CL];

    int tid = threadIdx.x;
    int co0 = blockIdx.y * CL;
    int n   = blockIdx.z;

    int tb = blockIdx.x;
    int tx = tb % NTX, ty = (tb / NTX) % NTX, tz = tb / (NTX*NTX);
    int pw = tid & 7, ph = (tid >> 3) & 7, pd = tid >> 6;
    int ix0 = tx*16 - 1, iy0 = ty*16 - 1, iz0 = tz*8 - 1;

    int sy0 = tid / 18, sx0 = tid - sy0*18;
    int sp1 = tid + 256;
    int sy1 = sp1 / 18, sx1 = sp1 - sy1*18;
    bool has1 = (sp1 < 324);

    float acc[CL][8];
    #pragma unroll
    for (int cl = 0; cl < CL; ++cl)
        #pragma unroll
        for (int p = 0; p < 8; ++p) acc[cl][p] = 0.f;

    int base = (2*pd)*SZ + (2*ph)*SY + 2*pw;

    for (int ci = 0; ci < CIN; ++ci) {
        __syncthreads();
        float s_in = 0.f, sh_in = 0.f;
        if (BNIN) { s_in = scin[ci]; sh_in = shin[ci]; }
        const float* ib;
        if (BNIN) ib = (s_in >= 0.f) ? inmax + ((size_t)(n*CIN + ci))*((size_t)D*D*D)
                                     : inmin + ((size_t)(n*CIN + ci))*((size_t)D*D*D);
        else      ib = inmax + ((size_t)(n*CIN + ci))*((size_t)D*D*D);

        #pragma unroll 2
        for (int z = 0; z < 10; ++z) {
            int gz = iz0 + z; bool zok = (unsigned)gz < (unsigned)D;
            {
                int gy = iy0 + sy0, gx = ix0 + sx0;
                float val = 0.f;
                if (zok && (unsigned)gy < (unsigned)D && (unsigned)gx < (unsigned)D) {
                    float v = ib[((size_t)gz*D + gy)*D + gx];
                    val = BNIN ? fmaxf(fmaf(v, s_in, sh_in), 0.f) : v;
                }
                tileL[z*SZ + sy0*SY + sx0] = val;
            }
            if (has1) {
                int gy = iy0 + sy1, gx = ix0 + sx1;
                float val = 0.f;
                if (zok && (unsigned)gy < (unsigned)D && (unsigned)gx < (unsigned)D) {
                    float v = ib[((size_t)gz*D + gy)*D + gx];
                    val = BNIN ? fmaxf(fmaf(v, s_in, sh_in), 0.f) : v;
                }
                tileL[z*SZ + sy1*SY + sx1] = val;
            }
        }
        __syncthreads();

        const float* wb = wt + ((size_t)co0*CIN + ci)*27;
        #pragma unroll
        for (int r = 0; r < 9; ++r) {
            const int kd = r/3, kh = r%3;
            float vv[2][2][4];
            #pragma unroll
            for (int dz = 0; dz < 2; ++dz)
            #pragma unroll
            for (int dy = 0; dy < 2; ++dy) {
                const float* rp = &tileL[base + (dz+kd)*SZ + (dy+kh)*SY];
                float2 p0 = ld2(rp), p1 = ld2(rp+2);
                vv[dz][dy][0]=p0.x; vv[dz][dy][1]=p0.y; vv[dz][dy][2]=p1.x; vv[dz][dy][3]=p1.y;
            }
            #pragma unroll
            for (int cl = 0; cl < CL; ++cl) {
                const float* wc = wb + (size_t)cl*CIN*27 + r*3;
                float w0 = wc[0], w1 = wc[1], w2 = wc[2];
                #pragma unroll
                for (int dz = 0; dz < 2; ++dz)
                #pragma unroll
                for (int dy = 0; dy < 2; ++dy)
                #pragma unroll
                for (int dx = 0; dx < 2; ++dx) {
                    int p = dz*4 + dy*2 + dx;
                    acc[cl][p] = fmaf(w0, vv[dz][dy][dx+0], acc[cl][p]);
                    acc[cl][p] = fmaf(w1, vv[dz][dy][dx+1], acc[cl][p]);
                    acc[cl][p] = fmaf(w2, vv[dz][dy][dx+2], acc[cl][p]);
                }
            }
        }
    }

    int ow = tx*8 + pw, oh = ty*8 + ph, od = tz*4 + pd;
    float ssum[CL], ssq[CL];
    size_t obase = ((size_t)n*COUT + co0)*((size_t)PD*PD*PD) + ((size_t)od*PD + oh)*PD + ow;
    #pragma unroll
    for (int cl = 0; cl < CL; ++cl) {
        float cb = bias[co0 + cl];
        float mx = -1e30f, mn = 1e30f, s = 0.f, q = 0.f;
        #pragma unroll
        for (int p = 0; p < 8; ++p) {
            float val = acc[cl][p] + cb;
            mx = fmaxf(mx, val); mn = fminf(mn, val);
            s += val; q = fmaf(val, val, q);
        }
        ssum[cl] = s; ssq[cl] = q;
        outmax[obase + (size_t)cl*(PD*PD*PD)] = mx;
        outmin[obase + (size_t)cl*(PD*PD*PD)] = mn;
    }

    int lane = tid & 63, wid = tid >> 6;
    #pragma unroll
    for (int cl = 0; cl < CL; ++cl) {
        float a_ = ssum[cl], b_ = ssq[cl];
        #pragma unroll
        for (int off = 32; off; off >>= 1) {
            a_ += __shfl_down(a_, off, 64);
            b_ += __shfl_down(b_, off, 64);
        }
        if (lane == 0) { swred[wid*2*CL + cl*2] = a_; swred[wid*2*CL + cl*2 + 1] = b_; }
    }
    __syncthreads();
    if (tid < 2*CL) {
        float t = swred[tid] + swred[2*CL + tid] + swred[4*CL + tid] + swred[6*CL + tid];
        unsafeAtomicAdd(&stats[co0*2 + tid], t);
    }
}

__global__ void bn_final_k(const float* __restrict__ stats, const float* __restrict__ g,
                           const float* __restrict__ b, float* __restrict__ sc, float* __restrict__ sh,
                           int C, float invN)
{
    int c = threadIdx.x; if (c >= C) return;
    float m = stats[c*2] * invN;
    float v = stats[c*2+1] * invN - m*m;
    float s = g[c] * rsqrtf(v + 1e-5f);
    sc[c] = s; sh[c] = b[c] - m*s;
}

// conv1 fp32 NCDHW max/min -> BN+ReLU -> channels-last bf16 [n][32^3][16]
__global__ __launch_bounds__(256) void bn_select_cl1_k(
    const float* __restrict__ inmax, const float* __restrict__ inmin,
    const float* __restrict__ sc, const float* __restrict__ sh,
    ushort* __restrict__ out)
{
    __shared__ ushort lds[256*16];
    int t = threadIdx.x;
    int vox0 = blockIdx.x*256;
    int n = blockIdx.y;
    for (int ci = 0; ci < 16; ++ci) {
        float s = sc[ci], shv = sh[ci];
        size_t gi = ((size_t)(n*16 + ci))*32768 + vox0 + t;
        float v = (s >= 0.f) ? inmax[gi] : inmin[gi];
        lds[t*16 + ci] = f2b(fmaxf(fmaf(v, s, shv), 0.f));
    }
    __syncthreads();
    size_t o = ((size_t)n*32768 + vox0 + t)*16;
    *(ushort8v*)(out + o)     = *(ushort8v*)(lds + t*16);
    *(ushort8v*)(out + o + 8) = *(ushort8v*)(lds + t*16 + 8);
}

// prepack conv weights into MFMA B-fragment order (bf16), zero-padded to K=448 per ci-half
// layout: [half][ct][ks 14][kg 4][col 16][j 8]
__global__ void wfrag_k(const float* __restrict__ wt, ushort* __restrict__ out,
                        int CIN, int COT, int total)
{
    int i = blockIdx.x*256 + threadIdx.x;
    if (i >= total) return;
    int per_h = COT*7168;
    int h  = i / per_h;
    int r0 = i - h*per_h;
    int ct = r0 / 7168;
    int r  = r0 - ct*7168;
    int ks = r >> 9;
    int r2 = r & 511;
    int kg = r2 >> 7, col = (r2 >> 3) & 15, j = r2 & 7;
    int k = ks*32 + kg*8 + j;
    int nbr = k >> 4, ci = (k & 15) + h*16;
    out[i] = (nbr < 27) ? f2b(wt[((size_t)(ct*16 + col)*CIN + ci)*27 + nbr]) : (ushort)0;
}

// ---------------- implicit-GEMM MFMA conv + bias + BN-stats + max/min pool -----------
// channels-last bf16 in/out. Block: 4 waves, region x16 x y2 x z8 conv voxels.
// Wave w: z-pair {2w,2w+1}; 4 M-tiles = (dz',dy'); COT co-tiles of 16.
template<int CIHALVES, int COT, int D, int CIN, int COUT>
__global__ __launch_bounds__(256) void conv_mfma_k(
    const ushort* __restrict__ Xcl, const ushort* __restrict__ WfragG,
    const float* __restrict__ bias,
    ushort* __restrict__ outmax, ushort* __restrict__ outmin, float* __restrict__ stats)
{
    constexpr int PD = D/2;
    constexpr int XT = D/16, YT = D/2;
    __shared__ __align__(16) ushort Ast[17280];        // [z10][y4][x18][24 (16ci+pad)]
    __shared__ __align__(16) ushort Bfr[COT*7168];     // [ct][ks14][kg4][col16][j8]
    __shared__ float red[4*COT*32];

    int tid = threadIdx.x;
    int n = blockIdx.y;
    int bx = blockIdx.x;
    int xb = bx % XT, yb = (bx/XT) % YT, zb = bx/(XT*YT);
    int w = tid >> 6, l = tid & 63;
    int col = l & 15, kg = l >> 4;

    // per-lane A-fragment offsets per K-step (nbr = ks*2 + (l>>5); clamp invalid to 0)
    int laneoff[14];
    #pragma unroll
    for (int ks = 0; ks < 14; ++ks) {
        int nbr = ks*2 + (l >> 5);
        if (nbr >= 27) nbr = 0;                       // finite value x zero weight
        int dz = nbr/9, r9 = nbr - dz*9, dy = r9/3, dx = r9 - dy*3;
        laneoff[ks] = dz*1728 + dy*432 + (col + dx)*24 + ((l>>4)&1)*8;
    }
    int Mbase[4];
    #pragma unroll
    for (int mt = 0; mt < 4; ++mt)
        Mbase[mt] = (2*w + (mt>>1))*1728 + (mt&1)*432;

    f32x4 acc[4][COT];
    #pragma unroll
    for (int mt = 0; mt < 4; ++mt)
        #pragma unroll
        for (int ct = 0; ct < COT; ++ct)
            acc[mt][ct] = (f32x4){0.f,0.f,0.f,0.f};

    for (int h = 0; h < CIHALVES; ++h) {
        __syncthreads();
        // stage input tile [10z][4y][18x] vec16 (half h), zero halo
        for (int i = tid; i < 1440; i += 256) {
            int vec = i >> 1, hi8 = (i & 1) << 3;
            int z = vec/72, r = vec - z*72, y = r/18, x = r - y*18;
            int gz = zb*8 - 1 + z, gy = yb*2 - 1 + y, gx = xb*16 - 1 + x;
            ushort8v val = {0,0,0,0,0,0,0,0};
            if ((unsigned)gz < (unsigned)D && (unsigned)gy < (unsigned)D && (unsigned)gx < (unsigned)D) {
                size_t gi = (((size_t)n*D*D*D) + ((size_t)gz*D + gy)*D + gx)*CIN + h*16 + hi8;
                val = *(const ushort8v*)(Xcl + gi);
            }
            *(ushort8v*)(Ast + (vec)*24 + hi8) = val;
        }
        // copy B fragments for this half
        for (int i = tid; i < COT*896; i += 256)
            *(ushort8v*)(Bfr + i*8) = *(const ushort8v*)(WfragG + (size_t)h*COT*7168 + i*8);
        __syncthreads();

        #pragma unroll
        for (int ks = 0; ks < 14; ++ks) {
            short8v a[4];
            #pragma unroll
            for (int mt = 0; mt < 4; ++mt)
                a[mt] = *(const short8v*)(Ast + Mbase[mt] + laneoff[ks]);
            short8v bb[COT];
            #pragma unroll
            for (int ct = 0; ct < COT; ++ct)
                bb[ct] = *(const short8v*)(Bfr + ct*7168 + ks*512 + kg*128 + col*8);
            #pragma unroll
            for (int mt = 0; mt < 4; ++mt)
                #pragma unroll
                for (int ct = 0; ct < COT; ++ct)
                    acc[mt][ct] = __builtin_amdgcn_mfma_f32_16x16x32_bf16(a[mt], bb[ct], acc[mt][ct], 0, 0, 0);
        }
    }

    // epilogue: bias, stats, 2x2x2 pool (mt covers z/y pairs, j-pairs cover x)
    int zp = zb*4 + w, yp = yb;
    #pragma unroll
    for (int ct = 0; ct < COT; ++ct) {
        float bl = bias[ct*16 + col];
        float s = 0.f, q = 0.f;
        float mx0 = -1e30f, mx1 = -1e30f, mn0 = 1e30f, mn1 = 1e30f;
        #pragma unroll
        for (int mt = 0; mt < 4; ++mt) {
            #pragma unroll
            for (int j = 0; j < 4; ++j) {
                float v = acc[mt][ct][j] + bl;
                s += v; q = fmaf(v, v, q);
                if (j < 2) { mx0 = fmaxf(mx0, v); mn0 = fminf(mn0, v); }
                else       { mx1 = fmaxf(mx1, v); mn1 = fminf(mn1, v); }
            }
        }
        s += __shfl_xor(s, 16); s += __shfl_xor(s, 32);
        q += __shfl_xor(q, 16); q += __shfl_xor(q, 32);
        if (kg == 0) {
            red[((w*COT + ct)*16 + col)*2]     = s;
            red[((w*COT + ct)*16 + col)*2 + 1] = q;
        }
        size_t ob = (((size_t)((n*PD + zp)*PD + yp))*PD + xb*8 + kg*2)*COUT + ct*16 + col;
        outmax[ob]        = f2b(mx0);
        outmin[ob]        = f2b(mn0);
        outmax[ob + COUT] = f2b(mx1);
        outmin[ob + COUT] = f2b(mn1);
    }
    __syncthreads();
    if (tid < COT*32) {
        int ct = tid >> 5, r = tid & 31, c2 = r >> 1, sq = r & 1;
        float t = red[((0*COT + ct)*16 + c2)*2 + sq] + red[((1*COT + ct)*16 + c2)*2 + sq]
                + red[((2*COT + ct)*16 + c2)*2 + sq] + red[((3*COT + ct)*16 + c2)*2 + sq];
        unsafeAtomicAdd(&stats[(ct*16 + c2)*2 + sq], t);
    }
}

// channels-last bf16 pooled max/min -> BN+ReLU -> bf16
__global__ __launch_bounds__(256) void bn_select_cl23_k(
    const ushort* __restrict__ mx, const ushort* __restrict__ mn,
    const float* __restrict__ sc, const float* __restrict__ sh,
    ushort* __restrict__ out, int cmask, int total)
{
    int idx = blockIdx.x*256 + threadIdx.x;
    if (idx >= total) return;
    int ci = idx & cmask;
    float s = sc[ci];
    float v = b2f((s >= 0.f) ? mx[idx] : mn[idx]);
    out[idx] = f2b(fmaxf(fmaf(v, s, sh[ci]), 0.f));
}

// fc: X channels-last bf16 [16][512][64]; W k-index = c*512 + sp
__global__ __launch_bounds__(128) void fc_acc_k(
    const ushort* __restrict__ X, const float* __restrict__ W, float* __restrict__ featv)
{
    int t = threadIdx.x;
    int k0 = blockIdx.x*256;
    float acc[16];
    #pragma unroll
    for (int b = 0; b < 16; ++b) acc[b] = 0.f;
    for (int k = k0; k < k0 + 256; ++k) {
        float w = W[(size_t)k*128 + t];
        int c = k >> 9, sp = k & 511;
        #pragma unroll
        for (int b = 0; b < 16; ++b)
            acc[b] = fmaf(b2f(X[(size_t)((b*512 + sp))*64 + c]), w, acc[b]);
    }
    for (int b = 0; b < 16; ++b) unsafeAtomicAdd(featv + b*512 + t, acc[b]);
}

// ---------------- small dense layers ----------------
__global__ __launch_bounds__(256) void head_k(
    const float* __restrict__ X, const float* __restrict__ W, const float* __restrict__ b,
    float* __restrict__ O, int K, int Ncol, int relu)
{
    int t = blockIdx.x*256 + threadIdx.x;
    if (t >= 16*Ncol) return;
    int bi = t / Ncol, c = t % Ncol;
    float acc = b[c];
    for (int k = 0; k < K; ++k) acc = fmaf(X[bi*K + k], W[k*Ncol + c], acc);
    if (relu) acc = fmaxf(acc, 0.f);
    O[bi*Ncol + c] = acc;
}

__global__ void gebn_k(const float* __restrict__ g2, const float* __restrict__ g,
                       const float* __restrict__ b, float* __restrict__ featg)
{
    int c = threadIdx.x;
    float m = 0.f;
    for (int i = 0; i < 16; ++i) m += g2[i*128 + c];
    m *= (1.f/16.f);
    float v = 0.f;
    for (int i = 0; i < 16; ++i) { float d = g2[i*128 + c] - m; v += d*d; }
    v *= (1.f/16.f);
    float s = g[c] * rsqrtf(v + 1e-5f);
    for (int i = 0; i < 16; ++i)
        featg[i*512 + c] = fmaxf((g2[i*128 + c] - m)*s + b[c], 0.f);
}

__global__ void finalize_feat_k(float* __restrict__ feat, const float* __restrict__ cntm,
                                const float* __restrict__ cntz, const float* __restrict__ fcb)
{
    int t = blockIdx.x*256 + threadIdx.x;
    if (t >= 8192) return;
    int bi = t >> 9, c = t & 511;
    float v = feat[t];
    if      (c < 128) v /= fmaxf(cntm[bi], 1.f);
    else if (c < 256) v /= fmaxf(cntz[bi], 1.f);
    else if (c >= 384) v = fmaxf(v + fcb[c - 384], 0.f);
    feat[t] = v;
}

// =====================================================================================
extern "C" void kernel_launch(void* const* d_in, const int* in_sizes, int n_in,
                              void* d_out, int out_size, void* d_ws, size_t ws_size,
                              hipStream_t stream)
{
    const int*   mol_x  = (const int*)  d_in[0];
    const float* mol_q  = (const float*)d_in[1];
    const int*   mol_ei = (const int*)  d_in[2];
    const float* mol_ew = (const float*)d_in[3];
    const int*   mol_bv = (const int*)  d_in[4];
    const int*   zeo_x  = (const int*)  d_in[5];
    const int*   zeo_ei = (const int*)  d_in[6];
    const int*   zeo_bv = (const int*)  d_in[7];
    const float* voxel  = (const float*)d_in[8];
    const float* gattr  = (const float*)d_in[9];
    const float* ea  = (const float*)d_in[10];
    const float* ed  = (const float*)d_in[11];
    const float* ec  = (const float*)d_in[12];
    const float* eh  = (const float*)d_in[13];
    const float* ear = (const float*)d_in[14];
    const float* ech = (const float*)d_in[15];
    const float* mc1w=(const float*)d_in[16]; const float* mc1b=(const float*)d_in[17];
    const float* mc2w=(const float*)d_in[18]; const float* mc2b=(const float*)d_in[19];
    const float* zc1w=(const float*)d_in[20]; const float* zc1b=(const float*)d_in[21];
    const float* zc2w=(const float*)d_in[22]; const float* zc2b=(const float*)d_in[23];
    const float* cv1w=(const float*)d_in[24]; const float* cv1b=(const float*)d_in[25];
    const float* bn1g=(const float*)d_in[26]; const float* bn1b=(const float*)d_in[27];
    const float* cv2w=(const float*)d_in[28]; const float* cv2b=(const float*)d_in[29];
    const float* bn2g=(const float*)d_in[30]; const float* bn2b=(const float*)d_in[31];
    const float* cv3w=(const float*)d_in[32]; const float* cv3b=(const float*)d_in[33];
    const float* bn3g=(const float*)d_in[34]; const float* bn3b=(const float*)d_in[35];
    const float* fcw =(const float*)d_in[36]; const float* fcb =(const float*)d_in[37];
    const float* ge1w=(const float*)d_in[38]; const float* ge1b=(const float*)d_in[39];
    const float* ge2w=(const float*)d_in[40]; const float* ge2b=(const float*)d_in[41];
    const float* gbng=(const float*)d_in[42]; const float* gbnb=(const float*)d_in[43];
    const float* h1w =(const float*)d_in[44]; const float* h1b =(const float*)d_in[45];
    const float* h2w =(const float*)d_in[46]; const float* h2b =(const float*)d_in[47];
    const float* h3w =(const float*)d_in[48]; const float* h3b =(const float*)d_in[49];

    const int Nm = in_sizes[0]/6, Em = in_sizes[2]/2;
    const int Nz = in_sizes[5]/6, Ez = in_sizes[6]/2;

    float* WS = (float*)d_ws;
    float* A  = WS;                     // 16,777,216 floats
    float* Bb = WS + 16777216;          // 16,777,216 floats
    float* S  = WS + 33554432;
    // bf16 GNN activations
    ushort* X0 = (ushort*)A;
    ushort* X1 = (ushort*)A + 16777216;
    ushort* X2 = (ushort*)Bb;
    ushort* X3 = (ushort*)Bb + 16777216;
    // conv channels-last bf16 buffers
    ushort* Au = (ushort*)A;
    ushort* Xcl1 = (ushort*)Bb;                  // [16][32768][16]
    ushort* pm2  = Au;                           // [16][4096][32]
    ushort* pn2  = Au + 2097152;
    ushort* Xcl2 = Au + 4194304;
    ushort* pm3  = (ushort*)Bb;                  // [16][512][64]
    ushort* pn3  = (ushort*)Bb + 524288;
    ushort* Xcl3 = (ushort*)Bb + 1048576;
    float* deg  = S;
    float* dis  = S + 131072;
    float* csr_nrm = S + 262144;
    float* T    = S + 786432;
    float* cntm = S + 807040;
    float* cntz = S + 807056;
    float* feat = S + 807072;
    float* st1  = S + 815264; float* st2 = st1 + 32; float* st3 = st1 + 96;
    float* sc1  = S + 815488; float* sh1 = sc1 + 16;
    float* sc2  = sc1 + 32;   float* sh2 = sc1 + 64;
    float* sc3  = sc1 + 96;   float* sh3 = sc1 + 160;
    float* g1   = S + 815712;
    float* g2   = S + 816736;
    float* H1   = S + 818784;
    float* H2   = S + 826976;
    int* rowptr  = (int*)(S + 831072);
    int* cursor  = (int*)(S + 962176);
    int* csr_src = (int*)(S + 1093248);          // ends S+1617536
    ushort* wf2 = (ushort*)(S + 1617536);        // 14336 ush
    ushort* wf3 = (ushort*)(S + 1624704);        // 57344 ush (ends S+1653376)

    hipMemsetAsync(S, 0, (size_t)831072*sizeof(float), stream);

    // weight prepacks for MFMA conv (independent of activations)
    wfrag_k<<<56,256,0,stream>>>(cv2w, wf2, 16, 2, 14336);
    wfrag_k<<<224,256,0,stream>>>(cv3w, wf3, 32, 4, 57344);

    // ---------------- molecule branch ----------------
    build_tables_k<<<161,128,0,stream>>>(ea,ed,ec,eh,ear,ech, mc1w, T);
    init_deg_k   <<<Nm/256,256,0,stream>>>(deg, Nm);
    deg_scatter_k<<<Em/256,256,0,stream>>>(mol_ei+Em, mol_ew, deg, Em);
    dis_k        <<<Nm/256,256,0,stream>>>(deg, dis, Nm);
    hipMemsetAsync(cursor, 0, (size_t)Nm*sizeof(int), stream);
    count_in_k   <<<Em/256,256,0,stream>>>(mol_ei+Em, cursor, Em);
    scan_k       <<<1,1024,0,stream>>>(cursor, rowptr, Nm);
    fill_csr_k   <<<Em/256,256,0,stream>>>(mol_ei, mol_ei+Em, mol_ew, dis, cursor, csr_src, csr_nrm, Em);
    embed_lookup_k<<<Nm/8,256,0,stream>>>(mol_x, mol_q, T, mc1w + 112*128, X0, Nm);
    gcn_gather_k <<<Nm/8,256,0,stream>>>(X0, rowptr, csr_src, csr_nrm, dis, mc1b, X1, Nm);
    gemm_mfma_k  <<<Nm/64,256,0,stream>>>(X1, mc2w, X2, Nm);
    gcn_gather_k <<<Nm/8,256,0,stream>>>(X2, rowptr, csr_src, csr_nrm, dis, mc2b, X3, Nm);
    count_batch_k<<<Nm/256,256,0,stream>>>(mol_bv, cntm, Nm);
    mean_pool_sum_k<<<256,128,0,stream>>>(X3, mol_bv, feat + 0, (Nm+255)/256, Nm);

    // ---------------- zeolite branch ----------------
    build_tables_k<<<161,128,0,stream>>>(ea,ed,ec,eh,ear,ech, zc1w, T);
    init_deg_k   <<<Nz/256,256,0,stream>>>(deg, Nz);
    deg_scatter_k<<<Ez/256,256,0,stream>>>(zeo_ei+Ez, nullptr, deg, Ez);
    dis_k        <<<Nz/256,256,0,stream>>>(deg, dis, Nz);
    hipMemsetAsync(cursor, 0, (size_t)Nz*sizeof(int), stream);
    count_in_k   <<<Ez/256,256,0,stream>>>(zeo_ei+Ez, cursor, Ez);
    scan_k       <<<1,1024,0,stream>>>(cursor, rowptr, Nz);
    fill_csr_k   <<<Ez/256,256,0,stream>>>(zeo_ei, zeo_ei+Ez, nullptr, dis, cursor, csr_src, csr_nrm, Ez);
    embed_lookup_k<<<Nz/8,256,0,stream>>>(zeo_x, nullptr, T, nullptr, X0, Nz);
    gcn_gather_k <<<Nz/8,256,0,stream>>>(X0, rowptr, csr_src, csr_nrm, dis, zc1b, X1, Nz);
    gemm_mfma_k  <<<Nz/64,256,0,stream>>>(X1, zc2w, X2, Nz);
    gcn_gather_k <<<Nz/8,256,0,stream>>>(X2, rowptr, csr_src, csr_nrm, dis, zc2b, X3, Nz);
    count_batch_k<<<Nz/256,256,0,stream>>>(zeo_bv, cntz, Nz);
    mean_pool_sum_k<<<256,128,0,stream>>>(X3, zeo_bv, feat + 128, (Nz+255)/256, Nz);

    // ---------------- voxel CNN ----------------
    // layer 1: direct conv, fp32 NCDHW max/min into A
    conv_pool4_k<2,16,64,8,false><<<dim3(128,2,16),256,0,stream>>>(
        voxel, nullptr, nullptr, nullptr, cv1w, cv1b, A, A+8388608, st1);
    bn_final_k<<<1,64,0,stream>>>(st1, bn1g, bn1b, sc1, sh1, 16, 1.f/(16.f*262144.f));
    bn_select_cl1_k<<<dim3(128,16),256,0,stream>>>(A, A+8388608, sc1, sh1, Xcl1);

    // layer 2: implicit-GEMM MFMA  (Xcl1 in Bb -> pooled bf16 CL in A)
    conv_mfma_k<1,2,32,16,32><<<dim3(128,16),256,0,stream>>>(Xcl1, wf2, cv2b, pm2, pn2, st2);
    bn_final_k<<<1,64,0,stream>>>(st2, bn2g, bn2b, sc2, sh2, 32, 1.f/(16.f*32768.f));
    bn_select_cl23_k<<<8192,256,0,stream>>>(pm2, pn2, sc2, sh2, Xcl2, 31, 2097152);

    // layer 3: implicit-GEMM MFMA  (Xcl2 in A -> pooled bf16 CL in Bb)
    conv_mfma_k<2,4,16,32,64><<<dim3(16,16),256,0,stream>>>(Xcl2, wf3, cv3b, pm3, pn3, st3);
    bn_final_k<<<1,64,0,stream>>>(st3, bn3g, bn3b, sc3, sh3, 64, 1.f/(16.f*4096.f));
    bn_select_cl23_k<<<2048,256,0,stream>>>(pm3, pn3, sc3, sh3, Xcl3, 63, 524288);

    fc_acc_k<<<128,128,0,stream>>>(Xcl3, fcw, feat + 384);

    // ---------------- global encoder ----------------
    head_k<<<4,256,0,stream>>>(gattr, ge1w, ge1b, g1, 17, 64, 1);
    head_k<<<8,256,0,stream>>>(g1, ge2w, ge2b, g2, 64, 128, 0);
    gebn_k<<<1,128,0,stream>>>(g2, gbng, gbnb, feat + 256);

    // ---------------- fusion head ----------------
    finalize_feat_k<<<32,256,0,stream>>>(feat, cntm, cntz, fcb);
    head_k<<<32,256,0,stream>>>(feat, h1w, h1b, H1, 512, 512, 1);
    head_k<<<16,256,0,stream>>>(H1, h2w, h2b, H2, 512, 256, 1);
    head_k<<<1,256,0,stream>>>(H2, h3w, h3b, (float*)d_out, 256, 3, 0);
}

// Round 10
// 1457.775 us; speedup vs baseline: 1.9151x; 1.3987x over previous
//
#include <hip/hip_runtime.h>
#include <math.h>

#define DEV static __device__ __forceinline__

DEV float4 ld4(const float* p){ return *(const float4*)p; }
DEV float2 ld2(const float* p){ return *(const float2*)p; }
DEV void   st4(float* p, float4 v){ *(float4*)p = v; }
DEV float4 f4add(float4 a, float4 b){ return make_float4(a.x+b.x,a.y+b.y,a.z+b.z,a.w+b.w); }
DEV float4 f4fma(float s, float4 a, float4 c){ return make_float4(fmaf(s,a.x,c.x),fmaf(s,a.y,c.y),fmaf(s,a.z,c.z),fmaf(s,a.w,c.w)); }
DEV float4 f4relu(float4 a){ return make_float4(fmaxf(a.x,0.f),fmaxf(a.y,0.f),fmaxf(a.z,0.f),fmaxf(a.w,0.f)); }

// bf16 helpers (RNE pack, exact unpack)
DEV float  b2f(ushort u){ return __uint_as_float(((unsigned)u) << 16); }
DEV ushort f2b(float f){
    unsigned u = __float_as_uint(f);
    return (ushort)((u + 0x7FFFu + ((u >> 16) & 1u)) >> 16);
}
DEV float4 b2f4(ushort4 v){ return make_float4(b2f(v.x), b2f(v.y), b2f(v.z), b2f(v.w)); }
DEV ushort4 f2b4(float4 v){ ushort4 o; o.x=f2b(v.x); o.y=f2b(v.y); o.z=f2b(v.z); o.w=f2b(v.w); return o; }

typedef __attribute__((ext_vector_type(8))) short short8v;            // 8 bf16 = 4 VGPR
typedef __attribute__((ext_vector_type(8))) unsigned short ushort8v;
typedef __attribute__((ext_vector_type(4))) float f32x4;

// ---------------- GNN: embedding tables  T[161][128] = emb_f @ W_slice ----------------
__global__ __launch_bounds__(128) void build_tables_k(
    const float* __restrict__ ea, const float* __restrict__ ed, const float* __restrict__ ec,
    const float* __restrict__ eh, const float* __restrict__ ear, const float* __restrict__ ech,
    const float* __restrict__ Wm, float* __restrict__ T)
{
    int r = blockIdx.x, c = threadIdx.x;
    const float* e; int dim, woff, rl;
    if      (r < 120) { e=ea;  dim=64; woff=0;   rl=r; }
    else if (r < 132) { e=ed;  dim=16; woff=64;  rl=r-120; }
    else if (r < 147) { e=ec;  dim=16; woff=80;  rl=r-132; }
    else if (r < 155) { e=eh;  dim=8;  woff=96;  rl=r-147; }
    else if (r < 157) { e=ear; dim=4;  woff=104; rl=r-155; }
    else              { e=ech; dim=4;  woff=108; rl=r-157; }
    float acc = 0.f;
    for (int k = 0; k < dim; ++k) acc += e[rl*dim + k] * Wm[(woff + k)*128 + c];
    T[r*128 + c] = acc;
}

__global__ __launch_bounds__(256) void embed_lookup_k(
    const int* __restrict__ xi, const float* __restrict__ charge,
    const float* __restrict__ T, const float* __restrict__ wq,
    ushort* __restrict__ H, int N)
{
    int t = threadIdx.x;
    int node = blockIdx.x*8 + (t >> 5);
    if (node >= N) return;
    int c = (t & 31)*4;
    const int* xp = xi + node*6;
    float4 acc = ld4(T + (       xp[0])*128 + c);
    acc = f4add(acc, ld4(T + (120+xp[1])*128 + c));
    acc = f4add(acc, ld4(T + (132+xp[2])*128 + c));
    acc = f4add(acc, ld4(T + (147+xp[3])*128 + c));
    acc = f4add(acc, ld4(T + (155+xp[4])*128 + c));
    acc = f4add(acc, ld4(T + (157+xp[5])*128 + c));
    if (charge) acc = f4fma(charge[node], ld4(wq + c), acc);
    *(ushort4*)(H + (size_t)node*128 + c) = f2b4(acc);
}

// ---------------- GCN degree / norm / CSR build ----------------
__global__ void init_deg_k(float* deg, int N){ int i = blockIdx.x*256+threadIdx.x; if (i<N) deg[i]=1.f; }

__global__ void deg_scatter_k(const int* __restrict__ col, const float* __restrict__ ew, float* deg, int E){
    int e = blockIdx.x*256+threadIdx.x; if (e>=E) return;
    unsafeAtomicAdd(deg + col[e], ew ? ew[e] : 1.f);
}

__global__ void dis_k(const float* __restrict__ deg, float* __restrict__ dis, int N){
    int i = blockIdx.x*256+threadIdx.x; if (i<N) dis[i] = 1.f/sqrtf(deg[i]);
}

__global__ void count_in_k(const int* __restrict__ col, int* __restrict__ cnt, int E){
    int e = blockIdx.x*256+threadIdx.x; if (e>=E) return;
    atomicAdd(&cnt[col[e]], 1);
}

// ---- multi-block exclusive scan (3 phases; 1024 elems / block) ----
__global__ __launch_bounds__(256) void blocksum_k(const int* __restrict__ cnt, int* __restrict__ bsum, int N){
    int b = blockIdx.x, t = threadIdx.x;
    int base = b*1024 + t*4;
    int s = 0;
    if (base + 3 < N) { int4 v = *(const int4*)(cnt + base); s = v.x + v.y + v.z + v.w; }
    else { for (int i = 0; i < 4; ++i) { int idx = base + i; if (idx < N) s += cnt[idx]; } }
    __shared__ int red[256];
    red[t] = s; __syncthreads();
    for (int off = 128; off; off >>= 1) { if (t < off) red[t] += red[t+off]; __syncthreads(); }
    if (!t) bsum[b] = red[0];
}

__global__ __launch_bounds__(256) void scan_bsum_k(int* __restrict__ bsum, int NB){
    int t = threadIdx.x;
    __shared__ int sh[256];
    sh[t] = (t < NB) ? bsum[t] : 0;
    __syncthreads();
    for (int off = 1; off < 256; off <<= 1) {
        int v = (t >= off) ? sh[t-off] : 0;
        __syncthreads();
        sh[t] += v;
        __syncthreads();
    }
    if (t < NB) bsum[t] = (t == 0) ? 0 : sh[t-1];
}

// reads counts from cur, writes rowptr + resets cur to run starts (same buffer ok: per-thread RAW only)
__global__ __launch_bounds__(256) void scan_apply_k(int* cur, const int* __restrict__ bsum,
                                                    int* __restrict__ rowptr, int N, int E){
    int b = blockIdx.x, t = threadIdx.x;
    int base = b*1024 + t*4;
    int c[4]; int s = 0;
    #pragma unroll
    for (int i = 0; i < 4; ++i) { int idx = base + i; c[i] = (idx < N) ? cur[idx] : 0; s += c[i]; }
    __shared__ int sh[256];
    sh[t] = s; __syncthreads();
    for (int off = 1; off < 256; off <<= 1) {
        int v = (t >= off) ? sh[t-off] : 0;
        __syncthreads();
        sh[t] += v;
        __syncthreads();
    }
    int run = bsum[b] + ((t == 0) ? 0 : sh[t-1]);
    #pragma unroll
    for (int i = 0; i < 4; ++i) {
        int idx = base + i;
        if (idx < N) { rowptr[idx] = run; cur[idx] = run; run += c[i]; }
    }
    if (b == 0 && t == 0) rowptr[N] = E;
}

__global__ void fill_csr_k(const int* __restrict__ row, const int* __restrict__ col,
                           const float* __restrict__ ew, const float* __restrict__ dis,
                           int* __restrict__ cursor, int* __restrict__ csr_src,
                           float* __restrict__ csr_nrm, int E)
{
    int e = blockIdx.x*256+threadIdx.x; if (e>=E) return;
    int r = row[e], c = col[e];
    int pos = atomicAdd(&cursor[c], 1);
    csr_src[pos] = r;
    csr_nrm[pos] = dis[r] * (ew ? ew[e] : 1.f) * dis[c];
}

// O[i] = bias + dis[i]^2 * H[i] + sum_j nrm_j * H[src_j]   -- bf16 in/out, fp32 math
__global__ __launch_bounds__(256) void gcn_gather_k(
    const ushort* __restrict__ H, const int* __restrict__ rowptr,
    const int* __restrict__ csr_src, const float* __restrict__ csr_nrm,
    const float* __restrict__ dis, const float* __restrict__ bias,
    ushort* __restrict__ O, int N)
{
    int node = blockIdx.x*8 + (threadIdx.x >> 5);
    if (node >= N) return;
    int lane = (threadIdx.x & 31)*4;
    float s = dis[node]; s *= s;
    float4 h = b2f4(*(const ushort4*)(H + (size_t)node*128 + lane));
    float4 b = ld4(bias + lane);
    float4 acc = f4fma(s, h, b);
    int j = rowptr[node], end = rowptr[node+1];
    for (; j + 4 <= end; j += 4) {
        int   s0 = csr_src[j],   s1 = csr_src[j+1], s2 = csr_src[j+2], s3 = csr_src[j+3];
        float n0 = csr_nrm[j],   n1 = csr_nrm[j+1], n2 = csr_nrm[j+2], n3 = csr_nrm[j+3];
        float4 h0 = b2f4(*(const ushort4*)(H + (size_t)s0*128 + lane));
        float4 h1 = b2f4(*(const ushort4*)(H + (size_t)s1*128 + lane));
        float4 h2 = b2f4(*(const ushort4*)(H + (size_t)s2*128 + lane));
        float4 h3 = b2f4(*(const ushort4*)(H + (size_t)s3*128 + lane));
        acc = f4fma(n0, h0, acc);
        acc = f4fma(n1, h1, acc);
        acc = f4fma(n2, h2, acc);
        acc = f4fma(n3, h3, acc);
    }
    for (; j < end; ++j) {
        float4 h0 = b2f4(*(const ushort4*)(H + (size_t)csr_src[j]*128 + lane));
        acc = f4fma(csr_nrm[j], h0, acc);
    }
    *(ushort4*)(O + (size_t)node*128 + lane) = f2b4(acc);
}

// O = relu(A) @ W via bf16 MFMA; A:[N,128] bf16, W:[128,128] f32, O bf16
__global__ __launch_bounds__(256) void gemm_mfma_k(
    const ushort* __restrict__ A, const float* __restrict__ W,
    ushort* __restrict__ O, int N)
{
    __shared__ ushort WsF[16384];
    __shared__ ushort As[64*136];
    int t = threadIdx.x;
    for (int i = t; i < 16384; i += 256) {
        int j = i & 7, col = (i >> 3) & 15, kg = (i >> 7) & 3, ks = (i >> 9) & 3, ct = i >> 11;
        WsF[i] = f2b(W[(ks*32 + kg*8 + j)*128 + ct*16 + col]);
    }
    int row0 = blockIdx.x*64;
    for (int i = t; i < 64*32; i += 256) {
        int r = i >> 5, c4 = (i & 31)*4;
        ushort4 v = *(const ushort4*)(A + (size_t)(row0 + r)*128 + c4);
        v.x = (v.x & 0x8000) ? 0 : v.x;
        v.y = (v.y & 0x8000) ? 0 : v.y;
        v.z = (v.z & 0x8000) ? 0 : v.z;
        v.w = (v.w & 0x8000) ? 0 : v.w;
        *(ushort4*)(As + r*136 + c4) = v;
    }
    __syncthreads();
    int w = t >> 6, l = t & 63;
    int m16 = l & 15, kg = l >> 4;
    short8v af[4];
    #pragma unroll
    for (int ks = 0; ks < 4; ++ks)
        af[ks] = *(const short8v*)(As + (w*16 + m16)*136 + ks*32 + kg*8);
    #pragma unroll
    for (int ct = 0; ct < 8; ++ct) {
        f32x4 acc = {0.f, 0.f, 0.f, 0.f};
        #pragma unroll
        for (int ks = 0; ks < 4; ++ks) {
            short8v bf = *(const short8v*)(WsF + ((ct*4 + ks)*4 + kg)*128 + m16*8);
            acc = __builtin_amdgcn_mfma_f32_16x16x32_bf16(af[ks], bf, acc, 0, 0, 0);
        }
        int col = ct*16 + m16;
        int rbase = row0 + w*16 + kg*4;
        #pragma unroll
        for (int j = 0; j < 4; ++j)
            O[(size_t)(rbase + j)*128 + col] = f2b(acc[j]);
    }
}

// ---------------- mean pool (bf16 input) ----------------
__global__ __launch_bounds__(128) void mean_pool_sum_k(
    const ushort* __restrict__ X, const int* __restrict__ bv,
    float* __restrict__ featp, int chunk, int N)
{
    __shared__ float acc[16*128];
    int t = threadIdx.x;
    for (int b = 0; b < 16; ++b) acc[b*128 + t] = 0.f;
    int i0 = blockIdx.x * chunk;
    int iend = min(i0 + chunk, N);
    int bcur = bv[i0];
    float r = 0.f;
    for (int i = i0; i < iend; ++i) {
        int b = bv[i];
        if (b != bcur) { acc[bcur*128 + t] += r; r = 0.f; bcur = b; }
        r += fmaxf(b2f(X[(size_t)i*128 + t]), 0.f);
    }
    acc[bcur*128 + t] += r;
    for (int b = 0; b < 16; ++b) {
        float v = acc[b*128 + t];
        if (v != 0.f) unsafeAtomicAdd(featp + b*512 + t, v);
    }
}

__global__ void count_batch_k(const int* __restrict__ bv, float* __restrict__ cnt, int N){
    __shared__ int h[16];
    int t = threadIdx.x;
    if (t < 16) h[t] = 0;
    __syncthreads();
    int i = blockIdx.x*256 + t;
    if (i < N) atomicAdd(&h[bv[i]], 1);
    __syncthreads();
    if (t < 16 && h[t]) unsafeAtomicAdd(&cnt[t], (float)h[t]);
}

// ---------------- conv layer 1: direct LDS-tiled (Cin=2), fp32 NCDHW out -------------
template<int CIN, int COUT, int D, int CL, bool BNIN>
__global__ __launch_bounds__(256) void conv_pool4_k(
    const float* __restrict__ inmax, const float* __restrict__ inmin,
    const float* __restrict__ scin, const float* __restrict__ shin,
    const float* __restrict__ wt, const float* __restrict__ bias,
    float* __restrict__ outmax, float* __restrict__ outmin, float* __restrict__ stats)
{
    constexpr int PD = D/2;
    constexpr int NTX = (PD >= 8) ? PD/8 : 1;
    constexpr int SY = 20, SZ = 20*18;
    __shared__ float tileL[10*SZ];
    __shared__ float swred[4*2*CL];

    int tid = threadIdx.x;
    int co0 = blockIdx.y * CL;
    int n   = blockIdx.z;

    int tb = blockIdx.x;
    int tx = tb % NTX, ty = (tb / NTX) % NTX, tz = tb / (NTX*NTX);
    int pw = tid & 7, ph = (tid >> 3) & 7, pd = tid >> 6;
    int ix0 = tx*16 - 1, iy0 = ty*16 - 1, iz0 = tz*8 - 1;

    int sy0 = tid / 18, sx0 = tid - sy0*18;
    int sp1 = tid + 256;
    int sy1 = sp1 / 18, sx1 = sp1 - sy1*18;
    bool has1 = (sp1 < 324);

    float acc[CL][8];
    #pragma unroll
    for (int cl = 0; cl < CL; ++cl)
        #pragma unroll
        for (int p = 0; p < 8; ++p) acc[cl][p] = 0.f;

    int base = (2*pd)*SZ + (2*ph)*SY + 2*pw;

    for (int ci = 0; ci < CIN; ++ci) {
        __syncthreads();
        float s_in = 0.f, sh_in = 0.f;
        if (BNIN) { s_in = scin[ci]; sh_in = shin[ci]; }
        const float* ib;
        if (BNIN) ib = (s_in >= 0.f) ? inmax + ((size_t)(n*CIN + ci))*((size_t)D*D*D)
                                     : inmin + ((size_t)(n*CIN + ci))*((size_t)D*D*D);
        else      ib = inmax + ((size_t)(n*CIN + ci))*((size_t)D*D*D);

        #pragma unroll 2
        for (int z = 0; z < 10; ++z) {
            int gz = iz0 + z; bool zok = (unsigned)gz < (unsigned)D;
            {
                int gy = iy0 + sy0, gx = ix0 + sx0;
                float val = 0.f;
                if (zok && (unsigned)gy < (unsigned)D && (unsigned)gx < (unsigned)D) {
                    float v = ib[((size_t)gz*D + gy)*D + gx];
                    val = BNIN ? fmaxf(fmaf(v, s_in, sh_in), 0.f) : v;
                }
                tileL[z*SZ + sy0*SY + sx0] = val;
            }
            if (has1) {
                int gy = iy0 + sy1, gx = ix0 + sx1;
                float val = 0.f;
                if (zok && (unsigned)gy < (unsigned)D && (unsigned)gx < (unsigned)D) {
                    float v = ib[((size_t)gz*D + gy)*D + gx];
                    val = BNIN ? fmaxf(fmaf(v, s_in, sh_in), 0.f) : v;
                }
                tileL[z*SZ + sy1*SY + sx1] = val;
            }
        }
        __syncthreads();

        const float* wb = wt + ((size_t)co0*CIN + ci)*27;
        #pragma unroll
        for (int r = 0; r < 9; ++r) {
            const int kd = r/3, kh = r%3;
            float vv[2][2][4];
            #pragma unroll
            for (int dz = 0; dz < 2; ++dz)
            #pragma unroll
            for (int dy = 0; dy < 2; ++dy) {
                const float* rp = &tileL[base + (dz+kd)*SZ + (dy+kh)*SY];
                float2 p0 = ld2(rp), p1 = ld2(rp+2);
                vv[dz][dy][0]=p0.x; vv[dz][dy][1]=p0.y; vv[dz][dy][2]=p1.x; vv[dz][dy][3]=p1.y;
            }
            #pragma unroll
            for (int cl = 0; cl < CL; ++cl) {
                const float* wc = wb + (size_t)cl*CIN*27 + r*3;
                float w0 = wc[0], w1 = wc[1], w2 = wc[2];
                #pragma unroll
                for (int dz = 0; dz < 2; ++dz)
                #pragma unroll
                for (int dy = 0; dy < 2; ++dy)
                #pragma unroll
                for (int dx = 0; dx < 2; ++dx) {
                    int p = dz*4 + dy*2 + dx;
                    acc[cl][p] = fmaf(w0, vv[dz][dy][dx+0], acc[cl][p]);
                    acc[cl][p] = fmaf(w1, vv[dz][dy][dx+1], acc[cl][p]);
                    acc[cl][p] = fmaf(w2, vv[dz][dy][dx+2], acc[cl][p]);
                }
            }
        }
    }

    int ow = tx*8 + pw, oh = ty*8 + ph, od = tz*4 + pd;
    float ssum[CL], ssq[CL];
    size_t obase = ((size_t)n*COUT + co0)*((size_t)PD*PD*PD) + ((size_t)od*PD + oh)*PD + ow;
    #pragma unroll
    for (int cl = 0; cl < CL; ++cl) {
        float cb = bias[co0 + cl];
        float mx = -1e30f, mn = 1e30f, s = 0.f, q = 0.f;
        #pragma unroll
        for (int p = 0; p < 8; ++p) {
            float val = acc[cl][p] + cb;
            mx = fmaxf(mx, val); mn = fminf(mn, val);
            s += val; q = fmaf(val, val, q);
        }
        ssum[cl] = s; ssq[cl] = q;
        outmax[obase + (size_t)cl*(PD*PD*PD)] = mx;
        outmin[obase + (size_t)cl*(PD*PD*PD)] = mn;
    }

    int lane = tid & 63, wid = tid >> 6;
    #pragma unroll
    for (int cl = 0; cl < CL; ++cl) {
        float a_ = ssum[cl], b_ = ssq[cl];
        #pragma unroll
        for (int off = 32; off; off >>= 1) {
            a_ += __shfl_down(a_, off, 64);
            b_ += __shfl_down(b_, off, 64);
        }
        if (lane == 0) { swred[wid*2*CL + cl*2] = a_; swred[wid*2*CL + cl*2 + 1] = b_; }
    }
    __syncthreads();
    if (tid < 2*CL) {
        float t = swred[tid] + swred[2*CL + tid] + swred[4*CL + tid] + swred[6*CL + tid];
        unsafeAtomicAdd(&stats[co0*2 + tid], t);
    }
}

__global__ void bn_final_k(const float* __restrict__ stats, const float* __restrict__ g,
                           const float* __restrict__ b, float* __restrict__ sc, float* __restrict__ sh,
                           int C, float invN)
{
    int c = threadIdx.x; if (c >= C) return;
    float m = stats[c*2] * invN;
    float v = stats[c*2+1] * invN - m*m;
    float s = g[c] * rsqrtf(v + 1e-5f);
    sc[c] = s; sh[c] = b[c] - m*s;
}

// conv1 fp32 NCDHW max/min -> BN+ReLU -> channels-last bf16 [n][32^3][16]
__global__ __launch_bounds__(256) void bn_select_cl1_k(
    const float* __restrict__ inmax, const float* __restrict__ inmin,
    const float* __restrict__ sc, const float* __restrict__ sh,
    ushort* __restrict__ out)
{
    __shared__ ushort lds[256*16];
    int t = threadIdx.x;
    int vox0 = blockIdx.x*256;
    int n = blockIdx.y;
    for (int ci = 0; ci < 16; ++ci) {
        float s = sc[ci], shv = sh[ci];
        size_t gi = ((size_t)(n*16 + ci))*32768 + vox0 + t;
        float v = (s >= 0.f) ? inmax[gi] : inmin[gi];
        lds[t*16 + ci] = f2b(fmaxf(fmaf(v, s, shv), 0.f));
    }
    __syncthreads();
    size_t o = ((size_t)n*32768 + vox0 + t)*16;
    *(ushort8v*)(out + o)     = *(ushort8v*)(lds + t*16);
    *(ushort8v*)(out + o + 8) = *(ushort8v*)(lds + t*16 + 8);
}

// prepack conv weights into MFMA B-fragment order (bf16), zero-padded to K=448 per ci-half
__global__ void wfrag_k(const float* __restrict__ wt, ushort* __restrict__ out,
                        int CIN, int COT, int total)
{
    int i = blockIdx.x*256 + threadIdx.x;
    if (i >= total) return;
    int per_h = COT*7168;
    int h  = i / per_h;
    int r0 = i - h*per_h;
    int ct = r0 / 7168;
    int r  = r0 - ct*7168;
    int ks = r >> 9;
    int r2 = r & 511;
    int kg = r2 >> 7, col = (r2 >> 3) & 15, j = r2 & 7;
    int k = ks*32 + kg*8 + j;
    int nbr = k >> 4, ci = (k & 15) + h*16;
    out[i] = (nbr < 27) ? f2b(wt[((size_t)(ct*16 + col)*CIN + ci)*27 + nbr]) : (ushort)0;
}

// ---------------- implicit-GEMM MFMA conv + bias + BN-stats + max/min pool -----------
template<int CIHALVES, int COT, int D, int CIN, int COUT>
__global__ __launch_bounds__(256) void conv_mfma_k(
    const ushort* __restrict__ Xcl, const ushort* __restrict__ WfragG,
    const float* __restrict__ bias,
    ushort* __restrict__ outmax, ushort* __restrict__ outmin, float* __restrict__ stats)
{
    constexpr int PD = D/2;
    constexpr int XT = D/16, YT = D/2;
    __shared__ __align__(16) ushort Ast[17280];
    __shared__ __align__(16) ushort Bfr[COT*7168];
    __shared__ float red[4*COT*32];

    int tid = threadIdx.x;
    int n = blockIdx.y;
    int bx = blockIdx.x;
    int xb = bx % XT, yb = (bx/XT) % YT, zb = bx/(XT*YT);
    int w = tid >> 6, l = tid & 63;
    int col = l & 15, kg = l >> 4;

    int laneoff[14];
    #pragma unroll
    for (int ks = 0; ks < 14; ++ks) {
        int nbr = ks*2 + (l >> 5);
        if (nbr >= 27) nbr = 0;
        int dz = nbr/9, r9 = nbr - dz*9, dy = r9/3, dx = r9 - dy*3;
        laneoff[ks] = dz*1728 + dy*432 + (col + dx)*24 + ((l>>4)&1)*8;
    }
    int Mbase[4];
    #pragma unroll
    for (int mt = 0; mt < 4; ++mt)
        Mbase[mt] = (2*w + (mt>>1))*1728 + (mt&1)*432;

    f32x4 acc[4][COT];
    #pragma unroll
    for (int mt = 0; mt < 4; ++mt)
        #pragma unroll
        for (int ct = 0; ct < COT; ++ct)
            acc[mt][ct] = (f32x4){0.f,0.f,0.f,0.f};

    for (int h = 0; h < CIHALVES; ++h) {
        __syncthreads();
        for (int i = tid; i < 1440; i += 256) {
            int vec = i >> 1, hi8 = (i & 1) << 3;
            int z = vec/72, r = vec - z*72, y = r/18, x = r - y*18;
            int gz = zb*8 - 1 + z, gy = yb*2 - 1 + y, gx = xb*16 - 1 + x;
            ushort8v val = {0,0,0,0,0,0,0,0};
            if ((unsigned)gz < (unsigned)D && (unsigned)gy < (unsigned)D && (unsigned)gx < (unsigned)D) {
                size_t gi = (((size_t)n*D*D*D) + ((size_t)gz*D + gy)*D + gx)*CIN + h*16 + hi8;
                val = *(const ushort8v*)(Xcl + gi);
            }
            *(ushort8v*)(Ast + (vec)*24 + hi8) = val;
        }
        for (int i = tid; i < COT*896; i += 256)
            *(ushort8v*)(Bfr + i*8) = *(const ushort8v*)(WfragG + (size_t)h*COT*7168 + i*8);
        __syncthreads();

        #pragma unroll
        for (int ks = 0; ks < 14; ++ks) {
            short8v a[4];
            #pragma unroll
            for (int mt = 0; mt < 4; ++mt)
                a[mt] = *(const short8v*)(Ast + Mbase[mt] + laneoff[ks]);
            short8v bb[COT];
            #pragma unroll
            for (int ct = 0; ct < COT; ++ct)
                bb[ct] = *(const short8v*)(Bfr + ct*7168 + ks*512 + kg*128 + col*8);
            #pragma unroll
            for (int mt = 0; mt < 4; ++mt)
                #pragma unroll
                for (int ct = 0; ct < COT; ++ct)
                    acc[mt][ct] = __builtin_amdgcn_mfma_f32_16x16x32_bf16(a[mt], bb[ct], acc[mt][ct], 0, 0, 0);
        }
    }

    int zp = zb*4 + w, yp = yb;
    #pragma unroll
    for (int ct = 0; ct < COT; ++ct) {
        float bl = bias[ct*16 + col];
        float s = 0.f, q = 0.f;
        float mx0 = -1e30f, mx1 = -1e30f, mn0 = 1e30f, mn1 = 1e30f;
        #pragma unroll
        for (int mt = 0; mt < 4; ++mt) {
            #pragma unroll
            for (int j = 0; j < 4; ++j) {
                float v = acc[mt][ct][j] + bl;
                s += v; q = fmaf(v, v, q);
                if (j < 2) { mx0 = fmaxf(mx0, v); mn0 = fminf(mn0, v); }
                else       { mx1 = fmaxf(mx1, v); mn1 = fminf(mn1, v); }
            }
        }
        s += __shfl_xor(s, 16); s += __shfl_xor(s, 32);
        q += __shfl_xor(q, 16); q += __shfl_xor(q, 32);
        if (kg == 0) {
            red[((w*COT + ct)*16 + col)*2]     = s;
            red[((w*COT + ct)*16 + col)*2 + 1] = q;
        }
        size_t ob = (((size_t)((n*PD + zp)*PD + yp))*PD + xb*8 + kg*2)*COUT + ct*16 + col;
        outmax[ob]        = f2b(mx0);
        outmin[ob]        = f2b(mn0);
        outmax[ob + COUT] = f2b(mx1);
        outmin[ob + COUT] = f2b(mn1);
    }
    __syncthreads();
    if (tid < COT*32) {
        int ct = tid >> 5, r = tid & 31, c2 = r >> 1, sq = r & 1;
        float t = red[((0*COT + ct)*16 + c2)*2 + sq] + red[((1*COT + ct)*16 + c2)*2 + sq]
                + red[((2*COT + ct)*16 + c2)*2 + sq] + red[((3*COT + ct)*16 + c2)*2 + sq];
        unsafeAtomicAdd(&stats[(ct*16 + c2)*2 + sq], t);
    }
}

// channels-last bf16 pooled max/min -> BN+ReLU -> bf16
__global__ __launch_bounds__(256) void bn_select_cl23_k(
    const ushort* __restrict__ mx, const ushort* __restrict__ mn,
    const float* __restrict__ sc, const float* __restrict__ sh,
    ushort* __restrict__ out, int cmask, int total)
{
    int idx = blockIdx.x*256 + threadIdx.x;
    if (idx >= total) return;
    int ci = idx & cmask;
    float s = sc[ci];
    float v = b2f((s >= 0.f) ? mx[idx] : mn[idx]);
    out[idx] = f2b(fmaxf(fmaf(v, s, sh[ci]), 0.f));
}

// fc: X channels-last bf16 [16][512][64]; W k-index = c*512 + sp
__global__ __launch_bounds__(128) void fc_acc_k(
    const ushort* __restrict__ X, const float* __restrict__ W, float* __restrict__ featv)
{
    int t = threadIdx.x;
    int k0 = blockIdx.x*256;
    float acc[16];
    #pragma unroll
    for (int b = 0; b < 16; ++b) acc[b] = 0.f;
    for (int k = k0; k < k0 + 256; ++k) {
        float w = W[(size_t)k*128 + t];
        int c = k >> 9, sp = k & 511;
        #pragma unroll
        for (int b = 0; b < 16; ++b)
            acc[b] = fmaf(b2f(X[(size_t)((b*512 + sp))*64 + c]), w, acc[b]);
    }
    for (int b = 0; b < 16; ++b) unsafeAtomicAdd(featv + b*512 + t, acc[b]);
}

// ---------------- small dense layers ----------------
__global__ __launch_bounds__(256) void head_k(
    const float* __restrict__ X, const float* __restrict__ W, const float* __restrict__ b,
    float* __restrict__ O, int K, int Ncol, int relu)
{
    int t = blockIdx.x*256 + threadIdx.x;
    if (t >= 16*Ncol) return;
    int bi = t / Ncol, c = t % Ncol;
    float acc = b[c];
    for (int k = 0; k < K; ++k) acc = fmaf(X[bi*K + k], W[k*Ncol + c], acc);
    if (relu) acc = fmaxf(acc, 0.f);
    O[bi*Ncol + c] = acc;
}

__global__ void gebn_k(const float* __restrict__ g2, const float* __restrict__ g,
                       const float* __restrict__ b, float* __restrict__ featg)
{
    int c = threadIdx.x;
    float m = 0.f;
    for (int i = 0; i < 16; ++i) m += g2[i*128 + c];
    m *= (1.f/16.f);
    float v = 0.f;
    for (int i = 0; i < 16; ++i) { float d = g2[i*128 + c] - m; v += d*d; }
    v *= (1.f/16.f);
    float s = g[c] * rsqrtf(v + 1e-5f);
    for (int i = 0; i < 16; ++i)
        featg[i*512 + c] = fmaxf((g2[i*128 + c] - m)*s + b[c], 0.f);
}

__global__ void finalize_feat_k(float* __restrict__ feat, const float* __restrict__ cntm,
                                const float* __restrict__ cntz, const float* __restrict__ fcb)
{
    int t = blockIdx.x*256 + threadIdx.x;
    if (t >= 8192) return;
    int bi = t >> 9, c = t & 511;
    float v = feat[t];
    if      (c < 128) v /= fmaxf(cntm[bi], 1.f);
    else if (c < 256) v /= fmaxf(cntz[bi], 1.f);
    else if (c >= 384) v = fmaxf(v + fcb[c - 384], 0.f);
    feat[t] = v;
}

// =====================================================================================
extern "C" void kernel_launch(void* const* d_in, const int* in_sizes, int n_in,
                              void* d_out, int out_size, void* d_ws, size_t ws_size,
                              hipStream_t stream)
{
    const int*   mol_x  = (const int*)  d_in[0];
    const float* mol_q  = (const float*)d_in[1];
    const int*   mol_ei = (const int*)  d_in[2];
    const float* mol_ew = (const float*)d_in[3];
    const int*   mol_bv = (const int*)  d_in[4];
    const int*   zeo_x  = (const int*)  d_in[5];
    const int*   zeo_ei = (const int*)  d_in[6];
    const int*   zeo_bv = (const int*)  d_in[7];
    const float* voxel  = (const float*)d_in[8];
    const float* gattr  = (const float*)d_in[9];
    const float* ea  = (const float*)d_in[10];
    const float* ed  = (const float*)d_in[11];
    const float* ec  = (const float*)d_in[12];
    const float* eh  = (const float*)d_in[13];
    const float* ear = (const float*)d_in[14];
    const float* ech = (const float*)d_in[15];
    const float* mc1w=(const float*)d_in[16]; const float* mc1b=(const float*)d_in[17];
    const float* mc2w=(const float*)d_in[18]; const float* mc2b=(const float*)d_in[19];
    const float* zc1w=(const float*)d_in[20]; const float* zc1b=(const float*)d_in[21];
    const float* zc2w=(const float*)d_in[22]; const float* zc2b=(const float*)d_in[23];
    const float* cv1w=(const float*)d_in[24]; const float* cv1b=(const float*)d_in[25];
    const float* bn1g=(const float*)d_in[26]; const float* bn1b=(const float*)d_in[27];
    const float* cv2w=(const float*)d_in[28]; const float* cv2b=(const float*)d_in[29];
    const float* bn2g=(const float*)d_in[30]; const float* bn2b=(const float*)d_in[31];
    const float* cv3w=(const float*)d_in[32]; const float* cv3b=(const float*)d_in[33];
    const float* bn3g=(const float*)d_in[34]; const float* bn3b=(const float*)d_in[35];
    const float* fcw =(const float*)d_in[36]; const float* fcb =(const float*)d_in[37];
    const float* ge1w=(const float*)d_in[38]; const float* ge1b=(const float*)d_in[39];
    const float* ge2w=(const float*)d_in[40]; const float* ge2b=(const float*)d_in[41];
    const float* gbng=(const float*)d_in[42]; const float* gbnb=(const float*)d_in[43];
    const float* h1w =(const float*)d_in[44]; const float* h1b =(const float*)d_in[45];
    const float* h2w =(const float*)d_in[46]; const float* h2b =(const float*)d_in[47];
    const float* h3w =(const float*)d_in[48]; const float* h3b =(const float*)d_in[49];

    const int Nm = in_sizes[0]/6, Em = in_sizes[2]/2;
    const int Nz = in_sizes[5]/6, Ez = in_sizes[6]/2;
    const int NBm = (Nm + 1023)/1024, NBz = (Nz + 1023)/1024;

    float* WS = (float*)d_ws;
    float* A  = WS;
    float* Bb = WS + 16777216;
    float* S  = WS + 33554432;
    ushort* X0 = (ushort*)A;
    ushort* X1 = (ushort*)A + 16777216;
    ushort* X2 = (ushort*)Bb;
    ushort* X3 = (ushort*)Bb + 16777216;
    ushort* Au = (ushort*)A;
    ushort* Xcl1 = (ushort*)Bb;
    ushort* pm2  = Au;
    ushort* pn2  = Au + 2097152;
    ushort* Xcl2 = Au + 4194304;
    ushort* pm3  = (ushort*)Bb;
    ushort* pn3  = (ushort*)Bb + 524288;
    ushort* Xcl3 = (ushort*)Bb + 1048576;
    float* deg  = S;
    float* dis  = S + 131072;
    float* csr_nrm = S + 262144;
    float* T    = S + 786432;
    float* cntm = S + 807040;
    float* cntz = S + 807056;
    float* feat = S + 807072;
    float* st1  = S + 815264; float* st2 = st1 + 32; float* st3 = st1 + 96;
    float* sc1  = S + 815488; float* sh1 = sc1 + 16;
    float* sc2  = sc1 + 32;   float* sh2 = sc1 + 64;
    float* sc3  = sc1 + 96;   float* sh3 = sc1 + 160;
    float* g1   = S + 815712;
    float* g2   = S + 816736;
    float* H1   = S + 818784;
    float* H2   = S + 826976;
    int* rowptr  = (int*)(S + 831072);          // 131073
    int* cursor  = (int*)(S + 962176);          // 131072
    int* csr_src = (int*)(S + 1093248);         // 524288 (ends S+1617536)
    ushort* wf2 = (ushort*)(S + 1617536);       // 14336 ush
    ushort* wf3 = (ushort*)(S + 1624704);       // 57344 ush
    int* bsum   = (int*)(S + 1653376);          // 256 (ends S+1653632)

    hipMemsetAsync(S, 0, (size_t)831072*sizeof(float), stream);

    // weight prepacks for MFMA conv
    wfrag_k<<<56,256,0,stream>>>(cv2w, wf2, 16, 2, 14336);
    wfrag_k<<<224,256,0,stream>>>(cv3w, wf3, 32, 4, 57344);

    // ---------------- molecule branch ----------------
    build_tables_k<<<161,128,0,stream>>>(ea,ed,ec,eh,ear,ech, mc1w, T);
    init_deg_k   <<<Nm/256,256,0,stream>>>(deg, Nm);
    deg_scatter_k<<<Em/256,256,0,stream>>>(mol_ei+Em, mol_ew, deg, Em);
    dis_k        <<<Nm/256,256,0,stream>>>(deg, dis, Nm);
    hipMemsetAsync(cursor, 0, (size_t)Nm*sizeof(int), stream);
    count_in_k   <<<Em/256,256,0,stream>>>(mol_ei+Em, cursor, Em);
    blocksum_k   <<<NBm,256,0,stream>>>(cursor, bsum, Nm);
    scan_bsum_k  <<<1,256,0,stream>>>(bsum, NBm);
    scan_apply_k <<<NBm,256,0,stream>>>(cursor, bsum, rowptr, Nm, Em);
    fill_csr_k   <<<Em/256,256,0,stream>>>(mol_ei, mol_ei+Em, mol_ew, dis, cursor, csr_src, csr_nrm, Em);
    embed_lookup_k<<<Nm/8,256,0,stream>>>(mol_x, mol_q, T, mc1w + 112*128, X0, Nm);
    gcn_gather_k <<<Nm/8,256,0,stream>>>(X0, rowptr, csr_src, csr_nrm, dis, mc1b, X1, Nm);
    gemm_mfma_k  <<<Nm/64,256,0,stream>>>(X1, mc2w, X2, Nm);
    gcn_gather_k <<<Nm/8,256,0,stream>>>(X2, rowptr, csr_src, csr_nrm, dis, mc2b, X3, Nm);
    count_batch_k<<<Nm/256,256,0,stream>>>(mol_bv, cntm, Nm);
    mean_pool_sum_k<<<256,128,0,stream>>>(X3, mol_bv, feat + 0, (Nm+255)/256, Nm);

    // ---------------- zeolite branch ----------------
    build_tables_k<<<161,128,0,stream>>>(ea,ed,ec,eh,ear,ech, zc1w, T);
    init_deg_k   <<<Nz/256,256,0,stream>>>(deg, Nz);
    deg_scatter_k<<<Ez/256,256,0,stream>>>(zeo_ei+Ez, nullptr, deg, Ez);
    dis_k        <<<Nz/256,256,0,stream>>>(deg, dis, Nz);
    hipMemsetAsync(cursor, 0, (size_t)Nz*sizeof(int), stream);
    count_in_k   <<<Ez/256,256,0,stream>>>(zeo_ei+Ez, cursor, Ez);
    blocksum_k   <<<NBz,256,0,stream>>>(cursor, bsum, Nz);
    scan_bsum_k  <<<1,256,0,stream>>>(bsum, NBz);
    scan_apply_k <<<NBz,256,0,stream>>>(cursor, bsum, rowptr, Nz, Ez);
    fill_csr_k   <<<Ez/256,256,0,stream>>>(zeo_ei, zeo_ei+Ez, nullptr, dis, cursor, csr_src, csr_nrm, Ez);
    embed_lookup_k<<<Nz/8,256,0,stream>>>(zeo_x, nullptr, T, nullptr, X0, Nz);
    gcn_gather_k <<<Nz/8,256,0,stream>>>(X0, rowptr, csr_src, csr_nrm, dis, zc1b, X1, Nz);
    gemm_mfma_k  <<<Nz/64,256,0,stream>>>(X1, zc2w, X2, Nz);
    gcn_gather_k <<<Nz/8,256,0,stream>>>(X2, rowptr, csr_src, csr_nrm, dis, zc2b, X3, Nz);
    count_batch_k<<<Nz/256,256,0,stream>>>(zeo_bv, cntz, Nz);
    mean_pool_sum_k<<<256,128,0,stream>>>(X3, zeo_bv, feat + 128, (Nz+255)/256, Nz);

    // ---------------- voxel CNN ----------------
    conv_pool4_k<2,16,64,8,false><<<dim3(128,2,16),256,0,stream>>>(
        voxel, nullptr, nullptr, nullptr, cv1w, cv1b, A, A+8388608, st1);
    bn_final_k<<<1,64,0,stream>>>(st1, bn1g, bn1b, sc1, sh1, 16, 1.f/(16.f*262144.f));
    bn_select_cl1_k<<<dim3(128,16),256,0,stream>>>(A, A+8388608, sc1, sh1, Xcl1);

    conv_mfma_k<1,2,32,16,32><<<dim3(128,16),256,0,stream>>>(Xcl1, wf2, cv2b, pm2, pn2, st2);
    bn_final_k<<<1,64,0,stream>>>(st2, bn2g, bn2b, sc2, sh2, 32, 1.f/(16.f*32768.f));
    bn_select_cl23_k<<<8192,256,0,stream>>>(pm2, pn2, sc2, sh2, Xcl2, 31, 2097152);

    conv_mfma_k<2,4,16,32,64><<<dim3(16,16),256,0,stream>>>(Xcl2, wf3, cv3b, pm3, pn3, st3);
    bn_final_k<<<1,64,0,stream>>>(st3, bn3g, bn3b, sc3, sh3, 64, 1.f/(16.f*4096.f));
    bn_select_cl23_k<<<2048,256,0,stream>>>(pm3, pn3, sc3, sh3, Xcl3, 63, 524288);

    fc_acc_k<<<128,128,0,stream>>>(Xcl3, fcw, feat + 384);

    // ---------------- global encoder ----------------
    head_k<<<4,256,0,stream>>>(gattr, ge1w, ge1b, g1, 17, 64, 1);
    head_k<<<8,256,0,stream>>>(g1, ge2w, ge2b, g2, 64, 128, 0);
    gebn_k<<<1,128,0,stream>>>(g2, gbng, gbnb, feat + 256);

    // ---------------- fusion head ----------------
    finalize_feat_k<<<32,256,0,stream>>>(feat, cntm, cntz, fcb);
    head_k<<<32,256,0,stream>>>(feat, h1w, h1b, H1, 512, 512, 1);
    head_k<<<16,256,0,stream>>>(H1, h2w, h2b, H2, 512, 256, 1);
    head_k<<<1,256,0,stream>>>(H2, h3w, h3b, (float*)d_out, 256, 3, 0);
}